// Round 1
// baseline (543.490 us; speedup 1.0000x reference)
//
#include <hip/hip_runtime.h>
#include <cmath>

#define EPSV 1e-5f
using f4 = float4;

// ---- ws layout (float offsets) ----
#define WS_SKV   0           // [4][256]
#define WS_SHKV  1024        // [4][256]
#define WS_SH    2048        // [4][256]  s_h
#define WS_SHH   3072        // [4][256]  sh_h
#define WS_A     4096        // [4][4][256] (b,h,d), includes 1/sqrt(64)
#define WS_R     8192        // [4096][4][256]
#define WS_HT    4202496     // [4096][256]
#define WS_HN    5251072     // [4096][256]
#define WS_G     6299648     // [4096][1024]

#define FMA8(acc, s, wa, wb) \
  acc[0]=fmaf((s),(wa).x,acc[0]); acc[1]=fmaf((s),(wa).y,acc[1]); \
  acc[2]=fmaf((s),(wa).z,acc[2]); acc[3]=fmaf((s),(wa).w,acc[3]); \
  acc[4]=fmaf((s),(wb).x,acc[4]); acc[5]=fmaf((s),(wb).y,acc[5]); \
  acc[6]=fmaf((s),(wb).z,acc[6]); acc[7]=fmaf((s),(wb).w,acc[7]);

#define DOT8(res, v, wa, wb) \
  res = fmaf((v)[0],(wa).x,res); res = fmaf((v)[1],(wa).y,res); \
  res = fmaf((v)[2],(wa).z,res); res = fmaf((v)[3],(wa).w,res); \
  res = fmaf((v)[4],(wb).x,res); res = fmaf((v)[5],(wb).y,res); \
  res = fmaf((v)[6],(wb).z,res); res = fmaf((v)[7],(wb).w,res);

__device__ __forceinline__ float bfly32(float v){
  v += __shfl_xor(v, 1);  v += __shfl_xor(v, 2);  v += __shfl_xor(v, 4);
  v += __shfl_xor(v, 8);  v += __shfl_xor(v, 16);
  return v;
}

__device__ __forceinline__ float gelu_tanh(float x){
  float inner = 0.7978845608028654f*(x + 0.044715f*x*x*x);
  return 0.5f*x*(1.0f + tanhf(inner));
}

// ------------------------------------------------------------------
// K0: per-batch setup. grid=4, block=256
// ------------------------------------------------------------------
__global__ __launch_bounds__(256) void k0_setup(
    const float* __restrict__ ctx, const float* __restrict__ q_emb,
    const float* __restrict__ Wkv, const float* __restrict__ bkv,
    const float* __restrict__ Wqc, const float* __restrict__ bqc,
    const float* __restrict__ Whc, const float* __restrict__ bhc,
    const float* __restrict__ Wq,  const float* __restrict__ Wk,
    float* __restrict__ ws)
{
  const int b = blockIdx.x, tid = threadIdx.x;
  __shared__ float c[64], sq[256], shq[256], qn[256], qh[256], red[8];
  if (tid < 64) c[tid] = ctx[b*64 + tid];
  __syncthreads();
  {
    float s0=0.f, s1=0.f;
    for (int j=0;j<64;++j){ float cj=c[j];
      s0 = fmaf(cj, Wkv[j*512+tid], s0); s1 = fmaf(cj, Wkv[j*512+256+tid], s1); }
    ws[WS_SKV  + b*256 + tid] = s0 + bkv[tid];
    ws[WS_SHKV + b*256 + tid] = s1 + bkv[256+tid];
  }
  {
    float s0=0.f, s1=0.f;
    for (int j=0;j<64;++j){ float cj=c[j];
      s0 = fmaf(cj, Wqc[j*512+tid], s0); s1 = fmaf(cj, Wqc[j*512+256+tid], s1); }
    sq[tid] = s0 + bqc[tid]; shq[tid] = s1 + bqc[256+tid];
  }
  {
    float s0=0.f, s1=0.f;
    for (int j=0;j<64;++j){ float cj=c[j];
      s0 = fmaf(cj, Whc[j*512+tid], s0); s1 = fmaf(cj, Whc[j*512+256+tid], s1); }
    ws[WS_SH  + b*256 + tid] = s0 + bhc[tid];
    ws[WS_SHH + b*256 + tid] = s1 + bhc[256+tid];
  }
  __syncthreads();
  // qn = LN(q_emb)*(1+sq)+shq
  float qe = q_emb[tid];
  float s1r = qe, s2r = qe*qe;
  for (int m=1;m<64;m<<=1){ s1r += __shfl_xor(s1r,m); s2r += __shfl_xor(s2r,m); }
  int wv = tid>>6, ln = tid&63;
  if (ln==0){ red[wv*2]=s1r; red[wv*2+1]=s2r; }
  __syncthreads();
  float S1 = red[0]+red[2]+red[4]+red[6];
  float S2 = red[1]+red[3]+red[5]+red[7];
  float mean = S1*(1.0f/256.0f);
  float var  = S2*(1.0f/256.0f) - mean*mean;
  float rs   = rsqrtf(var + EPSV);
  qn[tid] = (qe-mean)*rs*(1.0f+sq[tid]) + shq[tid];
  __syncthreads();
  { // qh = qn @ Wq
    float a=0.f;
    for (int d=0;d<256;++d) a = fmaf(qn[d], Wq[d*256+tid], a);
    qh[tid]=a;
  }
  __syncthreads();
  // A[h][d] = (1/8) * sum_e qh[h*64+e]*Wk[d*256+h*64+e]
  #pragma unroll
  for (int h=0;h<4;++h){
    float a=0.f;
    const float* wkr = Wk + (size_t)tid*256 + h*64;
    const float* qhr = qh + h*64;
    for (int e=0;e<64;++e) a = fmaf(qhr[e], wkr[e], a);
    ws[WS_A + b*1024 + h*256 + tid] = 0.125f*a;
  }
}

// ------------------------------------------------------------------
// K1: fused kv + LN + affine+bias + attention logits + softmax + r
// grid=512 (8 tokens each), block=128  (tq=tid>>5 in 0..3, dg=tid&31)
// thread tokens: {tq, tq+4}; thread d-set: {4dg..4dg+3} U {128+4dg..+3}
// ------------------------------------------------------------------
__device__ __forceinline__ void k1_stage_w(const float* wp, float* wls, int tid){
  f4 u0 = *(const f4*)(wp + tid*8);
  f4 u1 = *(const f4*)(wp + tid*8 + 4);
  f4 u2 = *(const f4*)(wp + (tid+128)*8);
  f4 u3 = *(const f4*)(wp + (tid+128)*8 + 4);
  __syncthreads();   // previous iteration's reads complete
  wls[0*256+tid]=u0.x; wls[1*256+tid]=u0.y; wls[2*256+tid]=u0.z; wls[3*256+tid]=u0.w;
  wls[4*256+tid]=u1.x; wls[5*256+tid]=u1.y; wls[6*256+tid]=u1.z; wls[7*256+tid]=u1.w;
  wls[0*256+tid+128]=u2.x; wls[1*256+tid+128]=u2.y; wls[2*256+tid+128]=u2.z; wls[3*256+tid+128]=u2.w;
  wls[4*256+tid+128]=u3.x; wls[5*256+tid+128]=u3.y; wls[6*256+tid+128]=u3.z; wls[7*256+tid+128]=u3.w;
  __syncthreads();
}

__device__ __forceinline__ void k1_compute_val(const float* xs, const float* wls,
    int tq, int dA, int dB, int f, float val[2][8])
{
  float xv[2][8];
  #pragma unroll
  for (int tt=0;tt<2;++tt){
    int t = tq + tt*4;
    f4 xa = *(const f4*)(xs + t*256 + f*8);
    f4 xb = *(const f4*)(xs + t*256 + f*8 + 4);
    xv[tt][0]=xa.x; xv[tt][1]=xa.y; xv[tt][2]=xa.z; xv[tt][3]=xa.w;
    xv[tt][4]=xb.x; xv[tt][5]=xb.y; xv[tt][6]=xb.z; xv[tt][7]=xb.w;
  }
  #pragma unroll
  for (int tt=0;tt<2;++tt)
    #pragma unroll
    for (int jj=0;jj<8;++jj) val[tt][jj]=0.f;
  #pragma unroll
  for (int i=0;i<8;++i){
    f4 wA = *(const f4*)(wls + i*256 + dA);
    f4 wB = *(const f4*)(wls + i*256 + dB);
    #pragma unroll
    for (int tt=0;tt<2;++tt){
      float xi = xv[tt][i];
      FMA8(val[tt], xi, wA, wB);
    }
  }
}

__global__ __launch_bounds__(128) void k1_attn(
  const float* __restrict__ x, const int* __restrict__ idx,
  const float* __restrict__ Wp, const float* __restrict__ Bp,
  float* __restrict__ ws)
{
  __shared__ float xs[2048];    // [t][f][i]
  __shared__ float wls[2048];   // [i][d] for current f
  __shared__ float As[1024];    // [h][d]
  __shared__ float stats[512];  // [t][f][{mean,rs}]
  __shared__ float lg[1024];    // [t][h][f] logits -> att

  const int tid = threadIdx.x;
  const int p0  = blockIdx.x * 8;
  const int b   = p0 >> 10;
  const int tq  = tid >> 5;
  const int dg  = tid & 31;
  const int dA  = 4*dg, dB = 128 + 4*dg;

  #pragma unroll
  for (int k=0;k<4;++k)
    *(f4*)&xs[(k*128+tid)*4] = *(const f4*)(x + (size_t)p0*256 + (k*128+tid)*4);
  #pragma unroll
  for (int k=0;k<2;++k)
    *(f4*)&As[(k*128+tid)*4] = *(const f4*)(ws + WS_A + b*1024 + (k*128+tid)*4);

  f4 skA = *(const f4*)(ws + WS_SKV  + b*256 + dA);
  f4 skB = *(const f4*)(ws + WS_SKV  + b*256 + dB);
  f4 shA = *(const f4*)(ws + WS_SHKV + b*256 + dA);
  f4 shB = *(const f4*)(ws + WS_SHKV + b*256 + dB);
  float coef[8] = {1.f+skA.x,1.f+skA.y,1.f+skA.z,1.f+skA.w,
                   1.f+skB.x,1.f+skB.y,1.f+skB.z,1.f+skB.w};
  float shk[8]  = {shA.x,shA.y,shA.z,shA.w, shB.x,shB.y,shB.z,shB.w};
  __syncthreads();

  // ---------------- pass 1: LN stats + logits ----------------
  for (int f=0; f<32; ++f){
    int row = idx[f];
    f4 ba = *(const f4*)(Bp + (size_t)row*256 + dA);
    f4 bb = *(const f4*)(Bp + (size_t)row*256 + dB);
    k1_stage_w(Wp + (size_t)row*2048, wls, tid);

    float val[2][8];
    k1_compute_val(xs, wls, tq, dA, dB, f, val);

    float bias8[8] = {ba.x,ba.y,ba.z,ba.w, bb.x,bb.y,bb.z,bb.w};
    float kvl[2][8];
    float lp[2][4] = {};
    #pragma unroll
    for (int tt=0;tt<2;++tt){
      float s=0.f, ss=0.f;
      #pragma unroll
      for (int jj=0;jj<8;++jj){ s += val[tt][jj]; ss = fmaf(val[tt][jj],val[tt][jj],ss); }
      s = bfly32(s); ss = bfly32(ss);
      float mean = s*(1.f/256.f);
      float var  = ss*(1.f/256.f) - mean*mean;
      float rsg  = rsqrtf(var + EPSV);
      if (dg==0){
        int t = tq + tt*4;
        stats[(t*32+f)*2]   = mean;
        stats[(t*32+f)*2+1] = rsg;
      }
      float mrs = mean*rsg;
      #pragma unroll
      for (int jj=0;jj<8;++jj)
        kvl[tt][jj] = fmaf(fmaf(val[tt][jj], rsg, -mrs), coef[jj], shk[jj]+bias8[jj]);
    }
    #pragma unroll
    for (int h=0;h<4;++h){
      f4 Aa = *(const f4*)&As[h*256 + dA];
      f4 Ab = *(const f4*)&As[h*256 + dB];
      #pragma unroll
      for (int tt=0;tt<2;++tt){ DOT8(lp[tt][h], kvl[tt], Aa, Ab); }
    }
    #pragma unroll
    for (int tt=0;tt<2;++tt)
      #pragma unroll
      for (int h=0;h<4;++h) lp[tt][h] = bfly32(lp[tt][h]);
    if (dg < 4){
      #pragma unroll
      for (int tt=0;tt<2;++tt){
        int t = tq + tt*4;
        lg[t*128 + dg*32 + f] = lp[tt][dg];
      }
    }
  }
  __syncthreads();
  // ---------------- softmax over f ----------------
  if (tid < 32){
    int t = tid>>2, h = tid&3;
    float* L = &lg[t*128 + h*32];
    float mx = L[0];
    for (int f2=1; f2<32; ++f2) mx = fmaxf(mx, L[f2]);
    float sum = 0.f;
    for (int f2=0; f2<32; ++f2){ float e = __expf(L[f2]-mx); L[f2]=e; sum+=e; }
    float inv = 1.f/sum;
    for (int f2=0; f2<32; ++f2) L[f2] *= inv;
  }
  __syncthreads();
  // ---------------- pass 2: r = att @ kv_ln ----------------
  float racc[2][4][8] = {};
  for (int f=0; f<32; ++f){
    int row = idx[f];
    f4 ba = *(const f4*)(Bp + (size_t)row*256 + dA);
    f4 bb = *(const f4*)(Bp + (size_t)row*256 + dB);
    k1_stage_w(Wp + (size_t)row*2048, wls, tid);

    float val[2][8];
    k1_compute_val(xs, wls, tq, dA, dB, f, val);

    float bias8[8] = {ba.x,ba.y,ba.z,ba.w, bb.x,bb.y,bb.z,bb.w};
    #pragma unroll
    for (int tt=0;tt<2;++tt){
      int t = tq + tt*4;
      float mean = stats[(t*32+f)*2];
      float rsg  = stats[(t*32+f)*2+1];
      float mrs  = mean*rsg;
      float kvlv[8];
      #pragma unroll
      for (int jj=0;jj<8;++jj)
        kvlv[jj] = fmaf(fmaf(val[tt][jj], rsg, -mrs), coef[jj], shk[jj]+bias8[jj]);
      #pragma unroll
      for (int h=0;h<4;++h){
        float at = lg[t*128 + h*32 + f];
        #pragma unroll
        for (int jj=0;jj<8;++jj)
          racc[tt][h][jj] = fmaf(at, kvlv[jj], racc[tt][h][jj]);
      }
    }
  }
  #pragma unroll
  for (int tt=0;tt<2;++tt){
    int t = tq + tt*4;
    float* rp = ws + WS_R + (size_t)(p0+t)*1024;
    #pragma unroll
    for (int h=0;h<4;++h){
      *(f4*)&rp[h*256+dA] = make_float4(racc[tt][h][0],racc[tt][h][1],racc[tt][h][2],racc[tt][h][3]);
      *(f4*)&rp[h*256+dB] = make_float4(racc[tt][h][4],racc[tt][h][5],racc[tt][h][6],racc[tt][h][7]);
    }
  }
}

// ------------------------------------------------------------------
// K2: o = r @ Wv(head), o2 = o @ Wo, htok = q_emb+o2, hn = CLN(htok)
// grid=256 (16 tokens each), block=512 (tq=tid>>5 in 0..15, jq=tid&31)
// ------------------------------------------------------------------
__global__ __launch_bounds__(512) void k2_ovo(
  const float* __restrict__ Wv, const float* __restrict__ Wo,
  const float* __restrict__ q_emb, float* __restrict__ ws)
{
  __shared__ float rl[16640];   // r tile padded [t]*1040 + [h]*260 + d ; reused for o
  const int tid = threadIdx.x;
  const int p0  = blockIdx.x * 16;
  const int b   = p0 >> 10;
  const int tq  = tid >> 5;
  const int jq  = tid & 31;
  const int c0  = jq*8;

  #pragma unroll
  for (int k=0;k<8;++k){
    int flat = k*2048 + tid*4;
    f4 v = *(const f4*)(ws + WS_R + (size_t)p0*1024 + flat);
    int t = flat>>10, rem = flat&1023;
    int hh = rem>>8, d = rem&255;
    *(f4*)&rl[t*1040 + hh*260 + d] = v;
  }
  __syncthreads();

  const int hh = jq >> 3;
  float oa[8] = {};
  {
    const float* rrow = &rl[tq*1040 + hh*260];
    for (int d4=0; d4<64; ++d4){
      const int d = d4*4;
      f4 rt = *(const f4*)&rrow[d];
      float rcv[4] = {rt.x, rt.y, rt.z, rt.w};
      #pragma unroll
      for (int dd=0; dd<4; ++dd){
        f4 w0 = *(const f4*)(Wv + (size_t)(d+dd)*256 + c0);
        f4 w1 = *(const f4*)(Wv + (size_t)(d+dd)*256 + c0 + 4);
        FMA8(oa, rcv[dd], w0, w1);
      }
    }
  }
  __syncthreads();
  *(f4*)&rl[tq*256 + c0]     = make_float4(oa[0],oa[1],oa[2],oa[3]);
  *(f4*)&rl[tq*256 + c0 + 4] = make_float4(oa[4],oa[5],oa[6],oa[7]);
  __syncthreads();

  float ob[8] = {};
  {
    const float* orow = &rl[tq*256];
    for (int c4=0;c4<64;++c4){
      const int cc = c4*4;
      f4 ot = *(const f4*)&orow[cc];
      float ocv[4] = {ot.x, ot.y, ot.z, ot.w};
      #pragma unroll
      for (int dd=0;dd<4;++dd){
        f4 w0 = *(const f4*)(Wo + (size_t)(cc+dd)*256 + c0);
        f4 w1 = *(const f4*)(Wo + (size_t)(cc+dd)*256 + c0 + 4);
        FMA8(ob, ocv[dd], w0, w1);
      }
    }
  }
  f4 q0 = *(const f4*)(q_emb + c0);
  f4 q1 = *(const f4*)(q_emb + c0 + 4);
  float ht[8] = {ob[0]+q0.x, ob[1]+q0.y, ob[2]+q0.z, ob[3]+q0.w,
                 ob[4]+q1.x, ob[5]+q1.y, ob[6]+q1.z, ob[7]+q1.w};
  float s=0.f, ss=0.f;
  #pragma unroll
  for (int jj=0;jj<8;++jj){ s += ht[jj]; ss = fmaf(ht[jj],ht[jj],ss); }
  s = bfly32(s); ss = bfly32(ss);
  float mean = s*(1.f/256.f);
  float var  = ss*(1.f/256.f) - mean*mean;
  float rsg  = rsqrtf(var + EPSV);
  f4 sH0 = *(const f4*)(ws + WS_SH  + b*256 + c0);
  f4 sH1 = *(const f4*)(ws + WS_SH  + b*256 + c0 + 4);
  f4 hH0 = *(const f4*)(ws + WS_SHH + b*256 + c0);
  f4 hH1 = *(const f4*)(ws + WS_SHH + b*256 + c0 + 4);
  float sHv[8]  = {sH0.x,sH0.y,sH0.z,sH0.w, sH1.x,sH1.y,sH1.z,sH1.w};
  float hHv[8]  = {hH0.x,hH0.y,hH0.z,hH0.w, hH1.x,hH1.y,hH1.z,hH1.w};
  float hnv[8];
  #pragma unroll
  for (int jj=0;jj<8;++jj)
    hnv[jj] = (ht[jj]-mean)*rsg*(1.f+sHv[jj]) + hHv[jj];

  float* htp = ws + WS_HT + (size_t)(p0+tq)*256 + c0;
  float* hnp = ws + WS_HN + (size_t)(p0+tq)*256 + c0;
  *(f4*)htp     = make_float4(ht[0],ht[1],ht[2],ht[3]);
  *(f4*)(htp+4) = make_float4(ht[4],ht[5],ht[6],ht[7]);
  *(f4*)hnp     = make_float4(hnv[0],hnv[1],hnv[2],hnv[3]);
  *(f4*)(hnp+4) = make_float4(hnv[4],hnv[5],hnv[6],hnv[7]);
}

// ------------------------------------------------------------------
// K3: g = gelu(hn @ W1 + b1). grid = 256 token-tiles x 4 m-tiles.
// block=256 (tq=tid>>5 in 0..7 -> tokens {tq,tq+8}; mg=tid&31)
// ------------------------------------------------------------------
__global__ __launch_bounds__(256) void k3_ffn1(
  const float* __restrict__ W1, const float* __restrict__ b1,
  float* __restrict__ ws)
{
  __shared__ float hl[4096];
  const int tid = threadIdx.x;
  const int tb  = blockIdx.x >> 2;
  const int m0  = (blockIdx.x & 3) * 256;
  const int p0  = tb * 16;
  #pragma unroll
  for (int k=0;k<4;++k)
    *(f4*)&hl[(k*256+tid)*4] = *(const f4*)(ws + WS_HN + (size_t)p0*256 + (k*256+tid)*4);
  __syncthreads();
  const int tq = tid>>5, mg = tid&31;
  const int m  = m0 + mg*8;
  float ga[2][8] = {};
  for (int j4=0;j4<64;++j4){
    const int j = j4*4;
    f4 h0 = *(const f4*)&hl[tq*256 + j];
    f4 h1 = *(const f4*)&hl[(tq+8)*256 + j];
    float a0[4] = {h0.x,h0.y,h0.z,h0.w};
    float a1[4] = {h1.x,h1.y,h1.z,h1.w};
    #pragma unroll
    for (int dd=0;dd<4;++dd){
      f4 w0 = *(const f4*)(W1 + (size_t)(j+dd)*1024 + m);
      f4 w1 = *(const f4*)(W1 + (size_t)(j+dd)*1024 + m + 4);
      FMA8(ga[0], a0[dd], w0, w1);
      FMA8(ga[1], a1[dd], w0, w1);
    }
  }
  f4 bb0 = *(const f4*)(b1+m);
  f4 bb1 = *(const f4*)(b1+m+4);
  float bv[8] = {bb0.x,bb0.y,bb0.z,bb0.w, bb1.x,bb1.y,bb1.z,bb1.w};
  #pragma unroll
  for (int tt=0;tt<2;++tt){
    int t = tq + tt*8;
    float* gp = ws + WS_G + (size_t)(p0+t)*1024 + m;
    float o[8];
    #pragma unroll
    for (int jj=0;jj<8;++jj) o[jj] = gelu_tanh(ga[tt][jj]+bv[jj]);
    *(f4*)gp     = make_float4(o[0],o[1],o[2],o[3]);
    *(f4*)(gp+4) = make_float4(o[4],o[5],o[6],o[7]);
  }
}

// ------------------------------------------------------------------
// K4: out = htok + g @ W2 + b2. grid=256 (16 tokens), block=512
// ------------------------------------------------------------------
__global__ __launch_bounds__(512) void k4_ffn2(
  const float* __restrict__ W2, const float* __restrict__ b2,
  const float* __restrict__ ws, float* __restrict__ out)
{
  __shared__ float gl[16384];
  const int tid = threadIdx.x;
  const int p0  = blockIdx.x*16;
  #pragma unroll
  for (int k=0;k<8;++k){
    int flat = k*2048 + tid*4;
    *(f4*)&gl[flat] = *(const f4*)(ws + WS_G + (size_t)p0*1024 + flat);
  }
  __syncthreads();
  const int tq = tid>>5, jg = tid&31;
  const int j  = jg*8;
  float acc[8] = {};
  const float* grow = &gl[tq*1024];
  for (int m4=0;m4<256;++m4){
    const int m = m4*4;
    f4 gt = *(const f4*)&grow[m];
    float gv[4] = {gt.x,gt.y,gt.z,gt.w};
    #pragma unroll
    for (int dd=0;dd<4;++dd){
      f4 w0 = *(const f4*)(W2 + (size_t)(m+dd)*256 + j);
      f4 w1 = *(const f4*)(W2 + (size_t)(m+dd)*256 + j+4);
      FMA8(acc, gv[dd], w0, w1);
    }
  }
  f4 bb0 = *(const f4*)(b2+j);
  f4 bb1 = *(const f4*)(b2+j+4);
  const float* htp = ws + WS_HT + (size_t)(p0+tq)*256 + j;
  f4 h0 = *(const f4*)htp;
  f4 h1 = *(const f4*)(htp+4);
  float* op = out + (size_t)(p0+tq)*256 + j;
  *(f4*)op     = make_float4(acc[0]+h0.x+bb0.x, acc[1]+h0.y+bb0.y,
                             acc[2]+h0.z+bb0.z, acc[3]+h0.w+bb0.w);
  *(f4*)(op+4) = make_float4(acc[4]+h1.x+bb1.x, acc[5]+h1.y+bb1.y,
                             acc[6]+h1.z+bb1.z, acc[7]+h1.w+bb1.w);
}

// ------------------------------------------------------------------
extern "C" void kernel_launch(void* const* d_in, const int* in_sizes, int n_in,
                              void* d_out, int out_size, void* d_ws, size_t ws_size,
                              hipStream_t stream)
{
  const float* x    = (const float*)d_in[0];
  const int*   idx  = (const int*)  d_in[1];
  const float* ctx  = (const float*)d_in[2];
  const float* Wp   = (const float*)d_in[3];
  const float* Bp   = (const float*)d_in[4];
  const float* qemb = (const float*)d_in[5];
  const float* Wkv  = (const float*)d_in[6];
  const float* bkv  = (const float*)d_in[7];
  const float* Wqc  = (const float*)d_in[8];
  const float* bqc  = (const float*)d_in[9];
  const float* Whc  = (const float*)d_in[10];
  const float* bhc  = (const float*)d_in[11];
  const float* Wq   = (const float*)d_in[12];
  const float* Wk   = (const float*)d_in[13];
  const float* Wv   = (const float*)d_in[14];
  const float* Wo   = (const float*)d_in[15];
  const float* W1   = (const float*)d_in[16];
  const float* b1   = (const float*)d_in[17];
  const float* W2   = (const float*)d_in[18];
  const float* b2   = (const float*)d_in[19];
  float* ws  = (float*)d_ws;
  float* out = (float*)d_out;

  hipLaunchKernelGGL(k0_setup, dim3(4),    dim3(256), 0, stream,
                     ctx, qemb, Wkv, bkv, Wqc, bqc, Whc, bhc, Wq, Wk, ws);
  hipLaunchKernelGGL(k1_attn,  dim3(512),  dim3(128), 0, stream, x, idx, Wp, Bp, ws);
  hipLaunchKernelGGL(k2_ovo,   dim3(256),  dim3(512), 0, stream, Wv, Wo, qemb, ws);
  hipLaunchKernelGGL(k3_ffn1,  dim3(1024), dim3(256), 0, stream, W1, b1, ws);
  hipLaunchKernelGGL(k4_ffn2,  dim3(256),  dim3(512), 0, stream, W2, b2, ws, out);
}

// Round 2
// 460.032 us; speedup vs baseline: 1.1814x; 1.1814x over previous
//
#include <hip/hip_runtime.h>
#include <cmath>

#define EPSV 1e-5f
using f4 = float4;

// ---- ws layout (float offsets) ----
#define WS_SKV   0           // [4][256]
#define WS_SHKV  1024        // [4][256]
#define WS_SH    2048        // [4][256]  s_h
#define WS_SHH   3072        // [4][256]  sh_h
#define WS_A     4096        // [4][4][256] (b,h,d), includes 1/sqrt(64)
#define WS_R     8192        // [4096][4][256]
#define WS_TMP   8192        // transient: sq/shq [4][512] (K0a->K0b, then overwritten by r)
#define WS_HT    4202496     // [4096][256]   (transient: STATS [4096][32][2] for k1a->k1c)
#define WS_HN    5251072     // [4096][256]   (transient: ATT [4096][4][32] for k1a->k1c)
#define WS_G     6299648     // [4096][1024]
#define WS_STATS WS_HT
#define WS_ATT   WS_HN

#define FMA8(acc, s, wa, wb) \
  acc[0]=fmaf((s),(wa).x,acc[0]); acc[1]=fmaf((s),(wa).y,acc[1]); \
  acc[2]=fmaf((s),(wa).z,acc[2]); acc[3]=fmaf((s),(wa).w,acc[3]); \
  acc[4]=fmaf((s),(wb).x,acc[4]); acc[5]=fmaf((s),(wb).y,acc[5]); \
  acc[6]=fmaf((s),(wb).z,acc[6]); acc[7]=fmaf((s),(wb).w,acc[7]);

#define DOT8(res, v, wa, wb) \
  res = fmaf((v)[0],(wa).x,res); res = fmaf((v)[1],(wa).y,res); \
  res = fmaf((v)[2],(wa).z,res); res = fmaf((v)[3],(wa).w,res); \
  res = fmaf((v)[4],(wb).x,res); res = fmaf((v)[5],(wb).y,res); \
  res = fmaf((v)[6],(wb).z,res); res = fmaf((v)[7],(wb).w,res);

__device__ __forceinline__ float bfly32(float v){
  v += __shfl_xor(v, 1);  v += __shfl_xor(v, 2);  v += __shfl_xor(v, 4);
  v += __shfl_xor(v, 8);  v += __shfl_xor(v, 16);
  return v;
}

__device__ __forceinline__ float gelu_tanh(float x){
  float inner = 0.7978845608028654f*(x + 0.044715f*x*x*x);
  return 0.5f*x*(1.0f + tanhf(inner));
}

// ------------------------------------------------------------------
// K0a: ctx CLN projections for all three CLNs. grid = 12 (b*3+m), block=512.
// out col<256 -> scale vec, col>=256 -> shift vec.
// ------------------------------------------------------------------
__global__ __launch_bounds__(512) void k0a_proj(
    const float* __restrict__ ctx,
    const float* __restrict__ Wkv, const float* __restrict__ bkv,
    const float* __restrict__ Wqc, const float* __restrict__ bqc,
    const float* __restrict__ Whc, const float* __restrict__ bhc,
    float* __restrict__ ws)
{
  const int b = blockIdx.x / 3, m = blockIdx.x % 3;
  const int tid = threadIdx.x;
  __shared__ float c[64];
  if (tid < 64) c[tid] = ctx[b*64 + tid];
  __syncthreads();
  const float* W  = (m==0) ? Wkv : (m==1) ? Wqc : Whc;
  const float* bb = (m==0) ? bkv : (m==1) ? bqc : bhc;
  float acc = bb[tid];
  #pragma unroll 8
  for (int j=0;j<64;++j) acc = fmaf(c[j], W[j*512 + tid], acc);
  if (m==0){
    if (tid<256) ws[WS_SKV  + b*256 + tid] = acc;
    else         ws[WS_SHKV + b*256 + tid-256] = acc;
  } else if (m==1){
    ws[WS_TMP + b*512 + tid] = acc;     // sq[0..255], shq[256..511]
  } else {
    if (tid<256) ws[WS_SH  + b*256 + tid] = acc;
    else         ws[WS_SHH + b*256 + tid-256] = acc;
  }
}

// ------------------------------------------------------------------
// K0b: per (b,h): qn, qh slice, A[h][:]. grid=16 (b*4+h), block=256.
// ------------------------------------------------------------------
__global__ __launch_bounds__(256) void k0b_qa(
    const float* __restrict__ q_emb,
    const float* __restrict__ Wq,  const float* __restrict__ Wk,
    float* __restrict__ ws)
{
  const int b = blockIdx.x >> 2, h = blockIdx.x & 3;
  const int tid = threadIdx.x;
  __shared__ float qn[256], ph[256], qh64[64], red[8];

  // qn = LN(q_emb)*(1+sq)+shq
  float sq_t  = ws[WS_TMP + b*512 + tid];
  float shq_t = ws[WS_TMP + b*512 + 256 + tid];
  float qe = q_emb[tid];
  float s1r = qe, s2r = qe*qe;
  for (int mm=1;mm<64;mm<<=1){ s1r += __shfl_xor(s1r,mm); s2r += __shfl_xor(s2r,mm); }
  int wv = tid>>6, ln = tid&63;
  if (ln==0){ red[wv*2]=s1r; red[wv*2+1]=s2r; }
  __syncthreads();
  float S1 = red[0]+red[2]+red[4]+red[6];
  float S2 = red[1]+red[3]+red[5]+red[7];
  float mean = S1*(1.0f/256.0f);
  float var  = S2*(1.0f/256.0f) - mean*mean;
  float rs   = rsqrtf(var + EPSV);
  qn[tid] = (qe-mean)*rs*(1.0f+sq_t) + shq_t;
  __syncthreads();

  // qh slice for head h: qh[h*64+t] = sum_d qn[d]*Wq[d*256 + h*64+t], K-split 4-way
  {
    const int t = tid & 63, ks = tid >> 6;
    float p = 0.f;
    const float* wq = Wq + (size_t)(ks*64)*256 + h*64 + t;
    #pragma unroll 8
    for (int d=0; d<64; ++d) p = fmaf(qn[ks*64+d], wq[d*256], p);
    ph[tid] = p;
  }
  __syncthreads();
  if (tid < 64) qh64[tid] = ph[tid] + ph[64+tid] + ph[128+tid] + ph[192+tid];
  __syncthreads();

  // A[h][d] = 0.125 * sum_e qh64[e]*Wk[d*256 + h*64 + e]
  {
    float a = 0.f;
    const float* wkr = Wk + (size_t)tid*256 + h*64;
    #pragma unroll
    for (int e4=0; e4<16; ++e4){
      f4 wv4 = *(const f4*)(wkr + e4*4);
      a = fmaf(qh64[e4*4+0], wv4.x, a);
      a = fmaf(qh64[e4*4+1], wv4.y, a);
      a = fmaf(qh64[e4*4+2], wv4.z, a);
      a = fmaf(qh64[e4*4+3], wv4.w, a);
    }
    ws[WS_A + b*1024 + h*256 + tid] = 0.125f*a;
  }
}

// ------------------------------------------------------------------
// K1 shared helpers (block = 128 threads, 8 tokens, 16 f per block)
// ------------------------------------------------------------------
__device__ __forceinline__ void k1_stage_w(const float* wp, float* wls, int tid){
  f4 u0 = *(const f4*)(wp + tid*8);
  f4 u1 = *(const f4*)(wp + tid*8 + 4);
  f4 u2 = *(const f4*)(wp + (tid+128)*8);
  f4 u3 = *(const f4*)(wp + (tid+128)*8 + 4);
  __syncthreads();   // previous iteration's reads complete
  wls[0*256+tid]=u0.x; wls[1*256+tid]=u0.y; wls[2*256+tid]=u0.z; wls[3*256+tid]=u0.w;
  wls[4*256+tid]=u1.x; wls[5*256+tid]=u1.y; wls[6*256+tid]=u1.z; wls[7*256+tid]=u1.w;
  wls[0*256+tid+128]=u2.x; wls[1*256+tid+128]=u2.y; wls[2*256+tid+128]=u2.z; wls[3*256+tid+128]=u2.w;
  wls[4*256+tid+128]=u3.x; wls[5*256+tid+128]=u3.y; wls[6*256+tid+128]=u3.z; wls[7*256+tid+128]=u3.w;
  __syncthreads();
}

__device__ __forceinline__ void k1_compute_val(const float* xs, const float* wls,
    int tq, int dA, int dB, int f, float val[2][8])
{
  float xv[2][8];
  #pragma unroll
  for (int tt=0;tt<2;++tt){
    int t = tq + tt*4;
    f4 xa = *(const f4*)(xs + t*256 + f*8);
    f4 xb = *(const f4*)(xs + t*256 + f*8 + 4);
    xv[tt][0]=xa.x; xv[tt][1]=xa.y; xv[tt][2]=xa.z; xv[tt][3]=xa.w;
    xv[tt][4]=xb.x; xv[tt][5]=xb.y; xv[tt][6]=xb.z; xv[tt][7]=xb.w;
  }
  #pragma unroll
  for (int tt=0;tt<2;++tt)
    #pragma unroll
    for (int jj=0;jj<8;++jj) val[tt][jj]=0.f;
  #pragma unroll
  for (int i=0;i<8;++i){
    f4 wA = *(const f4*)(wls + i*256 + dA);
    f4 wB = *(const f4*)(wls + i*256 + dB);
    #pragma unroll
    for (int tt=0;tt<2;++tt){
      float xi = xv[tt][i];
      FMA8(val[tt], xi, wA, wB);
    }
  }
}

// ------------------------------------------------------------------
// K1a: LN stats + attention logits (+ zero r region).
// grid = 1024 = (512 token-tiles of 8) x (2 f-halves of 16), block = 128
// ------------------------------------------------------------------
__global__ __launch_bounds__(128) void k1a_logits(
  const float* __restrict__ x, const int* __restrict__ idx,
  const float* __restrict__ Wp, const float* __restrict__ Bp,
  float* __restrict__ ws)
{
  __shared__ float xs[2048];    // [t][f][i]
  __shared__ float wls[2048];   // [i][d] for current f
  __shared__ float As[1024];    // [h][d]

  const int tid = threadIdx.x;
  const int p0  = (blockIdx.x >> 1) * 8;
  const int f0  = (blockIdx.x & 1) * 16;
  const int b   = p0 >> 10;
  const int tq  = tid >> 5;
  const int dg  = tid & 31;
  const int dA  = 4*dg, dB = 128 + 4*dg;

  // zero the r-partial region this block owns (ws is poisoned each launch)
  {
    float* rz = ws + WS_R + (size_t)blockIdx.x * 4096;
    f4 z = make_float4(0.f,0.f,0.f,0.f);
    #pragma unroll
    for (int k=0;k<8;++k) *(f4*)(rz + k*512 + tid*4) = z;
  }

  #pragma unroll
  for (int k=0;k<4;++k)
    *(f4*)&xs[(k*128+tid)*4] = *(const f4*)(x + (size_t)p0*256 + (k*128+tid)*4);
  #pragma unroll
  for (int k=0;k<2;++k)
    *(f4*)&As[(k*128+tid)*4] = *(const f4*)(ws + WS_A + b*1024 + (k*128+tid)*4);

  f4 skA = *(const f4*)(ws + WS_SKV  + b*256 + dA);
  f4 skB = *(const f4*)(ws + WS_SKV  + b*256 + dB);
  f4 shA = *(const f4*)(ws + WS_SHKV + b*256 + dA);
  f4 shB = *(const f4*)(ws + WS_SHKV + b*256 + dB);
  float coef[8] = {1.f+skA.x,1.f+skA.y,1.f+skA.z,1.f+skA.w,
                   1.f+skB.x,1.f+skB.y,1.f+skB.z,1.f+skB.w};
  float shk[8]  = {shA.x,shA.y,shA.z,shA.w, shB.x,shB.y,shB.z,shB.w};
  __syncthreads();

  for (int fl=0; fl<16; ++fl){
    const int f = f0 + fl;
    int row = idx[f];
    f4 ba = *(const f4*)(Bp + (size_t)row*256 + dA);
    f4 bb = *(const f4*)(Bp + (size_t)row*256 + dB);
    k1_stage_w(Wp + (size_t)row*2048, wls, tid);

    float val[2][8];
    k1_compute_val(xs, wls, tq, dA, dB, f, val);

    float bias8[8] = {ba.x,ba.y,ba.z,ba.w, bb.x,bb.y,bb.z,bb.w};
    float kvl[2][8];
    float lp[2][4] = {};
    #pragma unroll
    for (int tt=0;tt<2;++tt){
      float s=0.f, ss=0.f;
      #pragma unroll
      for (int jj=0;jj<8;++jj){ s += val[tt][jj]; ss = fmaf(val[tt][jj],val[tt][jj],ss); }
      s = bfly32(s); ss = bfly32(ss);
      float mean = s*(1.f/256.f);
      float var  = ss*(1.f/256.f) - mean*mean;
      float rsg  = rsqrtf(var + EPSV);
      if (dg==0){
        int t = tq + tt*4;
        ws[WS_STATS + (size_t)(p0+t)*64 + f*2]     = mean;
        ws[WS_STATS + (size_t)(p0+t)*64 + f*2 + 1] = rsg;
      }
      float mrs = mean*rsg;
      #pragma unroll
      for (int jj=0;jj<8;++jj)
        kvl[tt][jj] = fmaf(fmaf(val[tt][jj], rsg, -mrs), coef[jj], shk[jj]+bias8[jj]);
    }
    #pragma unroll
    for (int h=0;h<4;++h){
      f4 Aa = *(const f4*)&As[h*256 + dA];
      f4 Ab = *(const f4*)&As[h*256 + dB];
      #pragma unroll
      for (int tt=0;tt<2;++tt){ DOT8(lp[tt][h], kvl[tt], Aa, Ab); }
    }
    #pragma unroll
    for (int tt=0;tt<2;++tt)
      #pragma unroll
      for (int h=0;h<4;++h) lp[tt][h] = bfly32(lp[tt][h]);
    if (dg < 4){
      #pragma unroll
      for (int tt=0;tt<2;++tt){
        int t = tq + tt*4;
        ws[WS_ATT + (size_t)(p0+t)*128 + dg*32 + f] = lp[tt][dg];
      }
    }
  }
}

// ------------------------------------------------------------------
// K1b: softmax over f per (t,h). grid=64, block=256 (1 task/thread).
// ------------------------------------------------------------------
__global__ __launch_bounds__(256) void k1b_softmax(float* __restrict__ ws)
{
  const int task = blockIdx.x*256 + threadIdx.x;   // t*4+h, 16384 tasks
  float* L = ws + WS_ATT + (size_t)task*32;
  float v[32];
  #pragma unroll
  for (int k=0;k<8;++k){
    f4 u = *(const f4*)(L + k*4);
    v[k*4]=u.x; v[k*4+1]=u.y; v[k*4+2]=u.z; v[k*4+3]=u.w;
  }
  float mx = v[0];
  #pragma unroll
  for (int f=1;f<32;++f) mx = fmaxf(mx, v[f]);
  float sum = 0.f;
  #pragma unroll
  for (int f=0;f<32;++f){ v[f] = __expf(v[f]-mx); sum += v[f]; }
  float inv = 1.f/sum;
  #pragma unroll
  for (int k=0;k<8;++k)
    *(f4*)(L + k*4) = make_float4(v[k*4]*inv, v[k*4+1]*inv, v[k*4+2]*inv, v[k*4+3]*inv);
}

// ------------------------------------------------------------------
// K1c: r = att @ kv_ln (recompute kv, atomic-accumulate partial over f-half)
// grid = 1024 = 512 token-tiles x 2 f-halves, block = 128
// ------------------------------------------------------------------
__global__ __launch_bounds__(128) void k1c_racc(
  const float* __restrict__ x, const int* __restrict__ idx,
  const float* __restrict__ Wp, const float* __restrict__ Bp,
  float* __restrict__ ws)
{
  __shared__ float xs[2048];     // [t][f][i]
  __shared__ float wls[2048];    // [i][d]
  __shared__ float sst[256];     // [t][fl][{mean,rs}]
  __shared__ float atile[512];   // [t][h][fl]

  const int tid = threadIdx.x;
  const int p0  = (blockIdx.x >> 1) * 8;
  const int f0  = (blockIdx.x & 1) * 16;
  const int b   = p0 >> 10;
  const int tq  = tid >> 5;
  const int dg  = tid & 31;
  const int dA  = 4*dg, dB = 128 + 4*dg;

  #pragma unroll
  for (int k=0;k<4;++k)
    *(f4*)&xs[(k*128+tid)*4] = *(const f4*)(x + (size_t)p0*256 + (k*128+tid)*4);
  {
    int t = tid>>4, fl = tid&15;
    size_t g = (size_t)(p0+t)*64 + (f0+fl)*2;
    sst[t*32+fl*2]   = ws[WS_STATS + g];
    sst[t*32+fl*2+1] = ws[WS_STATS + g + 1];
    #pragma unroll
    for (int h=0;h<4;++h)
      atile[t*64 + h*16 + fl] = ws[WS_ATT + (size_t)(p0+t)*128 + h*32 + f0 + fl];
  }
  f4 skA = *(const f4*)(ws + WS_SKV  + b*256 + dA);
  f4 skB = *(const f4*)(ws + WS_SKV  + b*256 + dB);
  f4 shA = *(const f4*)(ws + WS_SHKV + b*256 + dA);
  f4 shB = *(const f4*)(ws + WS_SHKV + b*256 + dB);
  float coef[8] = {1.f+skA.x,1.f+skA.y,1.f+skA.z,1.f+skA.w,
                   1.f+skB.x,1.f+skB.y,1.f+skB.z,1.f+skB.w};
  float shk[8]  = {shA.x,shA.y,shA.z,shA.w, shB.x,shB.y,shB.z,shB.w};
  __syncthreads();

  float racc[2][4][8] = {};
  for (int fl=0; fl<16; ++fl){
    const int f = f0 + fl;
    int row = idx[f];
    f4 ba = *(const f4*)(Bp + (size_t)row*256 + dA);
    f4 bb = *(const f4*)(Bp + (size_t)row*256 + dB);
    k1_stage_w(Wp + (size_t)row*2048, wls, tid);

    float val[2][8];
    k1_compute_val(xs, wls, tq, dA, dB, f, val);

    float bias8[8] = {ba.x,ba.y,ba.z,ba.w, bb.x,bb.y,bb.z,bb.w};
    #pragma unroll
    for (int tt=0;tt<2;++tt){
      int t = tq + tt*4;
      float mean = sst[t*32 + fl*2];
      float rsg  = sst[t*32 + fl*2 + 1];
      float mrs  = mean*rsg;
      float kvlv[8];
      #pragma unroll
      for (int jj=0;jj<8;++jj)
        kvlv[jj] = fmaf(fmaf(val[tt][jj], rsg, -mrs), coef[jj], shk[jj]+bias8[jj]);
      #pragma unroll
      for (int h=0;h<4;++h){
        float at = atile[t*64 + h*16 + fl];
        #pragma unroll
        for (int jj=0;jj<8;++jj)
          racc[tt][h][jj] = fmaf(at, kvlv[jj], racc[tt][h][jj]);
      }
    }
  }
  #pragma unroll
  for (int tt=0;tt<2;++tt){
    int t = tq + tt*4;
    float* rp = ws + WS_R + (size_t)(p0+t)*1024;
    #pragma unroll
    for (int h=0;h<4;++h){
      #pragma unroll
      for (int jj=0;jj<4;++jj){
        atomicAdd(&rp[h*256 + dA + jj], racc[tt][h][jj]);
        atomicAdd(&rp[h*256 + dB + jj], racc[tt][h][jj+4]);
      }
    }
  }
}

// ------------------------------------------------------------------
// K2: o = r @ Wv(head), o2 = o @ Wo, htok = q_emb+o2, hn = CLN(htok)
// grid=512 (8 tokens each), block=256 (tq=tid>>5 in 0..7, jq=tid&31)
// ------------------------------------------------------------------
__global__ __launch_bounds__(256) void k2_ovo(
  const float* __restrict__ Wv, const float* __restrict__ Wo,
  const float* __restrict__ q_emb, float* __restrict__ ws)
{
  __shared__ float rl[8320];   // r tile padded [t]*1040 + [h]*260 + d ; reused for o
  const int tid = threadIdx.x;
  const int p0  = blockIdx.x * 8;
  const int b   = p0 >> 10;
  const int tq  = tid >> 5;
  const int jq  = tid & 31;
  const int c0  = jq*8;

  #pragma unroll
  for (int k=0;k<8;++k){
    int flat = k*1024 + tid*4;
    f4 v = *(const f4*)(ws + WS_R + (size_t)p0*1024 + flat);
    int t = flat>>10, rem = flat&1023;
    int hh2 = rem>>8, d = rem&255;
    *(f4*)&rl[t*1040 + hh2*260 + d] = v;
  }
  __syncthreads();

  const int hh = jq >> 3;
  float oa[8] = {};
  {
    const float* rrow = &rl[tq*1040 + hh*260];
    for (int d4=0; d4<64; ++d4){
      const int d = d4*4;
      f4 rt = *(const f4*)&rrow[d];
      float rcv[4] = {rt.x, rt.y, rt.z, rt.w};
      #pragma unroll
      for (int dd=0; dd<4; ++dd){
        f4 w0 = *(const f4*)(Wv + (size_t)(d+dd)*256 + c0);
        f4 w1 = *(const f4*)(Wv + (size_t)(d+dd)*256 + c0 + 4);
        FMA8(oa, rcv[dd], w0, w1);
      }
    }
  }
  __syncthreads();
  *(f4*)&rl[tq*256 + c0]     = make_float4(oa[0],oa[1],oa[2],oa[3]);
  *(f4*)&rl[tq*256 + c0 + 4] = make_float4(oa[4],oa[5],oa[6],oa[7]);
  __syncthreads();

  float ob[8] = {};
  {
    const float* orow = &rl[tq*256];
    for (int c4=0;c4<64;++c4){
      const int cc = c4*4;
      f4 ot = *(const f4*)&orow[cc];
      float ocv[4] = {ot.x, ot.y, ot.z, ot.w};
      #pragma unroll
      for (int dd=0;dd<4;++dd){
        f4 w0 = *(const f4*)(Wo + (size_t)(cc+dd)*256 + c0);
        f4 w1 = *(const f4*)(Wo + (size_t)(cc+dd)*256 + c0 + 4);
        FMA8(ob, ocv[dd], w0, w1);
      }
    }
  }
  f4 q0 = *(const f4*)(q_emb + c0);
  f4 q1 = *(const f4*)(q_emb + c0 + 4);
  float ht[8] = {ob[0]+q0.x, ob[1]+q0.y, ob[2]+q0.z, ob[3]+q0.w,
                 ob[4]+q1.x, ob[5]+q1.y, ob[6]+q1.z, ob[7]+q1.w};
  float s=0.f, ss=0.f;
  #pragma unroll
  for (int jj=0;jj<8;++jj){ s += ht[jj]; ss = fmaf(ht[jj],ht[jj],ss); }
  s = bfly32(s); ss = bfly32(ss);
  float mean = s*(1.f/256.f);
  float var  = ss*(1.f/256.f) - mean*mean;
  float rsg  = rsqrtf(var + EPSV);
  f4 sH0 = *(const f4*)(ws + WS_SH  + b*256 + c0);
  f4 sH1 = *(const f4*)(ws + WS_SH  + b*256 + c0 + 4);
  f4 hH0 = *(const f4*)(ws + WS_SHH + b*256 + c0);
  f4 hH1 = *(const f4*)(ws + WS_SHH + b*256 + c0 + 4);
  float sHv[8]  = {sH0.x,sH0.y,sH0.z,sH0.w, sH1.x,sH1.y,sH1.z,sH1.w};
  float hHv[8]  = {hH0.x,hH0.y,hH0.z,hH0.w, hH1.x,hH1.y,hH1.z,hH1.w};
  float hnv[8];
  #pragma unroll
  for (int jj=0;jj<8;++jj)
    hnv[jj] = (ht[jj]-mean)*rsg*(1.f+sHv[jj]) + hHv[jj];

  float* htp = ws + WS_HT + (size_t)(p0+tq)*256 + c0;
  float* hnp = ws + WS_HN + (size_t)(p0+tq)*256 + c0;
  *(f4*)htp     = make_float4(ht[0],ht[1],ht[2],ht[3]);
  *(f4*)(htp+4) = make_float4(ht[4],ht[5],ht[6],ht[7]);
  *(f4*)hnp     = make_float4(hnv[0],hnv[1],hnv[2],hnv[3]);
  *(f4*)(hnp+4) = make_float4(hnv[4],hnv[5],hnv[6],hnv[7]);
}

// ------------------------------------------------------------------
// K3: g = gelu(hn @ W1 + b1). grid = 256 token-tiles x 4 m-tiles.
// block=256 (tq=tid>>5 in 0..7 -> tokens {tq,tq+8}; mg=tid&31)
// ------------------------------------------------------------------
__global__ __launch_bounds__(256) void k3_ffn1(
  const float* __restrict__ W1, const float* __restrict__ b1,
  float* __restrict__ ws)
{
  __shared__ float hl[4096];
  const int tid = threadIdx.x;
  const int tb  = blockIdx.x >> 2;
  const int m0  = (blockIdx.x & 3) * 256;
  const int p0  = tb * 16;
  #pragma unroll
  for (int k=0;k<4;++k)
    *(f4*)&hl[(k*256+tid)*4] = *(const f4*)(ws + WS_HN + (size_t)p0*256 + (k*256+tid)*4);
  __syncthreads();
  const int tq = tid>>5, mg = tid&31;
  const int m  = m0 + mg*8;
  float ga[2][8] = {};
  for (int j4=0;j4<64;++j4){
    const int j = j4*4;
    f4 h0 = *(const f4*)&hl[tq*256 + j];
    f4 h1 = *(const f4*)&hl[(tq+8)*256 + j];
    float a0[4] = {h0.x,h0.y,h0.z,h0.w};
    float a1[4] = {h1.x,h1.y,h1.z,h1.w};
    #pragma unroll
    for (int dd=0;dd<4;++dd){
      f4 w0 = *(const f4*)(W1 + (size_t)(j+dd)*1024 + m);
      f4 w1 = *(const f4*)(W1 + (size_t)(j+dd)*1024 + m + 4);
      FMA8(ga[0], a0[dd], w0, w1);
      FMA8(ga[1], a1[dd], w0, w1);
    }
  }
  f4 bb0 = *(const f4*)(b1+m);
  f4 bb1 = *(const f4*)(b1+m+4);
  float bv[8] = {bb0.x,bb0.y,bb0.z,bb0.w, bb1.x,bb1.y,bb1.z,bb1.w};
  #pragma unroll
  for (int tt=0;tt<2;++tt){
    int t = tq + tt*8;
    float* gp = ws + WS_G + (size_t)(p0+t)*1024 + m;
    float o[8];
    #pragma unroll
    for (int jj=0;jj<8;++jj) o[jj] = gelu_tanh(ga[tt][jj]+bv[jj]);
    *(f4*)gp     = make_float4(o[0],o[1],o[2],o[3]);
    *(f4*)(gp+4) = make_float4(o[4],o[5],o[6],o[7]);
  }
}

// ------------------------------------------------------------------
// K4: out = htok + g @ W2 + b2.
// grid = 512 = 256 token-tiles(16) x 2 col-halves(128), block=256
// thread: tq=tid>>5 -> tokens {tq, tq+8}; mg=tid&31 -> cols n0+mg*4..+3
// ------------------------------------------------------------------
__global__ __launch_bounds__(256) void k4_ffn2(
  const float* __restrict__ W2, const float* __restrict__ b2,
  const float* __restrict__ ws, float* __restrict__ out)
{
  __shared__ float gl[16384];   // [16 t][1024 m]
  const int tid = threadIdx.x;
  const int tb  = blockIdx.x >> 1;
  const int n0  = (blockIdx.x & 1) * 128;
  const int p0  = tb * 16;
  #pragma unroll
  for (int k=0;k<16;++k){
    int flat = k*1024 + tid*4;
    *(f4*)&gl[flat] = *(const f4*)(ws + WS_G + (size_t)p0*1024 + flat);
  }
  __syncthreads();
  const int tq = tid>>5, mg = tid&31;
  const int col = n0 + mg*4;
  float acc[2][4] = {};
  for (int k4=0;k4<256;++k4){
    const int k = k4*4;
    f4 g0 = *(const f4*)&gl[tq*1024 + k];
    f4 g1 = *(const f4*)&gl[(tq+8)*1024 + k];
    float gv0[4] = {g0.x,g0.y,g0.z,g0.w};
    float gv1[4] = {g1.x,g1.y,g1.z,g1.w};
    #pragma unroll
    for (int dd=0;dd<4;++dd){
      f4 w = *(const f4*)(W2 + (size_t)(k+dd)*256 + col);
      acc[0][0]=fmaf(gv0[dd],w.x,acc[0][0]); acc[0][1]=fmaf(gv0[dd],w.y,acc[0][1]);
      acc[0][2]=fmaf(gv0[dd],w.z,acc[0][2]); acc[0][3]=fmaf(gv0[dd],w.w,acc[0][3]);
      acc[1][0]=fmaf(gv1[dd],w.x,acc[1][0]); acc[1][1]=fmaf(gv1[dd],w.y,acc[1][1]);
      acc[1][2]=fmaf(gv1[dd],w.z,acc[1][2]); acc[1][3]=fmaf(gv1[dd],w.w,acc[1][3]);
    }
  }
  f4 bb = *(const f4*)(b2 + col);
  #pragma unroll
  for (int tt=0;tt<2;++tt){
    int t = tq + tt*8;
    f4 h0 = *(const f4*)(ws + WS_HT + (size_t)(p0+t)*256 + col);
    *(f4*)(out + (size_t)(p0+t)*256 + col) =
      make_float4(acc[tt][0]+h0.x+bb.x, acc[tt][1]+h0.y+bb.y,
                  acc[tt][2]+h0.z+bb.z, acc[tt][3]+h0.w+bb.w);
  }
}

// ------------------------------------------------------------------
extern "C" void kernel_launch(void* const* d_in, const int* in_sizes, int n_in,
                              void* d_out, int out_size, void* d_ws, size_t ws_size,
                              hipStream_t stream)
{
  const float* x    = (const float*)d_in[0];
  const int*   idx  = (const int*)  d_in[1];
  const float* ctx  = (const float*)d_in[2];
  const float* Wp   = (const float*)d_in[3];
  const float* Bp   = (const float*)d_in[4];
  const float* qemb = (const float*)d_in[5];
  const float* Wkv  = (const float*)d_in[6];
  const float* bkv  = (const float*)d_in[7];
  const float* Wqc  = (const float*)d_in[8];
  const float* bqc  = (const float*)d_in[9];
  const float* Whc  = (const float*)d_in[10];
  const float* bhc  = (const float*)d_in[11];
  const float* Wq   = (const float*)d_in[12];
  const float* Wk   = (const float*)d_in[13];
  const float* Wv   = (const float*)d_in[14];
  const float* Wo   = (const float*)d_in[15];
  const float* W1   = (const float*)d_in[16];
  const float* b1   = (const float*)d_in[17];
  const float* W2   = (const float*)d_in[18];
  const float* b2   = (const float*)d_in[19];
  float* ws  = (float*)d_ws;
  float* out = (float*)d_out;

  hipLaunchKernelGGL(k0a_proj,   dim3(12),   dim3(512), 0, stream,
                     ctx, Wkv, bkv, Wqc, bqc, Whc, bhc, ws);
  hipLaunchKernelGGL(k0b_qa,     dim3(16),   dim3(256), 0, stream, qemb, Wq, Wk, ws);
  hipLaunchKernelGGL(k1a_logits, dim3(1024), dim3(128), 0, stream, x, idx, Wp, Bp, ws);
  hipLaunchKernelGGL(k1b_softmax,dim3(64),   dim3(256), 0, stream, ws);
  hipLaunchKernelGGL(k1c_racc,   dim3(1024), dim3(128), 0, stream, x, idx, Wp, Bp, ws);
  hipLaunchKernelGGL(k2_ovo,     dim3(512),  dim3(256), 0, stream, Wv, Wo, qemb, ws);
  hipLaunchKernelGGL(k3_ffn1,    dim3(1024), dim3(256), 0, stream, W1, b1, ws);
  hipLaunchKernelGGL(k4_ffn2,    dim3(512),  dim3(256), 0, stream, W2, b2, ws, out);
}

// Round 4
// 343.472 us; speedup vs baseline: 1.5823x; 1.3394x over previous
//
#include <hip/hip_runtime.h>
#include <cmath>

#define EPSV 1e-5f
using f4 = float4;

// ---- ws layout (float offsets) ----
#define WS_SKV   0           // [4][256]
#define WS_SHKV  1024        // [4][256]
#define WS_SH    2048        // [4][256]  s_h
#define WS_SHH   3072        // [4][256]  sh_h
#define WS_A     4096        // [4][4][256] (b,h,d), includes 1/sqrt(64)
#define WS_R     8192        // [4096][4][256]
#define WS_TMP   8192        // transient: sq/shq [4][512] (K0a->K0b, then overwritten by r)
#define WS_HT    4202496     // [4096][256]
#define WS_HN    5251072     // [4096][256]
#define WS_G     6299648     // [4096][1024]

#define FMA8(acc, s, wa, wb) \
  acc[0]=fmaf((s),(wa).x,acc[0]); acc[1]=fmaf((s),(wa).y,acc[1]); \
  acc[2]=fmaf((s),(wa).z,acc[2]); acc[3]=fmaf((s),(wa).w,acc[3]); \
  acc[4]=fmaf((s),(wb).x,acc[4]); acc[5]=fmaf((s),(wb).y,acc[5]); \
  acc[6]=fmaf((s),(wb).z,acc[6]); acc[7]=fmaf((s),(wb).w,acc[7]);

#define DOT8(res, v, wa, wb) \
  res = fmaf((v)[0],(wa).x,res); res = fmaf((v)[1],(wa).y,res); \
  res = fmaf((v)[2],(wa).z,res); res = fmaf((v)[3],(wa).w,res); \
  res = fmaf((v)[4],(wb).x,res); res = fmaf((v)[5],(wb).y,res); \
  res = fmaf((v)[6],(wb).z,res); res = fmaf((v)[7],(wb).w,res);

__device__ __forceinline__ float bfly32(float v){
  v += __shfl_xor(v, 1);  v += __shfl_xor(v, 2);  v += __shfl_xor(v, 4);
  v += __shfl_xor(v, 8);  v += __shfl_xor(v, 16);
  return v;
}

__device__ __forceinline__ float gelu_tanh(float x){
  float inner = 0.7978845608028654f*(x + 0.044715f*x*x*x);
  return 0.5f*x*(1.0f + tanhf(inner));
}

// ------------------------------------------------------------------
// K0a: ctx CLN projections for all three CLNs. grid = 12 (b*3+m), block=512.
// ------------------------------------------------------------------
__global__ __launch_bounds__(512) void k0a_proj(
    const float* __restrict__ ctx,
    const float* __restrict__ Wkv, const float* __restrict__ bkv,
    const float* __restrict__ Wqc, const float* __restrict__ bqc,
    const float* __restrict__ Whc, const float* __restrict__ bhc,
    float* __restrict__ ws)
{
  const int b = blockIdx.x / 3, m = blockIdx.x % 3;
  const int tid = threadIdx.x;
  __shared__ float c[64];
  if (tid < 64) c[tid] = ctx[b*64 + tid];
  __syncthreads();
  const float* W  = (m==0) ? Wkv : (m==1) ? Wqc : Whc;
  const float* bb = (m==0) ? bkv : (m==1) ? bqc : bhc;
  float acc = bb[tid];
  #pragma unroll 8
  for (int j=0;j<64;++j) acc = fmaf(c[j], W[j*512 + tid], acc);
  if (m==0){
    if (tid<256) ws[WS_SKV  + b*256 + tid] = acc;
    else         ws[WS_SHKV + b*256 + tid-256] = acc;
  } else if (m==1){
    ws[WS_TMP + b*512 + tid] = acc;     // sq[0..255], shq[256..511]
  } else {
    if (tid<256) ws[WS_SH  + b*256 + tid] = acc;
    else         ws[WS_SHH + b*256 + tid-256] = acc;
  }
}

// ------------------------------------------------------------------
// K0b: per (b,h): qn, qh slice, A[h][:]. grid=16 (b*4+h), block=256.
// ------------------------------------------------------------------
__global__ __launch_bounds__(256) void k0b_qa(
    const float* __restrict__ q_emb,
    const float* __restrict__ Wq,  const float* __restrict__ Wk,
    float* __restrict__ ws)
{
  const int b = blockIdx.x >> 2, h = blockIdx.x & 3;
  const int tid = threadIdx.x;
  __shared__ float qn[256], ph[256], qh64[64], red[8];

  float sq_t  = ws[WS_TMP + b*512 + tid];
  float shq_t = ws[WS_TMP + b*512 + 256 + tid];
  float qe = q_emb[tid];
  float s1r = qe, s2r = qe*qe;
  for (int mm=1;mm<64;mm<<=1){ s1r += __shfl_xor(s1r,mm); s2r += __shfl_xor(s2r,mm); }
  int wv = tid>>6, ln = tid&63;
  if (ln==0){ red[wv*2]=s1r; red[wv*2+1]=s2r; }
  __syncthreads();
  float S1 = red[0]+red[2]+red[4]+red[6];
  float S2 = red[1]+red[3]+red[5]+red[7];
  float mean = S1*(1.0f/256.0f);
  float var  = S2*(1.0f/256.0f) - mean*mean;
  float rs   = rsqrtf(var + EPSV);
  qn[tid] = (qe-mean)*rs*(1.0f+sq_t) + shq_t;
  __syncthreads();

  {
    const int t = tid & 63, ks = tid >> 6;
    float p = 0.f;
    const float* wq = Wq + (size_t)(ks*64)*256 + h*64 + t;
    #pragma unroll 8
    for (int d=0; d<64; ++d) p = fmaf(qn[ks*64+d], wq[d*256], p);
    ph[tid] = p;
  }
  __syncthreads();
  if (tid < 64) qh64[tid] = ph[tid] + ph[64+tid] + ph[128+tid] + ph[192+tid];
  __syncthreads();

  {
    float a = 0.f;
    const float* wkr = Wk + (size_t)tid*256 + h*64;
    #pragma unroll
    for (int e4=0; e4<16; ++e4){
      f4 wv4 = *(const f4*)(wkr + e4*4);
      a = fmaf(qh64[e4*4+0], wv4.x, a);
      a = fmaf(qh64[e4*4+1], wv4.y, a);
      a = fmaf(qh64[e4*4+2], wv4.z, a);
      a = fmaf(qh64[e4*4+3], wv4.w, a);
    }
    ws[WS_A + b*1024 + h*256 + tid] = 0.125f*a;
  }
}

// ------------------------------------------------------------------
// K1F: fully fused attention middle. grid=512 (8 tokens), block=256.
// thread = (t = tid>>5 in 0..7, dg = tid&31) owning d-set
// {dA=4dg..+3} U {dB=128+4dg..+3}  (round-2-verified convention).
// Per f: stage W_f (double-buffered LDS via verified scalar transpose,
// ONE barrier per f), val = x@W, LN via 32-lane butterfly, kvl affine,
// logits via shfl allreduce, p = exp(lg) (no max: |lg| std ~0.13),
// l[h] += p, racc[h][:] += p*kvl.  End: r = racc / l  -> WS_R.
// ------------------------------------------------------------------
__global__ __launch_bounds__(256) void k1f_attn(
  const float* __restrict__ x, const int* __restrict__ idx,
  const float* __restrict__ Wp, const float* __restrict__ Bp,
  float* __restrict__ ws)
{
  __shared__ float xs[2048];       // [t][256]
  __shared__ float wls[2][2048];   // dbuf [i][d]
  __shared__ float As[1024];       // [h][d]

  const int tid = threadIdx.x;
  const int p0  = blockIdx.x * 8;
  const int b   = p0 >> 10;
  const int t   = tid >> 5;
  const int dg  = tid & 31;
  const int dA  = 4*dg, dB = 128 + 4*dg;

  // stage xs: thread loads x[p0*256 + tid*8 .. +8) -> xs[t][dg*8..]
  {
    const float* xg = x + (size_t)p0*256 + tid*8;
    f4 a  = *(const f4*)xg;
    f4 bq = *(const f4*)(xg + 4);
    *(f4*)&xs[tid*8]     = a;
    *(f4*)&xs[tid*8 + 4] = bq;
  }
  // stage As (plain layout)
  *(f4*)&As[tid*4] = *(const f4*)(ws + WS_A + b*1024 + tid*4);

  // coef/shk for this thread's d-set
  f4 skA = *(const f4*)(ws + WS_SKV  + b*256 + dA);
  f4 skB = *(const f4*)(ws + WS_SKV  + b*256 + dB);
  f4 shA = *(const f4*)(ws + WS_SHKV + b*256 + dA);
  f4 shB = *(const f4*)(ws + WS_SHKV + b*256 + dB);
  float coef[8] = {1.f+skA.x,1.f+skA.y,1.f+skA.z,1.f+skA.w,
                   1.f+skB.x,1.f+skB.y,1.f+skB.z,1.f+skB.w};
  float shk[8]  = {shA.x,shA.y,shA.z,shA.w, shB.x,shB.y,shB.z,shB.w};

  // W prefetch: thread owns w[d=tid][i=0..7] = Wp_row[tid*8 .. +8)
  int row = idx[0];
  f4 u0, u1;
  {
    const float* wp0 = Wp + (size_t)row*2048 + tid*8;
    u0 = *(const f4*)wp0;
    u1 = *(const f4*)(wp0 + 4);
  }

  float l[4] = {0.f,0.f,0.f,0.f};
  float racc[4][8] = {};

  for (int f = 0; f < 32; ++f){
    // transpose-write staged W into buffer f&1 (verified pattern)
    {
      float* wb = wls[f&1];
      wb[0*256+tid]=u0.x; wb[1*256+tid]=u0.y; wb[2*256+tid]=u0.z; wb[3*256+tid]=u0.w;
      wb[4*256+tid]=u1.x; wb[5*256+tid]=u1.y; wb[6*256+tid]=u1.z; wb[7*256+tid]=u1.w;
    }
    // bias for current f (this thread's d-set)
    f4 ba = *(const f4*)(Bp + (size_t)row*256 + dA);
    f4 bb = *(const f4*)(Bp + (size_t)row*256 + dB);
    // next row
    int rown = idx[f < 31 ? f+1 : 31];
    const float* wpn = Wp + (size_t)rown*2048 + tid*8;
    row = rown;
    __syncthreads();
    // issue next-W loads (land during compute)
    u0 = *(const f4*)wpn;
    u1 = *(const f4*)(wpn + 4);

    // x fragment (all dg lanes of token t read same addr -> broadcast)
    f4 xa = *(const f4*)&xs[t*256 + f*8];
    f4 xb = *(const f4*)&xs[t*256 + f*8 + 4];
    float xf[8] = {xa.x,xa.y,xa.z,xa.w, xb.x,xb.y,xb.z,xb.w};

    // val = x @ W for this thread's d-set
    float val[8] = {};
    const float* wrow = wls[f&1];
    #pragma unroll
    for (int i=0;i<8;++i){
      f4 wa = *(const f4*)&wrow[i*256 + dA];
      f4 wbv = *(const f4*)&wrow[i*256 + dB];
      FMA8(val, xf[i], wa, wbv);
    }

    // LN across the 32 dg lanes of token t
    float s=0.f, ss=0.f;
    #pragma unroll
    for (int jj=0;jj<8;++jj){ s += val[jj]; ss = fmaf(val[jj],val[jj],ss); }
    s = bfly32(s); ss = bfly32(ss);
    float mean = s*(1.f/256.f);
    float var  = ss*(1.f/256.f) - mean*mean;
    float rsg  = rsqrtf(var + EPSV);
    float mrs  = mean*rsg;

    float off[8] = {shk[0]+ba.x, shk[1]+ba.y, shk[2]+ba.z, shk[3]+ba.w,
                    shk[4]+bb.x, shk[5]+bb.y, shk[6]+bb.z, shk[7]+bb.w};
    float kvl[8];
    #pragma unroll
    for (int jj=0;jj<8;++jj)
      kvl[jj] = fmaf(fmaf(val[jj], rsg, -mrs), coef[jj], off[jj]);

    // logits + exp + accumulate
    #pragma unroll
    for (int h=0;h<4;++h){
      f4 Aa = *(const f4*)&As[h*256 + dA];
      f4 Ab = *(const f4*)&As[h*256 + dB];
      float lg = 0.f;
      DOT8(lg, kvl, Aa, Ab);
      lg = bfly32(lg);                 // allreduce: every lane gets full logit
      float pp = __expf(lg);
      l[h] += pp;
      #pragma unroll
      for (int jj=0;jj<8;++jj)
        racc[h][jj] = fmaf(pp, kvl[jj], racc[h][jj]);
    }
  }

  // normalize and write r
  float* rp = ws + WS_R + (size_t)(p0+t)*1024;
  #pragma unroll
  for (int h=0;h<4;++h){
    float inv = 1.f / l[h];
    *(f4*)&rp[h*256 + dA] = make_float4(racc[h][0]*inv, racc[h][1]*inv,
                                        racc[h][2]*inv, racc[h][3]*inv);
    *(f4*)&rp[h*256 + dB] = make_float4(racc[h][4]*inv, racc[h][5]*inv,
                                        racc[h][6]*inv, racc[h][7]*inv);
  }
}

// ------------------------------------------------------------------
// K2: o = r @ Wv(head), o2 = o @ Wo, htok = q_emb+o2, hn = CLN(htok)
// grid=512 (8 tokens each), block=256 (tq=tid>>5 in 0..7, jq=tid&31)
// ------------------------------------------------------------------
__global__ __launch_bounds__(256) void k2_ovo(
  const float* __restrict__ Wv, const float* __restrict__ Wo,
  const float* __restrict__ q_emb, float* __restrict__ ws)
{
  __shared__ float rl[8320];   // r tile padded [t]*1040 + [h]*260 + d ; reused for o
  const int tid = threadIdx.x;
  const int p0  = blockIdx.x * 8;
  const int b   = p0 >> 10;
  const int tq  = tid >> 5;
  const int jq  = tid & 31;
  const int c0  = jq*8;

  #pragma unroll
  for (int k=0;k<8;++k){
    int flat = k*1024 + tid*4;
    f4 v = *(const f4*)(ws + WS_R + (size_t)p0*1024 + flat);
    int t = flat>>10, rem = flat&1023;
    int hh2 = rem>>8, d = rem&255;
    *(f4*)&rl[t*1040 + hh2*260 + d] = v;
  }
  __syncthreads();

  const int hh = jq >> 3;
  float oa[8] = {};
  {
    const float* rrow = &rl[tq*1040 + hh*260];
    for (int d4=0; d4<64; ++d4){
      const int d = d4*4;
      f4 rt = *(const f4*)&rrow[d];
      float rcv[4] = {rt.x, rt.y, rt.z, rt.w};
      #pragma unroll
      for (int dd=0; dd<4; ++dd){
        f4 w0 = *(const f4*)(Wv + (size_t)(d+dd)*256 + c0);
        f4 w1 = *(const f4*)(Wv + (size_t)(d+dd)*256 + c0 + 4);
        FMA8(oa, rcv[dd], w0, w1);
      }
    }
  }
  __syncthreads();
  *(f4*)&rl[tq*256 + c0]     = make_float4(oa[0],oa[1],oa[2],oa[3]);
  *(f4*)&rl[tq*256 + c0 + 4] = make_float4(oa[4],oa[5],oa[6],oa[7]);
  __syncthreads();

  float ob[8] = {};
  {
    const float* orow = &rl[tq*256];
    for (int c4=0;c4<64;++c4){
      const int cc = c4*4;
      f4 ot = *(const f4*)&orow[cc];
      float ocv[4] = {ot.x, ot.y, ot.z, ot.w};
      #pragma unroll
      for (int dd=0;dd<4;++dd){
        f4 w0 = *(const f4*)(Wo + (size_t)(cc+dd)*256 + c0);
        f4 w1 = *(const f4*)(Wo + (size_t)(cc+dd)*256 + c0 + 4);
        FMA8(ob, ocv[dd], w0, w1);
      }
    }
  }
  f4 q0 = *(const f4*)(q_emb + c0);
  f4 q1 = *(const f4*)(q_emb + c0 + 4);
  float ht[8] = {ob[0]+q0.x, ob[1]+q0.y, ob[2]+q0.z, ob[3]+q0.w,
                 ob[4]+q1.x, ob[5]+q1.y, ob[6]+q1.z, ob[7]+q1.w};
  float s=0.f, ss=0.f;
  #pragma unroll
  for (int jj=0;jj<8;++jj){ s += ht[jj]; ss = fmaf(ht[jj],ht[jj],ss); }
  s = bfly32(s); ss = bfly32(ss);
  float mean = s*(1.f/256.f);
  float var  = ss*(1.f/256.f) - mean*mean;
  float rsg  = rsqrtf(var + EPSV);
  f4 sH0 = *(const f4*)(ws + WS_SH  + b*256 + c0);
  f4 sH1 = *(const f4*)(ws + WS_SH  + b*256 + c0 + 4);
  f4 hH0 = *(const f4*)(ws + WS_SHH + b*256 + c0);
  f4 hH1 = *(const f4*)(ws + WS_SHH + b*256 + c0 + 4);
  float sHv[8]  = {sH0.x,sH0.y,sH0.z,sH0.w, sH1.x,sH1.y,sH1.z,sH1.w};
  float hHv[8]  = {hH0.x,hH0.y,hH0.z,hH0.w, hH1.x,hH1.y,hH1.z,hH1.w};
  float hnv[8];
  #pragma unroll
  for (int jj=0;jj<8;++jj)
    hnv[jj] = (ht[jj]-mean)*rsg*(1.f+sHv[jj]) + hHv[jj];

  float* htp = ws + WS_HT + (size_t)(p0+tq)*256 + c0;
  float* hnp = ws + WS_HN + (size_t)(p0+tq)*256 + c0;
  *(f4*)htp     = make_float4(ht[0],ht[1],ht[2],ht[3]);
  *(f4*)(htp+4) = make_float4(ht[4],ht[5],ht[6],ht[7]);
  *(f4*)hnp     = make_float4(hnv[0],hnv[1],hnv[2],hnv[3]);
  *(f4*)(hnp+4) = make_float4(hnv[4],hnv[5],hnv[6],hnv[7]);
}

// ------------------------------------------------------------------
// K3: g = gelu(hn @ W1 + b1). grid = 256 token-tiles x 4 m-tiles.
// block=256 (tq=tid>>5 in 0..7 -> tokens {tq,tq+8}; mg=tid&31)
// ------------------------------------------------------------------
__global__ __launch_bounds__(256) void k3_ffn1(
  const float* __restrict__ W1, const float* __restrict__ b1,
  float* __restrict__ ws)
{
  __shared__ float hl[4096];
  const int tid = threadIdx.x;
  const int tb  = blockIdx.x >> 2;
  const int m0  = (blockIdx.x & 3) * 256;
  const int p0  = tb * 16;
  #pragma unroll
  for (int k=0;k<4;++k)
    *(f4*)&hl[(k*256+tid)*4] = *(const f4*)(ws + WS_HN + (size_t)p0*256 + (k*256+tid)*4);
  __syncthreads();
  const int tq = tid>>5, mg = tid&31;
  const int m  = m0 + mg*8;
  float ga[2][8] = {};
  for (int j4=0;j4<64;++j4){
    const int j = j4*4;
    f4 h0 = *(const f4*)&hl[tq*256 + j];
    f4 h1 = *(const f4*)&hl[(tq+8)*256 + j];
    float a0[4] = {h0.x,h0.y,h0.z,h0.w};
    float a1[4] = {h1.x,h1.y,h1.z,h1.w};
    #pragma unroll
    for (int dd=0;dd<4;++dd){
      f4 w0 = *(const f4*)(W1 + (size_t)(j+dd)*1024 + m);
      f4 w1 = *(const f4*)(W1 + (size_t)(j+dd)*1024 + m + 4);
      FMA8(ga[0], a0[dd], w0, w1);
      FMA8(ga[1], a1[dd], w0, w1);
    }
  }
  f4 bb0 = *(const f4*)(b1+m);
  f4 bb1 = *(const f4*)(b1+m+4);
  float bv[8] = {bb0.x,bb0.y,bb0.z,bb0.w, bb1.x,bb1.y,bb1.z,bb1.w};
  #pragma unroll
  for (int tt=0;tt<2;++tt){
    int t = tq + tt*8;
    float* gp = ws + WS_G + (size_t)(p0+t)*1024 + m;
    float o[8];
    #pragma unroll
    for (int jj=0;jj<8;++jj) o[jj] = gelu_tanh(ga[tt][jj]+bv[jj]);
    *(f4*)gp     = make_float4(o[0],o[1],o[2],o[3]);
    *(f4*)(gp+4) = make_float4(o[4],o[5],o[6],o[7]);
  }
}

// ------------------------------------------------------------------
// K4: out = htok + g @ W2 + b2.
// grid = 512 = 256 token-tiles(16) x 2 col-halves(128), block=256
// ------------------------------------------------------------------
__global__ __launch_bounds__(256) void k4_ffn2(
  const float* __restrict__ W2, const float* __restrict__ b2,
  const float* __restrict__ ws, float* __restrict__ out)
{
  __shared__ float gl[16384];   // [16 t][1024 m]
  const int tid = threadIdx.x;
  const int tb  = blockIdx.x >> 1;
  const int n0  = (blockIdx.x & 1) * 128;
  const int p0  = tb * 16;
  #pragma unroll
  for (int k=0;k<16;++k){
    int flat = k*1024 + tid*4;
    *(f4*)&gl[flat] = *(const f4*)(ws + WS_G + (size_t)p0*1024 + flat);
  }
  __syncthreads();
  const int tq = tid>>5, mg = tid&31;
  const int col = n0 + mg*4;
  float acc[2][4] = {};
  for (int k4=0;k4<256;++k4){
    const int k = k4*4;
    f4 g0 = *(const f4*)&gl[tq*1024 + k];
    f4 g1 = *(const f4*)&gl[(tq+8)*1024 + k];
    float gv0[4] = {g0.x,g0.y,g0.z,g0.w};
    float gv1[4] = {g1.x,g1.y,g1.z,g1.w};
    #pragma unroll
    for (int dd=0;dd<4;++dd){
      f4 w = *(const f4*)(W2 + (size_t)(k+dd)*256 + col);
      acc[0][0]=fmaf(gv0[dd],w.x,acc[0][0]); acc[0][1]=fmaf(gv0[dd],w.y,acc[0][1]);
      acc[0][2]=fmaf(gv0[dd],w.z,acc[0][2]); acc[0][3]=fmaf(gv0[dd],w.w,acc[0][3]);
      acc[1][0]=fmaf(gv1[dd],w.x,acc[1][0]); acc[1][1]=fmaf(gv1[dd],w.y,acc[1][1]);
      acc[1][2]=fmaf(gv1[dd],w.z,acc[1][2]); acc[1][3]=fmaf(gv1[dd],w.w,acc[1][3]);
    }
  }
  f4 bb = *(const f4*)(b2 + col);
  #pragma unroll
  for (int tt=0;tt<2;++tt){
    int t = tq + tt*8;
    f4 h0 = *(const f4*)(ws + WS_HT + (size_t)(p0+t)*256 + col);
    *(f4*)(out + (size_t)(p0+t)*256 + col) =
      make_float4(acc[tt][0]+h0.x+bb.x, acc[tt][1]+h0.y+bb.y,
                  acc[tt][2]+h0.z+bb.z, acc[tt][3]+h0.w+bb.w);
  }
}

// ------------------------------------------------------------------
extern "C" void kernel_launch(void* const* d_in, const int* in_sizes, int n_in,
                              void* d_out, int out_size, void* d_ws, size_t ws_size,
                              hipStream_t stream)
{
  const float* x    = (const float*)d_in[0];
  const int*   idx  = (const int*)  d_in[1];
  const float* ctx  = (const float*)d_in[2];
  const float* Wp   = (const float*)d_in[3];
  const float* Bp   = (const float*)d_in[4];
  const float* qemb = (const float*)d_in[5];
  const float* Wkv  = (const float*)d_in[6];
  const float* bkv  = (const float*)d_in[7];
  const float* Wqc  = (const float*)d_in[8];
  const float* bqc  = (const float*)d_in[9];
  const float* Whc  = (const float*)d_in[10];
  const float* bhc  = (const float*)d_in[11];
  const float* Wq   = (const float*)d_in[12];
  const float* Wk   = (const float*)d_in[13];
  const float* Wv   = (const float*)d_in[14];
  const float* Wo   = (const float*)d_in[15];
  const float* W1   = (const float*)d_in[16];
  const float* b1   = (const float*)d_in[17];
  const float* W2   = (const float*)d_in[18];
  const float* b2   = (const float*)d_in[19];
  float* ws  = (float*)d_ws;
  float* out = (float*)d_out;

  hipLaunchKernelGGL(k0a_proj,   dim3(12),   dim3(512), 0, stream,
                     ctx, Wkv, bkv, Wqc, bqc, Whc, bhc, ws);
  hipLaunchKernelGGL(k0b_qa,     dim3(16),   dim3(256), 0, stream, qemb, Wq, Wk, ws);
  hipLaunchKernelGGL(k1f_attn,   dim3(512),  dim3(256), 0, stream, x, idx, Wp, Bp, ws);
  hipLaunchKernelGGL(k2_ovo,     dim3(512),  dim3(256), 0, stream, Wv, Wo, qemb, ws);
  hipLaunchKernelGGL(k3_ffn1,    dim3(1024), dim3(256), 0, stream, W1, b1, ws);
  hipLaunchKernelGGL(k4_ffn2,    dim3(512),  dim3(256), 0, stream, W2, b2, ws, out);
}

// Round 5
// 341.675 us; speedup vs baseline: 1.5907x; 1.0053x over previous
//
#include <hip/hip_runtime.h>
#include <cmath>

#define EPSV 1e-5f
using f4 = float4;

// ---- ws layout (float offsets) ----
#define WS_SKV   0           // [4][256]
#define WS_SHKV  1024        // [4][256]
#define WS_SH    2048        // [4][256]  s_h
#define WS_SHH   3072        // [4][256]  sh_h
#define WS_A     4096        // [4][4][256] (b,h,d), includes 1/sqrt(64)
#define WS_R     8192        // [4096][4][256]
#define WS_HT    4202496     // [4096][256]
#define WS_HN    5251072     // [4096][256]
#define WS_G     6299648     // [4096][1024]

#define FMA8(acc, s, wa, wb) \
  acc[0]=fmaf((s),(wa).x,acc[0]); acc[1]=fmaf((s),(wa).y,acc[1]); \
  acc[2]=fmaf((s),(wa).z,acc[2]); acc[3]=fmaf((s),(wa).w,acc[3]); \
  acc[4]=fmaf((s),(wb).x,acc[4]); acc[5]=fmaf((s),(wb).y,acc[5]); \
  acc[6]=fmaf((s),(wb).z,acc[6]); acc[7]=fmaf((s),(wb).w,acc[7]);

#define FMA4(acc, s, wa) \
  acc[0]=fmaf((s),(wa).x,acc[0]); acc[1]=fmaf((s),(wa).y,acc[1]); \
  acc[2]=fmaf((s),(wa).z,acc[2]); acc[3]=fmaf((s),(wa).w,acc[3]);

#define DOT8(res, v, wa, wb) \
  res = fmaf((v)[0],(wa).x,res); res = fmaf((v)[1],(wa).y,res); \
  res = fmaf((v)[2],(wa).z,res); res = fmaf((v)[3],(wa).w,res); \
  res = fmaf((v)[4],(wb).x,res); res = fmaf((v)[5],(wb).y,res); \
  res = fmaf((v)[6],(wb).z,res); res = fmaf((v)[7],(wb).w,res);

__device__ __forceinline__ float bfly32(float v){
  v += __shfl_xor(v, 1);  v += __shfl_xor(v, 2);  v += __shfl_xor(v, 4);
  v += __shfl_xor(v, 8);  v += __shfl_xor(v, 16);
  return v;
}

__device__ __forceinline__ float gelu_tanh(float x){
  float inner = 0.7978845608028654f*(x + 0.044715f*x*x*x);
  return 0.5f*x*(1.0f + tanhf(inner));
}

// ------------------------------------------------------------------
// K0: merged per-(b,h) setup. grid=16 (b*4+h), block=256.
// Each block recomputes the three ctx projections locally (cheap
// 64-K dots); only h==0 writes the shared scale/shift vectors.
// Then qn, qh slice, A[h][:] exactly as the verified k0b.
// ------------------------------------------------------------------
__global__ __launch_bounds__(256) void k0_all(
    const float* __restrict__ ctx, const float* __restrict__ q_emb,
    const float* __restrict__ Wkv, const float* __restrict__ bkv,
    const float* __restrict__ Wqc, const float* __restrict__ bqc,
    const float* __restrict__ Whc, const float* __restrict__ bhc,
    const float* __restrict__ Wq,  const float* __restrict__ Wk,
    float* __restrict__ ws)
{
  const int b = blockIdx.x >> 2, h = blockIdx.x & 3;
  const int tid = threadIdx.x;
  __shared__ float c[64], qn[256], ph[256], qh64[64], red[8];
  if (tid < 64) c[tid] = ctx[b*64 + tid];
  __syncthreads();

  float skv = bkv[tid],      shkv = bkv[256+tid];
  float sq  = bqc[tid],      shq  = bqc[256+tid];
  float sh  = bhc[tid],      shh  = bhc[256+tid];
  #pragma unroll 8
  for (int j=0;j<64;++j){
    float cj = c[j];
    skv  = fmaf(cj, Wkv[j*512 + tid],       skv);
    shkv = fmaf(cj, Wkv[j*512 + 256 + tid], shkv);
    sq   = fmaf(cj, Wqc[j*512 + tid],       sq);
    shq  = fmaf(cj, Wqc[j*512 + 256 + tid], shq);
    sh   = fmaf(cj, Whc[j*512 + tid],       sh);
    shh  = fmaf(cj, Whc[j*512 + 256 + tid], shh);
  }
  if (h == 0){
    ws[WS_SKV  + b*256 + tid] = skv;
    ws[WS_SHKV + b*256 + tid] = shkv;
    ws[WS_SH   + b*256 + tid] = sh;
    ws[WS_SHH  + b*256 + tid] = shh;
  }

  // qn = LN(q_emb)*(1+sq)+shq
  float qe = q_emb[tid];
  float s1r = qe, s2r = qe*qe;
  for (int mm=1;mm<64;mm<<=1){ s1r += __shfl_xor(s1r,mm); s2r += __shfl_xor(s2r,mm); }
  int wv = tid>>6, ln = tid&63;
  if (ln==0){ red[wv*2]=s1r; red[wv*2+1]=s2r; }
  __syncthreads();
  float S1 = red[0]+red[2]+red[4]+red[6];
  float S2 = red[1]+red[3]+red[5]+red[7];
  float mean = S1*(1.0f/256.0f);
  float var  = S2*(1.0f/256.0f) - mean*mean;
  float rs   = rsqrtf(var + EPSV);
  qn[tid] = (qe-mean)*rs*(1.0f+sq) + shq;
  __syncthreads();

  { // qh slice for head h, K-split 4-way
    const int t = tid & 63, ks = tid >> 6;
    float p = 0.f;
    const float* wq = Wq + (size_t)(ks*64)*256 + h*64 + t;
    #pragma unroll 8
    for (int d=0; d<64; ++d) p = fmaf(qn[ks*64+d], wq[d*256], p);
    ph[tid] = p;
  }
  __syncthreads();
  if (tid < 64) qh64[tid] = ph[tid] + ph[64+tid] + ph[128+tid] + ph[192+tid];
  __syncthreads();

  { // A[h][d] = 0.125 * sum_e qh64[e]*Wk[d*256 + h*64 + e]
    float a = 0.f;
    const float* wkr = Wk + (size_t)tid*256 + h*64;
    #pragma unroll
    for (int e4=0; e4<16; ++e4){
      f4 wv4 = *(const f4*)(wkr + e4*4);
      a = fmaf(qh64[e4*4+0], wv4.x, a);
      a = fmaf(qh64[e4*4+1], wv4.y, a);
      a = fmaf(qh64[e4*4+2], wv4.z, a);
      a = fmaf(qh64[e4*4+3], wv4.w, a);
    }
    ws[WS_A + b*1024 + h*256 + tid] = 0.125f*a;
  }
}

// ------------------------------------------------------------------
// K1F: fused attention middle (round-4 verified, unchanged).
// grid=512 (8 tokens), block=256.
// ------------------------------------------------------------------
__global__ __launch_bounds__(256) void k1f_attn(
  const float* __restrict__ x, const int* __restrict__ idx,
  const float* __restrict__ Wp, const float* __restrict__ Bp,
  float* __restrict__ ws)
{
  __shared__ float xs[2048];       // [t][256]
  __shared__ float wls[2][2048];   // dbuf [i][d]
  __shared__ float As[1024];       // [h][d]

  const int tid = threadIdx.x;
  const int p0  = blockIdx.x * 8;
  const int b   = p0 >> 10;
  const int t   = tid >> 5;
  const int dg  = tid & 31;
  const int dA  = 4*dg, dB = 128 + 4*dg;

  {
    const float* xg = x + (size_t)p0*256 + tid*8;
    f4 a  = *(const f4*)xg;
    f4 bq = *(const f4*)(xg + 4);
    *(f4*)&xs[tid*8]     = a;
    *(f4*)&xs[tid*8 + 4] = bq;
  }
  *(f4*)&As[tid*4] = *(const f4*)(ws + WS_A + b*1024 + tid*4);

  f4 skA = *(const f4*)(ws + WS_SKV  + b*256 + dA);
  f4 skB = *(const f4*)(ws + WS_SKV  + b*256 + dB);
  f4 shA = *(const f4*)(ws + WS_SHKV + b*256 + dA);
  f4 shB = *(const f4*)(ws + WS_SHKV + b*256 + dB);
  float coef[8] = {1.f+skA.x,1.f+skA.y,1.f+skA.z,1.f+skA.w,
                   1.f+skB.x,1.f+skB.y,1.f+skB.z,1.f+skB.w};
  float shk[8]  = {shA.x,shA.y,shA.z,shA.w, shB.x,shB.y,shB.z,shB.w};

  int row = idx[0];
  f4 u0, u1;
  {
    const float* wp0 = Wp + (size_t)row*2048 + tid*8;
    u0 = *(const f4*)wp0;
    u1 = *(const f4*)(wp0 + 4);
  }

  float l[4] = {0.f,0.f,0.f,0.f};
  float racc[4][8] = {};

  for (int f = 0; f < 32; ++f){
    {
      float* wb = wls[f&1];
      wb[0*256+tid]=u0.x; wb[1*256+tid]=u0.y; wb[2*256+tid]=u0.z; wb[3*256+tid]=u0.w;
      wb[4*256+tid]=u1.x; wb[5*256+tid]=u1.y; wb[6*256+tid]=u1.z; wb[7*256+tid]=u1.w;
    }
    f4 ba = *(const f4*)(Bp + (size_t)row*256 + dA);
    f4 bb = *(const f4*)(Bp + (size_t)row*256 + dB);
    int rown = idx[f < 31 ? f+1 : 31];
    const float* wpn = Wp + (size_t)rown*2048 + tid*8;
    row = rown;
    __syncthreads();
    u0 = *(const f4*)wpn;
    u1 = *(const f4*)(wpn + 4);

    f4 xa = *(const f4*)&xs[t*256 + f*8];
    f4 xb = *(const f4*)&xs[t*256 + f*8 + 4];
    float xf[8] = {xa.x,xa.y,xa.z,xa.w, xb.x,xb.y,xb.z,xb.w};

    float val[8] = {};
    const float* wrow = wls[f&1];
    #pragma unroll
    for (int i=0;i<8;++i){
      f4 wa = *(const f4*)&wrow[i*256 + dA];
      f4 wbv = *(const f4*)&wrow[i*256 + dB];
      FMA8(val, xf[i], wa, wbv);
    }

    float s=0.f, ss=0.f;
    #pragma unroll
    for (int jj=0;jj<8;++jj){ s += val[jj]; ss = fmaf(val[jj],val[jj],ss); }
    s = bfly32(s); ss = bfly32(ss);
    float mean = s*(1.f/256.f);
    float var  = ss*(1.f/256.f) - mean*mean;
    float rsg  = rsqrtf(var + EPSV);
    float mrs  = mean*rsg;

    float off[8] = {shk[0]+ba.x, shk[1]+ba.y, shk[2]+ba.z, shk[3]+ba.w,
                    shk[4]+bb.x, shk[5]+bb.y, shk[6]+bb.z, shk[7]+bb.w};
    float kvl[8];
    #pragma unroll
    for (int jj=0;jj<8;++jj)
      kvl[jj] = fmaf(fmaf(val[jj], rsg, -mrs), coef[jj], off[jj]);

    #pragma unroll
    for (int h=0;h<4;++h){
      f4 Aa = *(const f4*)&As[h*256 + dA];
      f4 Ab = *(const f4*)&As[h*256 + dB];
      float lg = 0.f;
      DOT8(lg, kvl, Aa, Ab);
      lg = bfly32(lg);
      float pp = __expf(lg);
      l[h] += pp;
      #pragma unroll
      for (int jj=0;jj<8;++jj)
        racc[h][jj] = fmaf(pp, kvl[jj], racc[h][jj]);
    }
  }

  float* rp = ws + WS_R + (size_t)(p0+t)*1024;
  #pragma unroll
  for (int h=0;h<4;++h){
    float inv = 1.f / l[h];
    *(f4*)&rp[h*256 + dA] = make_float4(racc[h][0]*inv, racc[h][1]*inv,
                                        racc[h][2]*inv, racc[h][3]*inv);
    *(f4*)&rp[h*256 + dB] = make_float4(racc[h][4]*inv, racc[h][5]*inv,
                                        racc[h][6]*inv, racc[h][7]*inv);
  }
}

// ------------------------------------------------------------------
// K2 v2: o = r@Wv(head-block), o2 = o@Wo, htok = q_emb+o2, hn = CLN.
// grid=512 (8 tokens), block=256. tq=tid>>5 -> token tq; jq=tid&31 ->
// cols cA=4jq (head jq>>4), cB=128+4jq (head 2+(jq>>4)).
// Wv/Wo staged through one 8-row x 256-col LDS dbuf (k1f pattern):
// per-block weight traffic 512KB (was 4MB).
// ------------------------------------------------------------------
__global__ __launch_bounds__(256) void k2_ovo(
  const float* __restrict__ Wv, const float* __restrict__ Wo,
  const float* __restrict__ q_emb, float* __restrict__ ws)
{
  __shared__ float rl[8192];      // [8 t][4 h][256 d] plain (broadcast reads)
  __shared__ float ot[2048];      // [8 t][256] o tile
  __shared__ float wt[2][2048];   // dbuf [8 rows][256 cols]

  const int tid = threadIdx.x;
  const int p0  = blockIdx.x * 8;
  const int b   = p0 >> 10;
  const int tq  = tid >> 5;
  const int jq  = tid & 31;
  const int cA  = 4*jq, cB = 128 + 4*jq;
  const int hA  = jq >> 4, hB = 2 + (jq >> 4);

  // stage r tile (coalesced, plain layout)
  #pragma unroll
  for (int i=0;i<8;++i){
    int off = i*1024 + tid*4;
    *(f4*)&rl[off] = *(const f4*)(ws + WS_R + (size_t)p0*1024 + off);
  }

  const int q0 = tid, q1 = tid + 256;   // staged f4 indices (row=q>>6, col4=q&63)
  f4 uw0, uw1;
  uw0 = *(const f4*)(Wv + (size_t)(q0>>6)*256 + (q0&63)*4);
  uw1 = *(const f4*)(Wv + (size_t)(q1>>6)*256 + (q1&63)*4);

  // ---------- phase A: o = r @ Wv ----------
  float oa[8] = {};
  for (int c=0; c<32; ++c){
    float* wb = wt[c&1];
    *(f4*)&wb[(q0>>6)*256 + (q0&63)*4] = uw0;
    *(f4*)&wb[(q1>>6)*256 + (q1&63)*4] = uw1;
    __syncthreads();
    int cn = (c < 31) ? c+1 : 31;
    uw0 = *(const f4*)(Wv + (size_t)(cn*8 + (q0>>6))*256 + (q0&63)*4);
    uw1 = *(const f4*)(Wv + (size_t)(cn*8 + (q1>>6))*256 + (q1&63)*4);
    const float* wrow = wt[c&1];
    #pragma unroll
    for (int dd=0; dd<8; ++dd){
      int d = c*8 + dd;
      float rA = rl[tq*1024 + hA*256 + d];
      float rB = rl[tq*1024 + hB*256 + d];
      f4 w0 = *(const f4*)&wrow[dd*256 + cA];
      f4 w1 = *(const f4*)&wrow[dd*256 + cB];
      FMA4(oa, rA, w0);
      float* ob4 = oa + 4;
      FMA4(ob4, rB, w1);
    }
  }
  *(f4*)&ot[tq*256 + cA] = make_float4(oa[0],oa[1],oa[2],oa[3]);
  *(f4*)&ot[tq*256 + cB] = make_float4(oa[4],oa[5],oa[6],oa[7]);
  uw0 = *(const f4*)(Wo + (size_t)(q0>>6)*256 + (q0&63)*4);
  uw1 = *(const f4*)(Wo + (size_t)(q1>>6)*256 + (q1&63)*4);
  __syncthreads();   // ot complete + phase A compute done

  // ---------- phase B: o2 = o @ Wo ----------
  float ob[8] = {};
  for (int c=0; c<32; ++c){
    float* wb = wt[c&1];
    *(f4*)&wb[(q0>>6)*256 + (q0&63)*4] = uw0;
    *(f4*)&wb[(q1>>6)*256 + (q1&63)*4] = uw1;
    __syncthreads();
    int cn = (c < 31) ? c+1 : 31;
    uw0 = *(const f4*)(Wo + (size_t)(cn*8 + (q0>>6))*256 + (q0&63)*4);
    uw1 = *(const f4*)(Wo + (size_t)(cn*8 + (q1>>6))*256 + (q1&63)*4);
    const float* wrow = wt[c&1];
    #pragma unroll
    for (int dd=0; dd<8; ++dd){
      int cc = c*8 + dd;
      float a = ot[tq*256 + cc];
      f4 w0 = *(const f4*)&wrow[dd*256 + cA];
      f4 w1 = *(const f4*)&wrow[dd*256 + cB];
      FMA8(ob, a, w0, w1);
    }
  }

  // ---------- epilogue: residual + CLN ----------
  f4 qA = *(const f4*)(q_emb + cA);
  f4 qB = *(const f4*)(q_emb + cB);
  float ht[8] = {ob[0]+qA.x, ob[1]+qA.y, ob[2]+qA.z, ob[3]+qA.w,
                 ob[4]+qB.x, ob[5]+qB.y, ob[6]+qB.z, ob[7]+qB.w};
  float s=0.f, ss=0.f;
  #pragma unroll
  for (int jj=0;jj<8;++jj){ s += ht[jj]; ss = fmaf(ht[jj],ht[jj],ss); }
  s = bfly32(s); ss = bfly32(ss);
  float mean = s*(1.f/256.f);
  float var  = ss*(1.f/256.f) - mean*mean;
  float rsg  = rsqrtf(var + EPSV);
  f4 sH0 = *(const f4*)(ws + WS_SH  + b*256 + cA);
  f4 sH1 = *(const f4*)(ws + WS_SH  + b*256 + cB);
  f4 hH0 = *(const f4*)(ws + WS_SHH + b*256 + cA);
  f4 hH1 = *(const f4*)(ws + WS_SHH + b*256 + cB);
  float sHv[8]  = {sH0.x,sH0.y,sH0.z,sH0.w, sH1.x,sH1.y,sH1.z,sH1.w};
  float hHv[8]  = {hH0.x,hH0.y,hH0.z,hH0.w, hH1.x,hH1.y,hH1.z,hH1.w};
  float hnv[8];
  #pragma unroll
  for (int jj=0;jj<8;++jj)
    hnv[jj] = (ht[jj]-mean)*rsg*(1.f+sHv[jj]) + hHv[jj];

  float* htp = ws + WS_HT + (size_t)(p0+tq)*256;
  float* hnp = ws + WS_HN + (size_t)(p0+tq)*256;
  *(f4*)(htp+cA) = make_float4(ht[0],ht[1],ht[2],ht[3]);
  *(f4*)(htp+cB) = make_float4(ht[4],ht[5],ht[6],ht[7]);
  *(f4*)(hnp+cA) = make_float4(hnv[0],hnv[1],hnv[2],hnv[3]);
  *(f4*)(hnp+cB) = make_float4(hnv[4],hnv[5],hnv[6],hnv[7]);
}

// ------------------------------------------------------------------
// K3 v2: g = gelu(hn @ W1 + b1).
// grid = 512 = 256 token-tiles(16) x 2 m-halves(512), block=256.
// thread: tq=tid>>5 -> tokens {tq,tq+8}; mg=tid&31 -> cols
// {m0 + 128*jj + 4mg, jj=0..3}. W1 staged in 8-row x 512-col LDS
// chunks (dbuf, k1f pattern): per-block W1 traffic 512KB (was 2MB).
// ------------------------------------------------------------------
__global__ __launch_bounds__(256) void k3_ffn1(
  const float* __restrict__ W1, const float* __restrict__ b1,
  float* __restrict__ ws)
{
  __shared__ float hl[4096];      // [16 t][256 k]
  __shared__ float wt[2][4096];   // dbuf [8 kk][512 m]

  const int tid = threadIdx.x;
  const int p0  = (blockIdx.x >> 1) * 16;
  const int m0  = (blockIdx.x & 1) * 512;
  const int tq  = tid >> 5;
  const int mg  = tid & 31;

  #pragma unroll
  for (int k=0;k<4;++k)
    *(f4*)&hl[(k*256+tid)*4] = *(const f4*)(ws + WS_HN + (size_t)p0*256 + (k*256+tid)*4);

  // staged f4 indices: q = tid + i*256, row = q>>7 (0..7), col4 = q&127
  f4 uw[4];
  #pragma unroll
  for (int i=0;i<4;++i){
    int q = tid + i*256;
    uw[i] = *(const f4*)(W1 + (size_t)(q>>7)*1024 + m0 + (q&127)*4);
  }

  float acc[2][4][4] = {};
  for (int c=0; c<32; ++c){
    float* wb = wt[c&1];
    #pragma unroll
    for (int i=0;i<4;++i){
      int q = tid + i*256;
      *(f4*)&wb[(q>>7)*512 + (q&127)*4] = uw[i];
    }
    __syncthreads();
    int cn = (c < 31) ? c+1 : 31;
    #pragma unroll
    for (int i=0;i<4;++i){
      int q = tid + i*256;
      uw[i] = *(const f4*)(W1 + (size_t)(cn*8 + (q>>7))*1024 + m0 + (q&127)*4);
    }
    const float* wrow = wt[c&1];
    #pragma unroll
    for (int kk=0; kk<8; ++kk){
      int k = c*8 + kk;
      float a0 = hl[tq*256 + k];
      float a1 = hl[(tq+8)*256 + k];
      #pragma unroll
      for (int jj=0;jj<4;++jj){
        f4 w = *(const f4*)&wrow[kk*512 + jj*128 + 4*mg];
        FMA4(acc[0][jj], a0, w);
        FMA4(acc[1][jj], a1, w);
      }
    }
  }

  #pragma unroll
  for (int jj=0;jj<4;++jj){
    const int col = m0 + jj*128 + 4*mg;
    f4 bb = *(const f4*)(b1 + col);
    #pragma unroll
    for (int tt=0;tt<2;++tt){
      int t = tq + tt*8;
      float* gp = ws + WS_G + (size_t)(p0+t)*1024 + col;
      *(f4*)gp = make_float4(gelu_tanh(acc[tt][jj][0]+bb.x),
                             gelu_tanh(acc[tt][jj][1]+bb.y),
                             gelu_tanh(acc[tt][jj][2]+bb.z),
                             gelu_tanh(acc[tt][jj][3]+bb.w));
    }
  }
}

// ------------------------------------------------------------------
// K4 v2: out = htok + g @ W2 + b2.
// grid = 512 = 256 token-tiles(16) x 2 n-halves(128), block=256.
// thread: tq=tid>>5 -> tokens {tq,tq+8}; mg=tid&31 -> cols n0+4mg.
// W2 staged in 32-row x 128-col chunks + g in 16x32 chunks (dbuf):
// per-block W2 traffic 512KB (was 4MB).
// ------------------------------------------------------------------
__global__ __launch_bounds__(256) void k4_ffn2(
  const float* __restrict__ W2, const float* __restrict__ b2,
  const float* __restrict__ ws, float* __restrict__ out)
{
  __shared__ float wt[2][4096];   // dbuf [32 kk][128 n]
  __shared__ float gt[2][512];    // dbuf [16 t][32 kk]

  const int tid = threadIdx.x;
  const int p0  = (blockIdx.x >> 1) * 16;
  const int n0  = (blockIdx.x & 1) * 128;
  const int tq  = tid >> 5;
  const int mg  = tid & 31;

  // staged f4 indices: wq = tid + i*256, row = wq>>5 (0..31), col4 = wq&31
  f4 uw[4];
  #pragma unroll
  for (int i=0;i<4;++i){
    int q = tid + i*256;
    uw[i] = *(const f4*)(W2 + (size_t)(q>>5)*256 + n0 + (q&31)*4);
  }
  f4 ug;
  if (tid < 128){
    int t = tid >> 3, i = tid & 7;
    ug = *(const f4*)(ws + WS_G + (size_t)(p0+t)*1024 + i*4);
  }

  float acc[2][4] = {};
  for (int c=0; c<32; ++c){
    float* wb = wt[c&1];
    #pragma unroll
    for (int i=0;i<4;++i){
      int q = tid + i*256;
      *(f4*)&wb[(q>>5)*128 + (q&31)*4] = uw[i];
    }
    if (tid < 128){
      int t = tid >> 3, i = tid & 7;
      *(f4*)&gt[c&1][t*32 + i*4] = ug;
    }
    __syncthreads();
    int cn = (c < 31) ? c+1 : 31;
    #pragma unroll
    for (int i=0;i<4;++i){
      int q = tid + i*256;
      uw[i] = *(const f4*)(W2 + (size_t)(cn*32 + (q>>5))*256 + n0 + (q&31)*4);
    }
    if (tid < 128){
      int t = tid >> 3, i = tid & 7;
      ug = *(const f4*)(ws + WS_G + (size_t)(p0+t)*1024 + cn*32 + i*4);
    }
    const float* wrow = wt[c&1];
    const float* grow = gt[c&1];
    #pragma unroll
    for (int kk=0; kk<32; ++kk){
      float a0 = grow[tq*32 + kk];
      float a1 = grow[(tq+8)*32 + kk];
      f4 w = *(const f4*)&wrow[kk*128 + 4*mg];
      FMA4(acc[0], a0, w);
      FMA4(acc[1], a1, w);
    }
  }

  const int col = n0 + 4*mg;
  f4 bb = *(const f4*)(b2 + col);
  #pragma unroll
  for (int tt=0;tt<2;++tt){
    int t = tq + tt*8;
    f4 h0 = *(const f4*)(ws + WS_HT + (size_t)(p0+t)*256 + col);
    *(f4*)(out + (size_t)(p0+t)*256 + col) =
      make_float4(acc[tt][0]+h0.x+bb.x, acc[tt][1]+h0.y+bb.y,
                  acc[tt][2]+h0.z+bb.z, acc[tt][3]+h0.w+bb.w);
  }
}

// ------------------------------------------------------------------
extern "C" void kernel_launch(void* const* d_in, const int* in_sizes, int n_in,
                              void* d_out, int out_size, void* d_ws, size_t ws_size,
                              hipStream_t stream)
{
  const float* x    = (const float*)d_in[0];
  const int*   idx  = (const int*)  d_in[1];
  const float* ctx  = (const float*)d_in[2];
  const float* Wp   = (const float*)d_in[3];
  const float* Bp   = (const float*)d_in[4];
  const float* qemb = (const float*)d_in[5];
  const float* Wkv  = (const float*)d_in[6];
  const float* bkv  = (const float*)d_in[7];
  const float* Wqc  = (const float*)d_in[8];
  const float* bqc  = (const float*)d_in[9];
  const float* Whc  = (const float*)d_in[10];
  const float* bhc  = (const float*)d_in[11];
  const float* Wq   = (const float*)d_in[12];
  const float* Wk   = (const float*)d_in[13];
  const float* Wv   = (const float*)d_in[14];
  const float* Wo   = (const float*)d_in[15];
  const float* W1   = (const float*)d_in[16];
  const float* b1   = (const float*)d_in[17];
  const float* W2   = (const float*)d_in[18];
  const float* b2   = (const float*)d_in[19];
  float* ws  = (float*)d_ws;
  float* out = (float*)d_out;

  hipLaunchKernelGGL(k0_all,   dim3(16),  dim3(256), 0, stream,
                     ctx, qemb, Wkv, bkv, Wqc, bqc, Whc, bhc, Wq, Wk, ws);
  hipLaunchKernelGGL(k1f_attn, dim3(512), dim3(256), 0, stream, x, idx, Wp, Bp, ws);
  hipLaunchKernelGGL(k2_ovo,   dim3(512), dim3(256), 0, stream, Wv, Wo, qemb, ws);
  hipLaunchKernelGGL(k3_ffn1,  dim3(512), dim3(256), 0, stream, W1, b1, ws);
  hipLaunchKernelGGL(k4_ffn2,  dim3(512), dim3(256), 0, stream, W2, b2, ws, out);
}

// Round 6
// 217.745 us; speedup vs baseline: 2.4960x; 1.5692x over previous
//
#include <hip/hip_runtime.h>
#include <cmath>

#define EPSV 1e-5f
using f4 = float4;

typedef __attribute__((ext_vector_type(8))) short bfrag;   // 8 bf16 (4 VGPRs)
typedef __attribute__((ext_vector_type(4))) float ffrag;   // 4 fp32 acc

// ---- ws layout (float offsets) ----
#define WS_SKV   0           // [4][256]
#define WS_SHKV  1024        // [4][256]
#define WS_SH    2048        // [4][256]  s_h
#define WS_SHH   3072        // [4][256]  sh_h
#define WS_A     4096        // [4][4][256] (b,h,d), includes 1/sqrt(64)
#define WS_R     8192        // [4096][4][256]
#define WS_HT    4202496     // [4096][256] htok fp32
#define WS_G     6299648     // region reused for bf16 buffers:
#define WS_GB    WS_G                   // ushort[4096*1024]  g bf16
#define WS_HNB   (WS_G + 2097152)       // ushort[4096*256]   hn bf16
#define WS_W1T   (WS_G + 2621440)       // ushort[1024*256]   W1^T bf16 [n][k]
#define WS_W2T   (WS_G + 2752512)       // ushort[256*1024]   W2^T bf16 [n][k]

#define FMA8(acc, s, wa, wb) \
  acc[0]=fmaf((s),(wa).x,acc[0]); acc[1]=fmaf((s),(wa).y,acc[1]); \
  acc[2]=fmaf((s),(wa).z,acc[2]); acc[3]=fmaf((s),(wa).w,acc[3]); \
  acc[4]=fmaf((s),(wb).x,acc[4]); acc[5]=fmaf((s),(wb).y,acc[5]); \
  acc[6]=fmaf((s),(wb).z,acc[6]); acc[7]=fmaf((s),(wb).w,acc[7]);

#define FMA4(acc, s, wa) \
  acc[0]=fmaf((s),(wa).x,acc[0]); acc[1]=fmaf((s),(wa).y,acc[1]); \
  acc[2]=fmaf((s),(wa).z,acc[2]); acc[3]=fmaf((s),(wa).w,acc[3]);

#define DOT8(res, v, wa, wb) \
  res = fmaf((v)[0],(wa).x,res); res = fmaf((v)[1],(wa).y,res); \
  res = fmaf((v)[2],(wa).z,res); res = fmaf((v)[3],(wa).w,res); \
  res = fmaf((v)[4],(wb).x,res); res = fmaf((v)[5],(wb).y,res); \
  res = fmaf((v)[6],(wb).z,res); res = fmaf((v)[7],(wb).w,res);

__device__ __forceinline__ float bfly32(float v){
  v += __shfl_xor(v, 1);  v += __shfl_xor(v, 2);  v += __shfl_xor(v, 4);
  v += __shfl_xor(v, 8);  v += __shfl_xor(v, 16);
  return v;
}

__device__ __forceinline__ float gelu_tanh(float x){
  float inner = 0.7978845608028654f*(x + 0.044715f*x*x*x);
  return 0.5f*x*(1.0f + tanhf(inner));
}
// identical math via sigmoid: 0.5(1+tanh(z)) = 1/(1+e^-2z)
__device__ __forceinline__ float gelu_fast(float x){
  float z2 = 1.5957691216057308f*(x + 0.044715f*x*x*x);
  return x / (1.0f + __expf(-z2));
}

__device__ __forceinline__ unsigned short f2bf(float x){
  union { float f; unsigned u; } v; v.f = x;
  unsigned r = v.u + 0x7fffu + ((v.u >> 16) & 1u);
  return (unsigned short)(r >> 16);
}

// ------------------------------------------------------------------
// KW: convert+transpose W1 -> W1T bf16 [1024][256], W2 -> W2T bf16
// [256][1024]. grid=128 (64 tiles W1, 64 tiles W2), block=256.
// ------------------------------------------------------------------
__global__ __launch_bounds__(256) void kw_conv(
  const float* __restrict__ W1, const float* __restrict__ W2,
  float* __restrict__ ws)
{
  __shared__ unsigned short lt[64][68];
  const int tid = threadIdx.x;
  int blk = blockIdx.x;
  const float* src; unsigned short* dst; int K, N, K0, N0;
  if (blk < 64){
    src = W1; dst = (unsigned short*)(ws + WS_W1T);
    K = 256; N = 1024; K0 = (blk >> 4)*64; N0 = (blk & 15)*64;
  } else {
    blk -= 64;
    src = W2; dst = (unsigned short*)(ws + WS_W2T);
    K = 1024; N = 256; K0 = (blk >> 2)*64; N0 = (blk & 3)*64;
  }
  #pragma unroll
  for (int i=0;i<4;++i){
    int r = i*16 + (tid>>4);
    int c = (tid&15)*4;
    f4 v = *(const f4*)(src + (size_t)(K0+r)*N + N0 + c);
    lt[r][c]   = f2bf(v.x); lt[r][c+1] = f2bf(v.y);
    lt[r][c+2] = f2bf(v.z); lt[r][c+3] = f2bf(v.w);
  }
  __syncthreads();
  #pragma unroll
  for (int i=0;i<4;++i){
    int n  = i*16 + (tid>>4);
    int kc = (tid&15)*4;
    ushort4 u;
    u.x = lt[kc][n]; u.y = lt[kc+1][n]; u.z = lt[kc+2][n]; u.w = lt[kc+3][n];
    *(ushort4*)(dst + (size_t)(N0+n)*K + K0 + kc) = u;
  }
}

// ------------------------------------------------------------------
// K0: merged per-(b,h) setup (round-5 verified). grid=16, block=256.
// ------------------------------------------------------------------
__global__ __launch_bounds__(256) void k0_all(
    const float* __restrict__ ctx, const float* __restrict__ q_emb,
    const float* __restrict__ Wkv, const float* __restrict__ bkv,
    const float* __restrict__ Wqc, const float* __restrict__ bqc,
    const float* __restrict__ Whc, const float* __restrict__ bhc,
    const float* __restrict__ Wq,  const float* __restrict__ Wk,
    float* __restrict__ ws)
{
  const int b = blockIdx.x >> 2, h = blockIdx.x & 3;
  const int tid = threadIdx.x;
  __shared__ float c[64], qn[256], ph[256], qh64[64], red[8];
  if (tid < 64) c[tid] = ctx[b*64 + tid];
  __syncthreads();

  float skv = bkv[tid],      shkv = bkv[256+tid];
  float sq  = bqc[tid],      shq  = bqc[256+tid];
  float sh  = bhc[tid],      shh  = bhc[256+tid];
  #pragma unroll 8
  for (int j=0;j<64;++j){
    float cj = c[j];
    skv  = fmaf(cj, Wkv[j*512 + tid],       skv);
    shkv = fmaf(cj, Wkv[j*512 + 256 + tid], shkv);
    sq   = fmaf(cj, Wqc[j*512 + tid],       sq);
    shq  = fmaf(cj, Wqc[j*512 + 256 + tid], shq);
    sh   = fmaf(cj, Whc[j*512 + tid],       sh);
    shh  = fmaf(cj, Whc[j*512 + 256 + tid], shh);
  }
  if (h == 0){
    ws[WS_SKV  + b*256 + tid] = skv;
    ws[WS_SHKV + b*256 + tid] = shkv;
    ws[WS_SH   + b*256 + tid] = sh;
    ws[WS_SHH  + b*256 + tid] = shh;
  }

  float qe = q_emb[tid];
  float s1r = qe, s2r = qe*qe;
  for (int mm=1;mm<64;mm<<=1){ s1r += __shfl_xor(s1r,mm); s2r += __shfl_xor(s2r,mm); }
  int wv = tid>>6, ln = tid&63;
  if (ln==0){ red[wv*2]=s1r; red[wv*2+1]=s2r; }
  __syncthreads();
  float S1 = red[0]+red[2]+red[4]+red[6];
  float S2 = red[1]+red[3]+red[5]+red[7];
  float mean = S1*(1.0f/256.0f);
  float var  = S2*(1.0f/256.0f) - mean*mean;
  float rs   = rsqrtf(var + EPSV);
  qn[tid] = (qe-mean)*rs*(1.0f+sq) + shq;
  __syncthreads();

  {
    const int t = tid & 63, ks = tid >> 6;
    float p = 0.f;
    const float* wq = Wq + (size_t)(ks*64)*256 + h*64 + t;
    #pragma unroll 8
    for (int d=0; d<64; ++d) p = fmaf(qn[ks*64+d], wq[d*256], p);
    ph[tid] = p;
  }
  __syncthreads();
  if (tid < 64) qh64[tid] = ph[tid] + ph[64+tid] + ph[128+tid] + ph[192+tid];
  __syncthreads();

  {
    float a = 0.f;
    const float* wkr = Wk + (size_t)tid*256 + h*64;
    #pragma unroll
    for (int e4=0; e4<16; ++e4){
      f4 wv4 = *(const f4*)(wkr + e4*4);
      a = fmaf(qh64[e4*4+0], wv4.x, a);
      a = fmaf(qh64[e4*4+1], wv4.y, a);
      a = fmaf(qh64[e4*4+2], wv4.z, a);
      a = fmaf(qh64[e4*4+3], wv4.w, a);
    }
    ws[WS_A + b*1024 + h*256 + tid] = 0.125f*a;
  }
}

// ------------------------------------------------------------------
// K1F: fused attention middle (round-4/5 verified, unchanged).
// grid=512 (8 tokens), block=256.
// ------------------------------------------------------------------
__global__ __launch_bounds__(256) void k1f_attn(
  const float* __restrict__ x, const int* __restrict__ idx,
  const float* __restrict__ Wp, const float* __restrict__ Bp,
  float* __restrict__ ws)
{
  __shared__ float xs[2048];       // [t][256]
  __shared__ float wls[2][2048];   // dbuf [i][d]
  __shared__ float As[1024];       // [h][d]

  const int tid = threadIdx.x;
  const int p0  = blockIdx.x * 8;
  const int b   = p0 >> 10;
  const int t   = tid >> 5;
  const int dg  = tid & 31;
  const int dA  = 4*dg, dB = 128 + 4*dg;

  {
    const float* xg = x + (size_t)p0*256 + tid*8;
    f4 a  = *(const f4*)xg;
    f4 bq = *(const f4*)(xg + 4);
    *(f4*)&xs[tid*8]     = a;
    *(f4*)&xs[tid*8 + 4] = bq;
  }
  *(f4*)&As[tid*4] = *(const f4*)(ws + WS_A + b*1024 + tid*4);

  f4 skA = *(const f4*)(ws + WS_SKV  + b*256 + dA);
  f4 skB = *(const f4*)(ws + WS_SKV  + b*256 + dB);
  f4 shA = *(const f4*)(ws + WS_SHKV + b*256 + dA);
  f4 shB = *(const f4*)(ws + WS_SHKV + b*256 + dB);
  float coef[8] = {1.f+skA.x,1.f+skA.y,1.f+skA.z,1.f+skA.w,
                   1.f+skB.x,1.f+skB.y,1.f+skB.z,1.f+skB.w};
  float shk[8]  = {shA.x,shA.y,shA.z,shA.w, shB.x,shB.y,shB.z,shB.w};

  int row = idx[0];
  f4 u0, u1;
  {
    const float* wp0 = Wp + (size_t)row*2048 + tid*8;
    u0 = *(const f4*)wp0;
    u1 = *(const f4*)(wp0 + 4);
  }

  float l[4] = {0.f,0.f,0.f,0.f};
  float racc[4][8] = {};

  for (int f = 0; f < 32; ++f){
    {
      float* wb = wls[f&1];
      wb[0*256+tid]=u0.x; wb[1*256+tid]=u0.y; wb[2*256+tid]=u0.z; wb[3*256+tid]=u0.w;
      wb[4*256+tid]=u1.x; wb[5*256+tid]=u1.y; wb[6*256+tid]=u1.z; wb[7*256+tid]=u1.w;
    }
    f4 ba = *(const f4*)(Bp + (size_t)row*256 + dA);
    f4 bb = *(const f4*)(Bp + (size_t)row*256 + dB);
    int rown = idx[f < 31 ? f+1 : 31];
    const float* wpn = Wp + (size_t)rown*2048 + tid*8;
    row = rown;
    __syncthreads();
    u0 = *(const f4*)wpn;
    u1 = *(const f4*)(wpn + 4);

    f4 xa = *(const f4*)&xs[t*256 + f*8];
    f4 xb = *(const f4*)&xs[t*256 + f*8 + 4];
    float xf[8] = {xa.x,xa.y,xa.z,xa.w, xb.x,xb.y,xb.z,xb.w};

    float val[8] = {};
    const float* wrow = wls[f&1];
    #pragma unroll
    for (int i=0;i<8;++i){
      f4 wa = *(const f4*)&wrow[i*256 + dA];
      f4 wbv = *(const f4*)&wrow[i*256 + dB];
      FMA8(val, xf[i], wa, wbv);
    }

    float s=0.f, ss=0.f;
    #pragma unroll
    for (int jj=0;jj<8;++jj){ s += val[jj]; ss = fmaf(val[jj],val[jj],ss); }
    s = bfly32(s); ss = bfly32(ss);
    float mean = s*(1.f/256.f);
    float var  = ss*(1.f/256.f) - mean*mean;
    float rsg  = rsqrtf(var + EPSV);
    float mrs  = mean*rsg;

    float off[8] = {shk[0]+ba.x, shk[1]+ba.y, shk[2]+ba.z, shk[3]+ba.w,
                    shk[4]+bb.x, shk[5]+bb.y, shk[6]+bb.z, shk[7]+bb.w};
    float kvl[8];
    #pragma unroll
    for (int jj=0;jj<8;++jj)
      kvl[jj] = fmaf(fmaf(val[jj], rsg, -mrs), coef[jj], off[jj]);

    #pragma unroll
    for (int h=0;h<4;++h){
      f4 Aa = *(const f4*)&As[h*256 + dA];
      f4 Ab = *(const f4*)&As[h*256 + dB];
      float lg = 0.f;
      DOT8(lg, kvl, Aa, Ab);
      lg = bfly32(lg);
      float pp = __expf(lg);
      l[h] += pp;
      #pragma unroll
      for (int jj=0;jj<8;++jj)
        racc[h][jj] = fmaf(pp, kvl[jj], racc[h][jj]);
    }
  }

  float* rp = ws + WS_R + (size_t)(p0+t)*1024;
  #pragma unroll
  for (int h=0;h<4;++h){
    float inv = 1.f / l[h];
    *(f4*)&rp[h*256 + dA] = make_float4(racc[h][0]*inv, racc[h][1]*inv,
                                        racc[h][2]*inv, racc[h][3]*inv);
    *(f4*)&rp[h*256 + dB] = make_float4(racc[h][4]*inv, racc[h][5]*inv,
                                        racc[h][6]*inv, racc[h][7]*inv);
  }
}

// ------------------------------------------------------------------
// K2 v2: o = r@Wv, o2 = o@Wo, htok = q_emb+o2 (fp32), hn = CLN (bf16).
// grid=512 (8 tokens), block=256. (round-5 verified; only the hn
// store changed: bf16 to WS_HNB instead of fp32.)
// ------------------------------------------------------------------
__global__ __launch_bounds__(256) void k2_ovo(
  const float* __restrict__ Wv, const float* __restrict__ Wo,
  const float* __restrict__ q_emb, float* __restrict__ ws)
{
  __shared__ float rl[8192];
  __shared__ float ot[2048];
  __shared__ float wt[2][2048];

  const int tid = threadIdx.x;
  const int p0  = blockIdx.x * 8;
  const int b   = p0 >> 10;
  const int tq  = tid >> 5;
  const int jq  = tid & 31;
  const int cA  = 4*jq, cB = 128 + 4*jq;
  const int hA  = jq >> 4, hB = 2 + (jq >> 4);

  #pragma unroll
  for (int i=0;i<8;++i){
    int off = i*1024 + tid*4;
    *(f4*)&rl[off] = *(const f4*)(ws + WS_R + (size_t)p0*1024 + off);
  }

  const int q0 = tid, q1 = tid + 256;
  f4 uw0, uw1;
  uw0 = *(const f4*)(Wv + (size_t)(q0>>6)*256 + (q0&63)*4);
  uw1 = *(const f4*)(Wv + (size_t)(q1>>6)*256 + (q1&63)*4);

  float oa[8] = {};
  for (int c=0; c<32; ++c){
    float* wb = wt[c&1];
    *(f4*)&wb[(q0>>6)*256 + (q0&63)*4] = uw0;
    *(f4*)&wb[(q1>>6)*256 + (q1&63)*4] = uw1;
    __syncthreads();
    int cn = (c < 31) ? c+1 : 31;
    uw0 = *(const f4*)(Wv + (size_t)(cn*8 + (q0>>6))*256 + (q0&63)*4);
    uw1 = *(const f4*)(Wv + (size_t)(cn*8 + (q1>>6))*256 + (q1&63)*4);
    const float* wrow = wt[c&1];
    #pragma unroll
    for (int dd=0; dd<8; ++dd){
      int d = c*8 + dd;
      float rA = rl[tq*1024 + hA*256 + d];
      float rB = rl[tq*1024 + hB*256 + d];
      f4 w0 = *(const f4*)&wrow[dd*256 + cA];
      f4 w1 = *(const f4*)&wrow[dd*256 + cB];
      FMA4(oa, rA, w0);
      float* ob4 = oa + 4;
      FMA4(ob4, rB, w1);
    }
  }
  *(f4*)&ot[tq*256 + cA] = make_float4(oa[0],oa[1],oa[2],oa[3]);
  *(f4*)&ot[tq*256 + cB] = make_float4(oa[4],oa[5],oa[6],oa[7]);
  uw0 = *(const f4*)(Wo + (size_t)(q0>>6)*256 + (q0&63)*4);
  uw1 = *(const f4*)(Wo + (size_t)(q1>>6)*256 + (q1&63)*4);
  __syncthreads();

  float ob[8] = {};
  for (int c=0; c<32; ++c){
    float* wb = wt[c&1];
    *(f4*)&wb[(q0>>6)*256 + (q0&63)*4] = uw0;
    *(f4*)&wb[(q1>>6)*256 + (q1&63)*4] = uw1;
    __syncthreads();
    int cn = (c < 31) ? c+1 : 31;
    uw0 = *(const f4*)(Wo + (size_t)(cn*8 + (q0>>6))*256 + (q0&63)*4);
    uw1 = *(const f4*)(Wo + (size_t)(cn*8 + (q1>>6))*256 + (q1&63)*4);
    const float* wrow = wt[c&1];
    #pragma unroll
    for (int dd=0; dd<8; ++dd){
      int cc = c*8 + dd;
      float a = ot[tq*256 + cc];
      f4 w0 = *(const f4*)&wrow[dd*256 + cA];
      f4 w1 = *(const f4*)&wrow[dd*256 + cB];
      FMA8(ob, a, w0, w1);
    }
  }

  f4 qA = *(const f4*)(q_emb + cA);
  f4 qB = *(const f4*)(q_emb + cB);
  float ht[8] = {ob[0]+qA.x, ob[1]+qA.y, ob[2]+qA.z, ob[3]+qA.w,
                 ob[4]+qB.x, ob[5]+qB.y, ob[6]+qB.z, ob[7]+qB.w};
  float s=0.f, ss=0.f;
  #pragma unroll
  for (int jj=0;jj<8;++jj){ s += ht[jj]; ss = fmaf(ht[jj],ht[jj],ss); }
  s = bfly32(s); ss = bfly32(ss);
  float mean = s*(1.f/256.f);
  float var  = ss*(1.f/256.f) - mean*mean;
  float rsg  = rsqrtf(var + EPSV);
  f4 sH0 = *(const f4*)(ws + WS_SH  + b*256 + cA);
  f4 sH1 = *(const f4*)(ws + WS_SH  + b*256 + cB);
  f4 hH0 = *(const f4*)(ws + WS_SHH + b*256 + cA);
  f4 hH1 = *(const f4*)(ws + WS_SHH + b*256 + cB);
  float sHv[8]  = {sH0.x,sH0.y,sH0.z,sH0.w, sH1.x,sH1.y,sH1.z,sH1.w};
  float hHv[8]  = {hH0.x,hH0.y,hH0.z,hH0.w, hH1.x,hH1.y,hH1.z,hH1.w};
  float hnv[8];
  #pragma unroll
  for (int jj=0;jj<8;++jj)
    hnv[jj] = (ht[jj]-mean)*rsg*(1.f+sHv[jj]) + hHv[jj];

  float* htp = ws + WS_HT + (size_t)(p0+tq)*256;
  *(f4*)(htp+cA) = make_float4(ht[0],ht[1],ht[2],ht[3]);
  *(f4*)(htp+cB) = make_float4(ht[4],ht[5],ht[6],ht[7]);
  unsigned short* hnb = (unsigned short*)(ws + WS_HNB);
  ushort4 uA, uB;
  uA.x=f2bf(hnv[0]); uA.y=f2bf(hnv[1]); uA.z=f2bf(hnv[2]); uA.w=f2bf(hnv[3]);
  uB.x=f2bf(hnv[4]); uB.y=f2bf(hnv[5]); uB.z=f2bf(hnv[6]); uB.w=f2bf(hnv[7]);
  *(ushort4*)(hnb + (size_t)(p0+tq)*256 + cA) = uA;
  *(ushort4*)(hnb + (size_t)(p0+tq)*256 + cB) = uB;
}

// ------------------------------------------------------------------
// K3 MFMA: g_bf16 = gelu(hn_bf16 @ W1 + b1).
// grid = 512 = 64 M-tiles(64) x 8 N-tiles(128), block=256 (4 waves).
// Wave tile 32m x 64n: 2 a-frags x 4 b-frags, 8 k-slices of 32.
// Operand-swapped mfma(Wfrag, Xfrag, acc): acc lane map col=m (lane&15),
// row=n (quad*4+reg) -> 4 consecutive n per frag for packed stores.
// LDS rows padded to 40 halves (80B: 16B-aligned, bank-uniform).
// ------------------------------------------------------------------
__global__ __launch_bounds__(256) void k3_mfma(
  const float* __restrict__ b1, float* __restrict__ ws)
{
  __shared__ unsigned short aT[2][64*40];    // hn tile  [m][k]
  __shared__ unsigned short bT[2][128*40];   // W1T tile [n][k]
  const unsigned short* hnb = (const unsigned short*)(ws + WS_HNB);
  const unsigned short* w1t = (const unsigned short*)(ws + WS_W1T);
  unsigned short* gb = (unsigned short*)(ws + WS_GB);

  const int tid = threadIdx.x;
  const int M0 = (blockIdx.x >> 3) * 64;
  const int N0 = (blockIdx.x & 7) * 128;
  const int lane = tid & 63;
  const int wid = tid >> 6;
  const int wm = wid >> 1, wn = wid & 1;
  const int m16 = lane & 15, q = lane >> 4;

  const int sa_m = tid >> 2, sa_k = (tid & 3) * 8;   // A stage: 64r x 32k
  const int sb_n = tid >> 1, sb_k = (tid & 1) * 16;  // B stage: 128r x 32k

  f4 ua, ub0, ub1;
  ua  = *(const f4*)(hnb + (size_t)(M0 + sa_m)*256 + sa_k);
  ub0 = *(const f4*)(w1t + (size_t)(N0 + sb_n)*256 + sb_k);
  ub1 = *(const f4*)(w1t + (size_t)(N0 + sb_n)*256 + sb_k + 8);

  ffrag acc[2][4];
  #pragma unroll
  for (int i=0;i<2;++i)
    #pragma unroll
    for (int j=0;j<4;++j) acc[i][j] = (ffrag){0.f,0.f,0.f,0.f};

  for (int ks=0; ks<8; ++ks){
    const int buf = ks & 1;
    *(f4*)&aT[buf][sa_m*40 + sa_k]     = ua;
    *(f4*)&bT[buf][sb_n*40 + sb_k]     = ub0;
    *(f4*)&bT[buf][sb_n*40 + sb_k + 8] = ub1;
    __syncthreads();
    int kn = (ks < 7) ? ks+1 : 7;
    ua  = *(const f4*)(hnb + (size_t)(M0 + sa_m)*256 + kn*32 + sa_k);
    ub0 = *(const f4*)(w1t + (size_t)(N0 + sb_n)*256 + kn*32 + sb_k);
    ub1 = *(const f4*)(w1t + (size_t)(N0 + sb_n)*256 + kn*32 + sb_k + 8);

    bfrag af[2], bf_[4];
    af[0] = *(const bfrag*)&aT[buf][(wm*32 + m16)*40 + q*8];
    af[1] = *(const bfrag*)&aT[buf][(wm*32 + 16 + m16)*40 + q*8];
    #pragma unroll
    for (int j=0;j<4;++j)
      bf_[j] = *(const bfrag*)&bT[buf][(wn*64 + j*16 + m16)*40 + q*8];
    #pragma unroll
    for (int i=0;i<2;++i)
      #pragma unroll
      for (int j=0;j<4;++j)
        acc[i][j] = __builtin_amdgcn_mfma_f32_16x16x32_bf16(bf_[j], af[i], acc[i][j], 0, 0, 0);
  }

  #pragma unroll
  for (int i=0;i<2;++i){
    const int m = M0 + wm*32 + i*16 + m16;
    #pragma unroll
    for (int j=0;j<4;++j){
      const int n4 = N0 + wn*64 + j*16 + q*4;
      f4 bv = *(const f4*)(b1 + n4);
      ushort4 u;
      u.x = f2bf(gelu_fast(acc[i][j][0] + bv.x));
      u.y = f2bf(gelu_fast(acc[i][j][1] + bv.y));
      u.z = f2bf(gelu_fast(acc[i][j][2] + bv.z));
      u.w = f2bf(gelu_fast(acc[i][j][3] + bv.w));
      *(ushort4*)(gb + (size_t)m*1024 + n4) = u;
    }
  }
}

// ------------------------------------------------------------------
// K4 MFMA: out = htok + g_bf16 @ W2 + b2.
// grid = 512 = 128 M-tiles(32) x 4 N-tiles(64), block=256 (4 waves).
// Wave tile 16m x 32n: 1 a-frag x 2 b-frags, 32 k-slices of 32.
// ------------------------------------------------------------------
__global__ __launch_bounds__(256) void k4_mfma(
  const float* __restrict__ b2, const float* __restrict__ ws_c,
  float* __restrict__ ws, float* __restrict__ out)
{
  __shared__ unsigned short aT[2][32*40];    // g tile   [m][k]
  __shared__ unsigned short bT[2][64*40];    // W2T tile [n][k]
  const unsigned short* gb  = (const unsigned short*)(ws_c + WS_GB);
  const unsigned short* w2t = (const unsigned short*)(ws_c + WS_W2T);

  const int tid = threadIdx.x;
  const int M0 = (blockIdx.x >> 2) * 32;
  const int N0 = (blockIdx.x & 3) * 64;
  const int lane = tid & 63;
  const int wid = tid >> 6;
  const int wm = wid >> 1, wn = wid & 1;
  const int m16 = lane & 15, q = lane >> 4;

  const int sa_m = tid >> 3, sa_k = (tid & 7) * 4;   // A stage: 32r x 32k (8B)
  const int sb_n = tid >> 2, sb_k = (tid & 3) * 8;   // B stage: 64r x 32k (16B)

  ushort4 ua;
  f4 ub;
  ua = *(const ushort4*)(gb  + (size_t)(M0 + sa_m)*1024 + sa_k);
  ub = *(const f4*)(w2t + (size_t)(N0 + sb_n)*1024 + sb_k);

  ffrag acc[2];
  acc[0] = (ffrag){0.f,0.f,0.f,0.f};
  acc[1] = (ffrag){0.f,0.f,0.f,0.f};

  for (int ks=0; ks<32; ++ks){
    const int buf = ks & 1;
    *(ushort4*)&aT[buf][sa_m*40 + sa_k] = ua;
    *(f4*)&bT[buf][sb_n*40 + sb_k]      = ub;
    __syncthreads();
    int kn = (ks < 31) ? ks+1 : 31;
    ua = *(const ushort4*)(gb  + (size_t)(M0 + sa_m)*1024 + kn*32 + sa_k);
    ub = *(const f4*)(w2t + (size_t)(N0 + sb_n)*1024 + kn*32 + sb_k);

    bfrag af, bf0, bf1;
    af  = *(const bfrag*)&aT[buf][(wm*16 + m16)*40 + q*8];
    bf0 = *(const bfrag*)&bT[buf][(wn*32 + m16)*40 + q*8];
    bf1 = *(const bfrag*)&bT[buf][(wn*32 + 16 + m16)*40 + q*8];
    acc[0] = __builtin_amdgcn_mfma_f32_16x16x32_bf16(bf0, af, acc[0], 0, 0, 0);
    acc[1] = __builtin_amdgcn_mfma_f32_16x16x32_bf16(bf1, af, acc[1], 0, 0, 0);
  }

  const int m = M0 + wm*16 + m16;
  #pragma unroll
  for (int j=0;j<2;++j){
    const int n4 = N0 + wn*32 + j*16 + q*4;
    f4 bv = *(const f4*)(b2 + n4);
    f4 hv = *(const f4*)(ws + WS_HT + (size_t)m*256 + n4);
    *(f4*)(out + (size_t)m*256 + n4) =
      make_float4(acc[j][0]+bv.x+hv.x, acc[j][1]+bv.y+hv.y,
                  acc[j][2]+bv.z+hv.z, acc[j][3]+bv.w+hv.w);
  }
}

// ------------------------------------------------------------------
extern "C" void kernel_launch(void* const* d_in, const int* in_sizes, int n_in,
                              void* d_out, int out_size, void* d_ws, size_t ws_size,
                              hipStream_t stream)
{
  const float* x    = (const float*)d_in[0];
  const int*   idx  = (const int*)  d_in[1];
  const float* ctx  = (const float*)d_in[2];
  const float* Wp   = (const float*)d_in[3];
  const float* Bp   = (const float*)d_in[4];
  const float* qemb = (const float*)d_in[5];
  const float* Wkv  = (const float*)d_in[6];
  const float* bkv  = (const float*)d_in[7];
  const float* Wqc  = (const float*)d_in[8];
  const float* bqc  = (const float*)d_in[9];
  const float* Whc  = (const float*)d_in[10];
  const float* bhc  = (const float*)d_in[11];
  const float* Wq   = (const float*)d_in[12];
  const float* Wk   = (const float*)d_in[13];
  const float* Wv   = (const float*)d_in[14];
  const float* Wo   = (const float*)d_in[15];
  const float* W1   = (const float*)d_in[16];
  const float* b1   = (const float*)d_in[17];
  const float* W2   = (const float*)d_in[18];
  const float* b2   = (const float*)d_in[19];
  float* ws  = (float*)d_ws;
  float* out = (float*)d_out;

  hipLaunchKernelGGL(kw_conv,  dim3(128), dim3(256), 0, stream, W1, W2, ws);
  hipLaunchKernelGGL(k0_all,   dim3(16),  dim3(256), 0, stream,
                     ctx, qemb, Wkv, bkv, Wqc, bqc, Whc, bhc, Wq, Wk, ws);
  hipLaunchKernelGGL(k1f_attn, dim3(512), dim3(256), 0, stream, x, idx, Wp, Bp, ws);
  hipLaunchKernelGGL(k2_ovo,   dim3(512), dim3(256), 0, stream, Wv, Wo, qemb, ws);
  hipLaunchKernelGGL(k3_mfma,  dim3(512), dim3(256), 0, stream, b1, ws);
  hipLaunchKernelGGL(k4_mfma,  dim3(512), dim3(256), 0, stream, b2, ws, ws, out);
}

// Round 7
// 202.694 us; speedup vs baseline: 2.6813x; 1.0743x over previous
//
#include <hip/hip_runtime.h>
#include <cmath>

#define EPSV 1e-5f
using f4 = float4;

typedef __attribute__((ext_vector_type(8))) short bfrag;   // 8 bf16 (4 VGPRs)
typedef __attribute__((ext_vector_type(4))) float ffrag;   // 4 fp32 acc

// ---- ws layout (float offsets) ----
#define WS_SKV   0           // [4][256]
#define WS_SHKV  1024        // [4][256]
#define WS_SH    2048        // [4][256]
#define WS_SHH   3072        // [4][256]
#define WS_A     4096        // [4][4][256]
#define WS_R     8192        // ushort view: racc partials [2][4096][4][256] bf16
                             // (kc combines in-place -> rb bf16 [4096][1024] in half0)
#define WS_HT    4202496     // [4096][256] fp32: o2 then htok (ke in-place)
#define WS_L     5251072     // [2][4096][4] fp32 l partials (freed WS_HN region)
#define WS_G     6299648
#define WS_GB    WS_G                   // ushort[4096*1024]  g bf16
#define WS_HNB   (WS_G + 2097152)       // ushort[4096*256]   hn bf16
#define WS_W1T   (WS_G + 2621440)       // ushort[1024*256]   W1^T bf16 [n][k]
#define WS_W2T   (WS_G + 2752512)       // ushort[256*1024]   W2^T bf16 [n][k]
#define WS_MT    (WS_G + 2883584)       // ushort[256*1024]   M^T bf16 [j][h*256+d]

#define FMA8(acc, s, wa, wb) \
  acc[0]=fmaf((s),(wa).x,acc[0]); acc[1]=fmaf((s),(wa).y,acc[1]); \
  acc[2]=fmaf((s),(wa).z,acc[2]); acc[3]=fmaf((s),(wa).w,acc[3]); \
  acc[4]=fmaf((s),(wb).x,acc[4]); acc[5]=fmaf((s),(wb).y,acc[5]); \
  acc[6]=fmaf((s),(wb).z,acc[6]); acc[7]=fmaf((s),(wb).w,acc[7]);

#define DOT8(res, v, wa, wb) \
  res = fmaf((v)[0],(wa).x,res); res = fmaf((v)[1],(wa).y,res); \
  res = fmaf((v)[2],(wa).z,res); res = fmaf((v)[3],(wa).w,res); \
  res = fmaf((v)[4],(wb).x,res); res = fmaf((v)[5],(wb).y,res); \
  res = fmaf((v)[6],(wb).z,res); res = fmaf((v)[7],(wb).w,res);

__device__ __forceinline__ float bfly32(float v){
  v += __shfl_xor(v, 1);  v += __shfl_xor(v, 2);  v += __shfl_xor(v, 4);
  v += __shfl_xor(v, 8);  v += __shfl_xor(v, 16);
  return v;
}

__device__ __forceinline__ float gelu_fast(float x){
  float z2 = 1.5957691216057308f*(x + 0.044715f*x*x*x);
  return x / (1.0f + __expf(-z2));
}

__device__ __forceinline__ unsigned short f2bf(float x){
  union { float f; unsigned u; } v; v.f = x;
  unsigned r = v.u + 0x7fffu + ((v.u >> 16) & 1u);
  return (unsigned short)(r >> 16);
}
__device__ __forceinline__ void bf2x(unsigned u, float& a, float& b){
  union { unsigned u; float f; } x, y;
  x.u = u << 16; y.u = u & 0xffff0000u;
  a = x.f; b = y.f;
}

// ------------------------------------------------------------------
// KW: convert+transpose W1 -> W1T bf16 [1024][256], W2 -> W2T bf16
// [256][1024]. grid=128, block=256. (round-6 verified)
// ------------------------------------------------------------------
__global__ __launch_bounds__(256) void kw_conv(
  const float* __restrict__ W1, const float* __restrict__ W2,
  float* __restrict__ ws)
{
  __shared__ unsigned short lt[64][68];
  const int tid = threadIdx.x;
  int blk = blockIdx.x;
  const float* src; unsigned short* dst; int K, N, K0, N0;
  if (blk < 64){
    src = W1; dst = (unsigned short*)(ws + WS_W1T);
    K = 256; N = 1024; K0 = (blk >> 4)*64; N0 = (blk & 15)*64;
  } else {
    blk -= 64;
    src = W2; dst = (unsigned short*)(ws + WS_W2T);
    K = 1024; N = 256; K0 = (blk >> 2)*64; N0 = (blk & 3)*64;
  }
  #pragma unroll
  for (int i=0;i<4;++i){
    int r = i*16 + (tid>>4);
    int c = (tid&15)*4;
    f4 v = *(const f4*)(src + (size_t)(K0+r)*N + N0 + c);
    lt[r][c]   = f2bf(v.x); lt[r][c+1] = f2bf(v.y);
    lt[r][c+2] = f2bf(v.z); lt[r][c+3] = f2bf(v.w);
  }
  __syncthreads();
  #pragma unroll
  for (int i=0;i<4;++i){
    int n  = i*16 + (tid>>4);
    int kc = (tid&15)*4;
    ushort4 u;
    u.x = lt[kc][n]; u.y = lt[kc+1][n]; u.z = lt[kc+2][n]; u.w = lt[kc+3][n];
    *(ushort4*)(dst + (size_t)(N0+n)*K + K0 + kc) = u;
  }
}

// ------------------------------------------------------------------
// KM: precompute M^T bf16 [256 j][1024 k], k = h*256+d,
// Mt[j][h*256+d] = sum_e Wv[d][h*64+e] * Wo[h*64+e][j].
// grid = 256 (h*64 + dg4), block=256 (j).
// ------------------------------------------------------------------
__global__ __launch_bounds__(256) void km_conv(
  const float* __restrict__ Wv, const float* __restrict__ Wo,
  float* __restrict__ ws)
{
  __shared__ float wvs[4*64];
  __shared__ float wos[64*256];
  const int tid = threadIdx.x;
  const int h   = blockIdx.x >> 6;
  const int dg4 = blockIdx.x & 63;
  {
    int d = tid >> 6, e = tid & 63;
    wvs[d*64+e] = Wv[(size_t)(dg4*4 + d)*256 + h*64 + e];
  }
  {
    int e = tid >> 2, c = (tid & 3)*64;
    const float* src = Wo + (size_t)(h*64 + e)*256 + c;
    #pragma unroll
    for (int i=0;i<16;++i)
      *(f4*)&wos[e*256 + c + i*4] = *(const f4*)(src + i*4);
  }
  __syncthreads();
  float acc[4] = {};
  for (int e=0;e<64;++e){
    float wo = wos[e*256 + tid];
    acc[0] = fmaf(wvs[0*64+e], wo, acc[0]);
    acc[1] = fmaf(wvs[1*64+e], wo, acc[1]);
    acc[2] = fmaf(wvs[2*64+e], wo, acc[2]);
    acc[3] = fmaf(wvs[3*64+e], wo, acc[3]);
  }
  unsigned short* Mt = (unsigned short*)(ws + WS_MT);
  ushort4 u;
  u.x = f2bf(acc[0]); u.y = f2bf(acc[1]); u.z = f2bf(acc[2]); u.w = f2bf(acc[3]);
  *(ushort4*)(Mt + (size_t)tid*1024 + h*256 + dg4*4) = u;
}

// ------------------------------------------------------------------
// K0: merged per-(b,h) setup (round-5/6 verified). grid=16, block=256.
// ------------------------------------------------------------------
__global__ __launch_bounds__(256) void k0_all(
    const float* __restrict__ ctx, const float* __restrict__ q_emb,
    const float* __restrict__ Wkv, const float* __restrict__ bkv,
    const float* __restrict__ Wqc, const float* __restrict__ bqc,
    const float* __restrict__ Whc, const float* __restrict__ bhc,
    const float* __restrict__ Wq,  const float* __restrict__ Wk,
    float* __restrict__ ws)
{
  const int b = blockIdx.x >> 2, h = blockIdx.x & 3;
  const int tid = threadIdx.x;
  __shared__ float c[64], qn[256], ph[256], qh64[64], red[8];
  if (tid < 64) c[tid] = ctx[b*64 + tid];
  __syncthreads();

  float skv = bkv[tid],      shkv = bkv[256+tid];
  float sq  = bqc[tid],      shq  = bqc[256+tid];
  float sh  = bhc[tid],      shh  = bhc[256+tid];
  #pragma unroll 8
  for (int j=0;j<64;++j){
    float cj = c[j];
    skv  = fmaf(cj, Wkv[j*512 + tid],       skv);
    shkv = fmaf(cj, Wkv[j*512 + 256 + tid], shkv);
    sq   = fmaf(cj, Wqc[j*512 + tid],       sq);
    shq  = fmaf(cj, Wqc[j*512 + 256 + tid], shq);
    sh   = fmaf(cj, Whc[j*512 + tid],       sh);
    shh  = fmaf(cj, Whc[j*512 + 256 + tid], shh);
  }
  if (h == 0){
    ws[WS_SKV  + b*256 + tid] = skv;
    ws[WS_SHKV + b*256 + tid] = shkv;
    ws[WS_SH   + b*256 + tid] = sh;
    ws[WS_SHH  + b*256 + tid] = shh;
  }

  float qe = q_emb[tid];
  float s1r = qe, s2r = qe*qe;
  for (int mm=1;mm<64;mm<<=1){ s1r += __shfl_xor(s1r,mm); s2r += __shfl_xor(s2r,mm); }
  int wv = tid>>6, ln = tid&63;
  if (ln==0){ red[wv*2]=s1r; red[wv*2+1]=s2r; }
  __syncthreads();
  float S1 = red[0]+red[2]+red[4]+red[6];
  float S2 = red[1]+red[3]+red[5]+red[7];
  float mean = S1*(1.0f/256.0f);
  float var  = S2*(1.0f/256.0f) - mean*mean;
  float rs   = rsqrtf(var + EPSV);
  qn[tid] = (qe-mean)*rs*(1.0f+sq) + shq;
  __syncthreads();

  {
    const int t = tid & 63, ks = tid >> 6;
    float p = 0.f;
    const float* wq = Wq + (size_t)(ks*64)*256 + h*64 + t;
    #pragma unroll 8
    for (int d=0; d<64; ++d) p = fmaf(qn[ks*64+d], wq[d*256], p);
    ph[tid] = p;
  }
  __syncthreads();
  if (tid < 64) qh64[tid] = ph[tid] + ph[64+tid] + ph[128+tid] + ph[192+tid];
  __syncthreads();

  {
    float a = 0.f;
    const float* wkr = Wk + (size_t)tid*256 + h*64;
    #pragma unroll
    for (int e4=0; e4<16; ++e4){
      f4 wv4 = *(const f4*)(wkr + e4*4);
      a = fmaf(qh64[e4*4+0], wv4.x, a);
      a = fmaf(qh64[e4*4+1], wv4.y, a);
      a = fmaf(qh64[e4*4+2], wv4.z, a);
      a = fmaf(qh64[e4*4+3], wv4.w, a);
    }
    ws[WS_A + b*1024 + h*256 + tid] = 0.125f*a;
  }
}

// ------------------------------------------------------------------
// K1F v2: f-split x2 + f-unroll x2. grid=1024 = 512 token-tiles x 2
// f-halves, block=256 (t=tid>>5, dg=tid&31, d-set dA/dB as verified).
// Per 2-f iter: barrier, write 2 staged W's, barrier, prefetch next 2,
// compute both f's (identical math to round-4-verified k1f).
// Writes UNNORMALIZED racc partial (bf16) + l partial (fp32).
// ------------------------------------------------------------------
__global__ __launch_bounds__(256,4) void k1f_attn(
  const float* __restrict__ x, const int* __restrict__ idx,
  const float* __restrict__ Wp, const float* __restrict__ Bp,
  float* __restrict__ ws)
{
  __shared__ float xs[2048];      // [t][256]
  __shared__ float wls[4096];     // [2 f][8 i][256 d]
  __shared__ float As[1024];      // [h][d]

  const int tid = threadIdx.x;
  const int p0  = (blockIdx.x >> 1) * 8;
  const int half= blockIdx.x & 1;
  const int f0  = half * 16;
  const int b   = p0 >> 10;
  const int t   = tid >> 5;
  const int dg  = tid & 31;
  const int dA  = 4*dg, dB = 128 + 4*dg;

  {
    const float* xg = x + (size_t)p0*256 + tid*8;
    f4 a  = *(const f4*)xg;
    f4 bq = *(const f4*)(xg + 4);
    *(f4*)&xs[tid*8]     = a;
    *(f4*)&xs[tid*8 + 4] = bq;
  }
  *(f4*)&As[tid*4] = *(const f4*)(ws + WS_A + b*1024 + tid*4);

  f4 skA = *(const f4*)(ws + WS_SKV  + b*256 + dA);
  f4 skB = *(const f4*)(ws + WS_SKV  + b*256 + dB);
  f4 shA = *(const f4*)(ws + WS_SHKV + b*256 + dA);
  f4 shB = *(const f4*)(ws + WS_SHKV + b*256 + dB);
  float coef[8] = {1.f+skA.x,1.f+skA.y,1.f+skA.z,1.f+skA.w,
                   1.f+skB.x,1.f+skB.y,1.f+skB.z,1.f+skB.w};
  float shk[8]  = {shA.x,shA.y,shA.z,shA.w, shB.x,shB.y,shB.z,shB.w};

  int r0 = idx[f0], r1 = idx[f0+1];
  f4 u0 = *(const f4*)(Wp + (size_t)r0*2048 + tid*8);
  f4 u1 = *(const f4*)(Wp + (size_t)r0*2048 + tid*8 + 4);
  f4 u2 = *(const f4*)(Wp + (size_t)r1*2048 + tid*8);
  f4 u3 = *(const f4*)(Wp + (size_t)r1*2048 + tid*8 + 4);

  float l[4] = {0.f,0.f,0.f,0.f};
  float racc[4][8] = {};

  for (int fi = 0; fi < 8; ++fi){
    const int f = f0 + fi*2;
    __syncthreads();
    wls[0*256+tid]=u0.x; wls[1*256+tid]=u0.y; wls[2*256+tid]=u0.z; wls[3*256+tid]=u0.w;
    wls[4*256+tid]=u1.x; wls[5*256+tid]=u1.y; wls[6*256+tid]=u1.z; wls[7*256+tid]=u1.w;
    wls[2048+0*256+tid]=u2.x; wls[2048+1*256+tid]=u2.y;
    wls[2048+2*256+tid]=u2.z; wls[2048+3*256+tid]=u2.w;
    wls[2048+4*256+tid]=u3.x; wls[2048+5*256+tid]=u3.y;
    wls[2048+6*256+tid]=u3.z; wls[2048+7*256+tid]=u3.w;
    __syncthreads();

    // bias for the current pair (L2-resident Bp rows)
    f4 ba0 = *(const f4*)(Bp + (size_t)r0*256 + dA);
    f4 bb0 = *(const f4*)(Bp + (size_t)r0*256 + dB);
    f4 ba1 = *(const f4*)(Bp + (size_t)r1*256 + dA);
    f4 bb1 = *(const f4*)(Bp + (size_t)r1*256 + dB);

    // prefetch next pair's W rows (land during compute)
    const int fn = (fi < 7) ? f + 2 : f0;
    int rn0 = idx[fn], rn1 = idx[fn+1];
    u0 = *(const f4*)(Wp + (size_t)rn0*2048 + tid*8);
    u1 = *(const f4*)(Wp + (size_t)rn0*2048 + tid*8 + 4);
    u2 = *(const f4*)(Wp + (size_t)rn1*2048 + tid*8);
    u3 = *(const f4*)(Wp + (size_t)rn1*2048 + tid*8 + 4);

    #pragma unroll
    for (int sub=0; sub<2; ++sub){
      const float* wrow = wls + sub*2048;
      const int fc = f + sub;
      f4 ba = sub ? ba1 : ba0;
      f4 bb = sub ? bb1 : bb0;

      f4 xa = *(const f4*)&xs[t*256 + fc*8];
      f4 xb = *(const f4*)&xs[t*256 + fc*8 + 4];
      float xf[8] = {xa.x,xa.y,xa.z,xa.w, xb.x,xb.y,xb.z,xb.w};

      float val[8] = {};
      #pragma unroll
      for (int i=0;i<8;++i){
        f4 wa  = *(const f4*)&wrow[i*256 + dA];
        f4 wbv = *(const f4*)&wrow[i*256 + dB];
        FMA8(val, xf[i], wa, wbv);
      }

      float s=0.f, ss=0.f;
      #pragma unroll
      for (int jj=0;jj<8;++jj){ s += val[jj]; ss = fmaf(val[jj],val[jj],ss); }
      s = bfly32(s); ss = bfly32(ss);
      float mean = s*(1.f/256.f);
      float var  = ss*(1.f/256.f) - mean*mean;
      float rsg  = rsqrtf(var + EPSV);
      float mrs  = mean*rsg;

      float off[8] = {shk[0]+ba.x, shk[1]+ba.y, shk[2]+ba.z, shk[3]+ba.w,
                      shk[4]+bb.x, shk[5]+bb.y, shk[6]+bb.z, shk[7]+bb.w};
      float kvl[8];
      #pragma unroll
      for (int jj=0;jj<8;++jj)
        kvl[jj] = fmaf(fmaf(val[jj], rsg, -mrs), coef[jj], off[jj]);

      #pragma unroll
      for (int h=0;h<4;++h){
        f4 Aa = *(const f4*)&As[h*256 + dA];
        f4 Ab = *(const f4*)&As[h*256 + dB];
        float lg = 0.f;
        DOT8(lg, kvl, Aa, Ab);
        lg = bfly32(lg);
        float pp = __expf(lg);
        l[h] += pp;
        #pragma unroll
        for (int jj=0;jj<8;++jj)
          racc[h][jj] = fmaf(pp, kvl[jj], racc[h][jj]);
      }
    }
    r0 = rn0; r1 = rn1;
  }

  // write UNNORMALIZED bf16 partials + l
  unsigned short* Pr = (unsigned short*)(ws + WS_R);
  size_t base = (size_t)(half*4096 + p0 + t) * 1024;
  #pragma unroll
  for (int h=0;h<4;++h){
    ushort4 ua, ub;
    ua.x=f2bf(racc[h][0]); ua.y=f2bf(racc[h][1]); ua.z=f2bf(racc[h][2]); ua.w=f2bf(racc[h][3]);
    ub.x=f2bf(racc[h][4]); ub.y=f2bf(racc[h][5]); ub.z=f2bf(racc[h][6]); ub.w=f2bf(racc[h][7]);
    *(ushort4*)(Pr + base + h*256 + dA) = ua;
    *(ushort4*)(Pr + base + h*256 + dB) = ub;
  }
  if (dg == 0){
    float* Lp = ws + WS_L;
    #pragma unroll
    for (int h=0;h<4;++h) Lp[(size_t)(half*4096 + p0 + t)*4 + h] = l[h];
  }
}

// ------------------------------------------------------------------
// KC: combine partials in-place: rb = (p0 + p1) / (l0 + l1), bf16.
// grid=512 (8 tokens), block=256; each thread owns its 16B groups.
// ------------------------------------------------------------------
__global__ __launch_bounds__(256) void kc_comb(float* __restrict__ ws)
{
  unsigned short* Pr = (unsigned short*)(ws + WS_R);
  const float* Lp = ws + WS_L;
  const int tid = threadIdx.x;
  const int p0 = blockIdx.x * 8;
  #pragma unroll
  for (int k=0;k<4;++k){
    size_t e0 = (size_t)p0*1024 + (size_t)k*2048 + (size_t)tid*8;
    int t = (int)(e0 >> 10);
    int h = (int)((e0 >> 8) & 3);
    float inv = 1.f / (Lp[(size_t)t*4 + h] + Lp[(size_t)(4096 + t)*4 + h]);
    uint4 a  = *(const uint4*)(Pr + e0);
    uint4 bq = *(const uint4*)(Pr + 4194304 + e0);
    unsigned au[4] = {a.x, a.y, a.z, a.w};
    unsigned bu[4] = {bq.x, bq.y, bq.z, bq.w};
    unsigned r[4];
    #pragma unroll
    for (int i=0;i<4;++i){
      float alo, ahi, blo, bhi;
      bf2x(au[i], alo, ahi);
      bf2x(bu[i], blo, bhi);
      float lo = (alo + blo) * inv;
      float hi = (ahi + bhi) * inv;
      r[i] = ((unsigned)f2bf(hi) << 16) | (unsigned)f2bf(lo);
    }
    *(uint4*)(Pr + e0) = make_uint4(r[0], r[1], r[2], r[3]);
  }
}

// ------------------------------------------------------------------
// K2G: o2 = rb[4096x1024]_bf16 @ Mt^T -> fp32 WS_HT (raw, no residual).
// Same verified MFMA structure as k4_mfma. grid=512 (128 M x 4 N).
// ------------------------------------------------------------------
__global__ __launch_bounds__(256) void k2g_mfma(float* __restrict__ ws)
{
  __shared__ unsigned short aT[2][32*40];
  __shared__ unsigned short bT[2][64*40];
  const unsigned short* rb = (const unsigned short*)(ws + WS_R);
  const unsigned short* mt = (const unsigned short*)(ws + WS_MT);

  const int tid = threadIdx.x;
  const int M0 = (blockIdx.x >> 2) * 32;
  const int N0 = (blockIdx.x & 3) * 64;
  const int lane = tid & 63;
  const int wid = tid >> 6;
  const int wm = wid >> 1, wn = wid & 1;
  const int m16 = lane & 15, q = lane >> 4;

  const int sa_m = tid >> 3, sa_k = (tid & 7) * 4;
  const int sb_n = tid >> 2, sb_k = (tid & 3) * 8;

  ushort4 ua;
  f4 ub;
  ua = *(const ushort4*)(rb + (size_t)(M0 + sa_m)*1024 + sa_k);
  ub = *(const f4*)(mt + (size_t)(N0 + sb_n)*1024 + sb_k);

  ffrag acc[2];
  acc[0] = (ffrag){0.f,0.f,0.f,0.f};
  acc[1] = (ffrag){0.f,0.f,0.f,0.f};

  for (int ks=0; ks<32; ++ks){
    const int buf = ks & 1;
    *(ushort4*)&aT[buf][sa_m*40 + sa_k] = ua;
    *(f4*)&bT[buf][sb_n*40 + sb_k]      = ub;
    __syncthreads();
    int kn = (ks < 31) ? ks+1 : 31;
    ua = *(const ushort4*)(rb + (size_t)(M0 + sa_m)*1024 + kn*32 + sa_k);
    ub = *(const f4*)(mt + (size_t)(N0 + sb_n)*1024 + kn*32 + sb_k);

    bfrag af, bf0, bf1;
    af  = *(const bfrag*)&aT[buf][(wm*16 + m16)*40 + q*8];
    bf0 = *(const bfrag*)&bT[buf][(wn*32 + m16)*40 + q*8];
    bf1 = *(const bfrag*)&bT[buf][(wn*32 + 16 + m16)*40 + q*8];
    acc[0] = __builtin_amdgcn_mfma_f32_16x16x32_bf16(bf0, af, acc[0], 0, 0, 0);
    acc[1] = __builtin_amdgcn_mfma_f32_16x16x32_bf16(bf1, af, acc[1], 0, 0, 0);
  }

  const int m = M0 + wm*16 + m16;
  #pragma unroll
  for (int j=0;j<2;++j){
    const int n4 = N0 + wn*32 + j*16 + q*4;
    *(f4*)(ws + WS_HT + (size_t)m*256 + n4) =
      make_float4(acc[j][0], acc[j][1], acc[j][2], acc[j][3]);
  }
}

// ------------------------------------------------------------------
// KE: htok = o2 + q_emb (in-place WS_HT), hn = CLN(htok) -> bf16 HNB.
// grid=512 (8 tokens), block=256. (epilogue cloned from verified k2)
// ------------------------------------------------------------------
__global__ __launch_bounds__(256) void ke_ln(
  const float* __restrict__ q_emb, float* __restrict__ ws)
{
  const int tid = threadIdx.x;
  const int p0 = blockIdx.x * 8;
  const int b  = p0 >> 10;
  const int tq = tid >> 5, jq = tid & 31;
  const int cA = 4*jq, cB = 128 + 4*jq;

  float* op = ws + WS_HT + (size_t)(p0+tq)*256;
  f4 oA = *(const f4*)(op + cA);
  f4 oB = *(const f4*)(op + cB);
  f4 qA = *(const f4*)(q_emb + cA);
  f4 qB = *(const f4*)(q_emb + cB);
  float ht[8] = {oA.x+qA.x, oA.y+qA.y, oA.z+qA.z, oA.w+qA.w,
                 oB.x+qB.x, oB.y+qB.y, oB.z+qB.z, oB.w+qB.w};
  float s=0.f, ss=0.f;
  #pragma unroll
  for (int jj=0;jj<8;++jj){ s += ht[jj]; ss = fmaf(ht[jj],ht[jj],ss); }
  s = bfly32(s); ss = bfly32(ss);
  float mean = s*(1.f/256.f);
  float var  = ss*(1.f/256.f) - mean*mean;
  float rsg  = rsqrtf(var + EPSV);
  f4 sH0 = *(const f4*)(ws + WS_SH  + b*256 + cA);
  f4 sH1 = *(const f4*)(ws + WS_SH  + b*256 + cB);
  f4 hH0 = *(const f4*)(ws + WS_SHH + b*256 + cA);
  f4 hH1 = *(const f4*)(ws + WS_SHH + b*256 + cB);
  float sHv[8]  = {sH0.x,sH0.y,sH0.z,sH0.w, sH1.x,sH1.y,sH1.z,sH1.w};
  float hHv[8]  = {hH0.x,hH0.y,hH0.z,hH0.w, hH1.x,hH1.y,hH1.z,hH1.w};
  float hnv[8];
  #pragma unroll
  for (int jj=0;jj<8;++jj)
    hnv[jj] = (ht[jj]-mean)*rsg*(1.f+sHv[jj]) + hHv[jj];

  *(f4*)(op+cA) = make_float4(ht[0],ht[1],ht[2],ht[3]);
  *(f4*)(op+cB) = make_float4(ht[4],ht[5],ht[6],ht[7]);
  unsigned short* hnb = (unsigned short*)(ws + WS_HNB);
  ushort4 uA, uB;
  uA.x=f2bf(hnv[0]); uA.y=f2bf(hnv[1]); uA.z=f2bf(hnv[2]); uA.w=f2bf(hnv[3]);
  uB.x=f2bf(hnv[4]); uB.y=f2bf(hnv[5]); uB.z=f2bf(hnv[6]); uB.w=f2bf(hnv[7]);
  *(ushort4*)(hnb + (size_t)(p0+tq)*256 + cA) = uA;
  *(ushort4*)(hnb + (size_t)(p0+tq)*256 + cB) = uB;
}

// ------------------------------------------------------------------
// K3 MFMA: g_bf16 = gelu(hn_bf16 @ W1 + b1). (round-6 verified)
// ------------------------------------------------------------------
__global__ __launch_bounds__(256) void k3_mfma(
  const float* __restrict__ b1, float* __restrict__ ws)
{
  __shared__ unsigned short aT[2][64*40];
  __shared__ unsigned short bT[2][128*40];
  const unsigned short* hnb = (const unsigned short*)(ws + WS_HNB);
  const unsigned short* w1t = (const unsigned short*)(ws + WS_W1T);
  unsigned short* gb = (unsigned short*)(ws + WS_GB);

  const int tid = threadIdx.x;
  const int M0 = (blockIdx.x >> 3) * 64;
  const int N0 = (blockIdx.x & 7) * 128;
  const int lane = tid & 63;
  const int wid = tid >> 6;
  const int wm = wid >> 1, wn = wid & 1;
  const int m16 = lane & 15, q = lane >> 4;

  const int sa_m = tid >> 2, sa_k = (tid & 3) * 8;
  const int sb_n = tid >> 1, sb_k = (tid & 1) * 16;

  f4 ua, ub0, ub1;
  ua  = *(const f4*)(hnb + (size_t)(M0 + sa_m)*256 + sa_k);
  ub0 = *(const f4*)(w1t + (size_t)(N0 + sb_n)*256 + sb_k);
  ub1 = *(const f4*)(w1t + (size_t)(N0 + sb_n)*256 + sb_k + 8);

  ffrag acc[2][4];
  #pragma unroll
  for (int i=0;i<2;++i)
    #pragma unroll
    for (int j=0;j<4;++j) acc[i][j] = (ffrag){0.f,0.f,0.f,0.f};

  for (int ks=0; ks<8; ++ks){
    const int buf = ks & 1;
    *(f4*)&aT[buf][sa_m*40 + sa_k]     = ua;
    *(f4*)&bT[buf][sb_n*40 + sb_k]     = ub0;
    *(f4*)&bT[buf][sb_n*40 + sb_k + 8] = ub1;
    __syncthreads();
    int kn = (ks < 7) ? ks+1 : 7;
    ua  = *(const f4*)(hnb + (size_t)(M0 + sa_m)*256 + kn*32 + sa_k);
    ub0 = *(const f4*)(w1t + (size_t)(N0 + sb_n)*256 + kn*32 + sb_k);
    ub1 = *(const f4*)(w1t + (size_t)(N0 + sb_n)*256 + kn*32 + sb_k + 8);

    bfrag af[2], bf_[4];
    af[0] = *(const bfrag*)&aT[buf][(wm*32 + m16)*40 + q*8];
    af[1] = *(const bfrag*)&aT[buf][(wm*32 + 16 + m16)*40 + q*8];
    #pragma unroll
    for (int j=0;j<4;++j)
      bf_[j] = *(const bfrag*)&bT[buf][(wn*64 + j*16 + m16)*40 + q*8];
    #pragma unroll
    for (int i=0;i<2;++i)
      #pragma unroll
      for (int j=0;j<4;++j)
        acc[i][j] = __builtin_amdgcn_mfma_f32_16x16x32_bf16(bf_[j], af[i], acc[i][j], 0, 0, 0);
  }

  #pragma unroll
  for (int i=0;i<2;++i){
    const int m = M0 + wm*32 + i*16 + m16;
    #pragma unroll
    for (int j=0;j<4;++j){
      const int n4 = N0 + wn*64 + j*16 + q*4;
      f4 bv = *(const f4*)(b1 + n4);
      ushort4 u;
      u.x = f2bf(gelu_fast(acc[i][j][0] + bv.x));
      u.y = f2bf(gelu_fast(acc[i][j][1] + bv.y));
      u.z = f2bf(gelu_fast(acc[i][j][2] + bv.z));
      u.w = f2bf(gelu_fast(acc[i][j][3] + bv.w));
      *(ushort4*)(gb + (size_t)m*1024 + n4) = u;
    }
  }
}

// ------------------------------------------------------------------
// K4 MFMA: out = htok + g_bf16 @ W2 + b2. (round-6 verified)
// ------------------------------------------------------------------
__global__ __launch_bounds__(256) void k4_mfma(
  const float* __restrict__ b2, const float* __restrict__ ws_c,
  float* __restrict__ ws, float* __restrict__ out)
{
  __shared__ unsigned short aT[2][32*40];
  __shared__ unsigned short bT[2][64*40];
  const unsigned short* gb  = (const unsigned short*)(ws_c + WS_GB);
  const unsigned short* w2t = (const unsigned short*)(ws_c + WS_W2T);

  const int tid = threadIdx.x;
  const int M0 = (blockIdx.x >> 2) * 32;
  const int N0 = (blockIdx.x & 3) * 64;
  const int lane = tid & 63;
  const int wid = tid >> 6;
  const int wm = wid >> 1, wn = wid & 1;
  const int m16 = lane & 15, q = lane >> 4;

  const int sa_m = tid >> 3, sa_k = (tid & 7) * 4;
  const int sb_n = tid >> 2, sb_k = (tid & 3) * 8;

  ushort4 ua;
  f4 ub;
  ua = *(const ushort4*)(gb  + (size_t)(M0 + sa_m)*1024 + sa_k);
  ub = *(const f4*)(w2t + (size_t)(N0 + sb_n)*1024 + sb_k);

  ffrag acc[2];
  acc[0] = (ffrag){0.f,0.f,0.f,0.f};
  acc[1] = (ffrag){0.f,0.f,0.f,0.f};

  for (int ks=0; ks<32; ++ks){
    const int buf = ks & 1;
    *(ushort4*)&aT[buf][sa_m*40 + sa_k] = ua;
    *(f4*)&bT[buf][sb_n*40 + sb_k]      = ub;
    __syncthreads();
    int kn = (ks < 31) ? ks+1 : 31;
    ua = *(const ushort4*)(gb  + (size_t)(M0 + sa_m)*1024 + kn*32 + sa_k);
    ub = *(const f4*)(w2t + (size_t)(N0 + sb_n)*1024 + kn*32 + sb_k);

    bfrag af, bf0, bf1;
    af  = *(const bfrag*)&aT[buf][(wm*16 + m16)*40 + q*8];
    bf0 = *(const bfrag*)&bT[buf][(wn*32 + m16)*40 + q*8];
    bf1 = *(const bfrag*)&bT[buf][(wn*32 + 16 + m16)*40 + q*8];
    acc[0] = __builtin_amdgcn_mfma_f32_16x16x32_bf16(bf0, af, acc[0], 0, 0, 0);
    acc[1] = __builtin_amdgcn_mfma_f32_16x16x32_bf16(bf1, af, acc[1], 0, 0, 0);
  }

  const int m = M0 + wm*16 + m16;
  #pragma unroll
  for (int j=0;j<2;++j){
    const int n4 = N0 + wn*32 + j*16 + q*4;
    f4 bv = *(const f4*)(b2 + n4);
    f4 hv = *(const f4*)(ws + WS_HT + (size_t)m*256 + n4);
    *(f4*)(out + (size_t)m*256 + n4) =
      make_float4(acc[j][0]+bv.x+hv.x, acc[j][1]+bv.y+hv.y,
                  acc[j][2]+bv.z+hv.z, acc[j][3]+bv.w+hv.w);
  }
}

// ------------------------------------------------------------------
extern "C" void kernel_launch(void* const* d_in, const int* in_sizes, int n_in,
                              void* d_out, int out_size, void* d_ws, size_t ws_size,
                              hipStream_t stream)
{
  const float* x    = (const float*)d_in[0];
  const int*   idx  = (const int*)  d_in[1];
  const float* ctx  = (const float*)d_in[2];
  const float* Wp   = (const float*)d_in[3];
  const float* Bp   = (const float*)d_in[4];
  const float* qemb = (const float*)d_in[5];
  const float* Wkv  = (const float*)d_in[6];
  const float* bkv  = (const float*)d_in[7];
  const float* Wqc  = (const float*)d_in[8];
  const float* bqc  = (const float*)d_in[9];
  const float* Whc  = (const float*)d_in[10];
  const float* bhc  = (const float*)d_in[11];
  const float* Wq   = (const float*)d_in[12];
  const float* Wk   = (const float*)d_in[13];
  const float* Wv   = (const float*)d_in[14];
  const float* Wo   = (const float*)d_in[15];
  const float* W1   = (const float*)d_in[16];
  const float* b1   = (const float*)d_in[17];
  const float* W2   = (const float*)d_in[18];
  const float* b2   = (const float*)d_in[19];
  float* ws  = (float*)d_ws;
  float* out = (float*)d_out;

  hipLaunchKernelGGL(kw_conv,  dim3(128),  dim3(256), 0, stream, W1, W2, ws);
  hipLaunchKernelGGL(km_conv,  dim3(256),  dim3(256), 0, stream, Wv, Wo, ws);
  hipLaunchKernelGGL(k0_all,   dim3(16),   dim3(256), 0, stream,
                     ctx, qemb, Wkv, bkv, Wqc, bqc, Whc, bhc, Wq, Wk, ws);
  hipLaunchKernelGGL(k1f_attn, dim3(1024), dim3(256), 0, stream, x, idx, Wp, Bp, ws);
  hipLaunchKernelGGL(kc_comb,  dim3(512),  dim3(256), 0, stream, ws);
  hipLaunchKernelGGL(k2g_mfma, dim3(512),  dim3(256), 0, stream, ws);
  hipLaunchKernelGGL(ke_ln,    dim3(512),  dim3(256), 0, stream, qemb, ws);
  hipLaunchKernelGGL(k3_mfma,  dim3(512),  dim3(256), 0, stream, b1, ws);
  hipLaunchKernelGGL(k4_mfma,  dim3(512),  dim3(256), 0, stream, b2, ws, ws, out);
}

// Round 8
// 193.849 us; speedup vs baseline: 2.8037x; 1.0456x over previous
//
#include <hip/hip_runtime.h>
#include <cmath>

#define EPSV 1e-5f
using f4 = float4;

typedef __attribute__((ext_vector_type(8))) short bfrag;   // 8 bf16 (4 VGPRs)
typedef __attribute__((ext_vector_type(4))) float ffrag;   // 4 fp32 acc

// ---- ws layout (float offsets) ----
#define WS_SKV   0           // [4][256]
#define WS_SHKV  1024        // [4][256]
#define WS_SH    2048        // [4][256]
#define WS_SHH   3072        // [4][256]
#define WS_A     4096        // [4][4][256]
#define WS_R     8192        // ushort view: racc partials [2][4096][4][256] bf16
#define WS_HT    4202496     // [4096][256] fp32: o2 then htok (ke in-place)
#define WS_L     5251072     // [2][4096][4] fp32 l partials
#define WS_G     6299648
#define WS_GB    WS_G                   // ushort[4096*1024]  g bf16
#define WS_HNB   (WS_G + 2097152)       // ushort[4096*256]   hn bf16
#define WS_W1T   (WS_G + 2621440)       // ushort[1024*256]   W1^T bf16 [n][k]
#define WS_W2T   (WS_G + 2752512)       // ushort[256*1024]   W2^T bf16 [n][k]
#define WS_MT    (WS_G + 2883584)       // ushort[256*1024]   M^T bf16 [j][h*256+d]

#define FMA8(acc, s, wa, wb) \
  acc[0]=fmaf((s),(wa).x,acc[0]); acc[1]=fmaf((s),(wa).y,acc[1]); \
  acc[2]=fmaf((s),(wa).z,acc[2]); acc[3]=fmaf((s),(wa).w,acc[3]); \
  acc[4]=fmaf((s),(wb).x,acc[4]); acc[5]=fmaf((s),(wb).y,acc[5]); \
  acc[6]=fmaf((s),(wb).z,acc[6]); acc[7]=fmaf((s),(wb).w,acc[7]);

#define DOT8(res, v, wa, wb) \
  res = fmaf((v)[0],(wa).x,res); res = fmaf((v)[1],(wa).y,res); \
  res = fmaf((v)[2],(wa).z,res); res = fmaf((v)[3],(wa).w,res); \
  res = fmaf((v)[4],(wb).x,res); res = fmaf((v)[5],(wb).y,res); \
  res = fmaf((v)[6],(wb).z,res); res = fmaf((v)[7],(wb).w,res);

__device__ __forceinline__ float bfly32(float v){
  v += __shfl_xor(v, 1);  v += __shfl_xor(v, 2);  v += __shfl_xor(v, 4);
  v += __shfl_xor(v, 8);  v += __shfl_xor(v, 16);
  return v;
}

// DPP-based 32-lane allreduce: 4 VALU cross-lane steps (no LDS pipe)
// + one ds_swizzle for the cross-row xor16. Codes: quad_perm[1,0,3,2]=0xB1,
// quad_perm[2,3,0,1]=0x4E, row_ror:4=0x124, row_ror:8=0x128. ror-based
// reduce is valid for commutative add (every lane accumulates all 4 quads).
template<int CTRL>
__device__ __forceinline__ float dpp_add(float v){
  int x = __builtin_bit_cast(int, v);
  int y = __builtin_amdgcn_update_dpp(0, x, CTRL, 0xf, 0xf, true);
  return v + __builtin_bit_cast(float, y);
}
__device__ __forceinline__ float red32(float v){
  v = dpp_add<0xB1>(v);
  v = dpp_add<0x4E>(v);
  v = dpp_add<0x124>(v);
  v = dpp_add<0x128>(v);
  v += __shfl_xor(v, 16);
  return v;
}

__device__ __forceinline__ float gelu_fast(float x){
  float z2 = 1.5957691216057308f*(x + 0.044715f*x*x*x);
  return x / (1.0f + __expf(-z2));
}

__device__ __forceinline__ unsigned short f2bf(float x){
  union { float f; unsigned u; } v; v.f = x;
  unsigned r = v.u + 0x7fffu + ((v.u >> 16) & 1u);
  return (unsigned short)(r >> 16);
}
__device__ __forceinline__ float bfu(unsigned short u){
  union { unsigned u; float f; } v; v.u = ((unsigned)u) << 16; return v.f;
}
__device__ __forceinline__ ushort4 comb4(ushort4 a, ushort4 b, float inv){
  ushort4 r;
  r.x = f2bf((bfu(a.x)+bfu(b.x))*inv);
  r.y = f2bf((bfu(a.y)+bfu(b.y))*inv);
  r.z = f2bf((bfu(a.z)+bfu(b.z))*inv);
  r.w = f2bf((bfu(a.w)+bfu(b.w))*inv);
  return r;
}

// ------------------------------------------------------------------
// KWM: merged weight prep. blk<128: W1/W2 convert+transpose (verified
// kw body). blk>=128: M^T = Wv@Wo per head (verified km body).
// grid=384, block=256.
// ------------------------------------------------------------------
__global__ __launch_bounds__(256) void kwm_conv(
  const float* __restrict__ W1, const float* __restrict__ W2,
  const float* __restrict__ Wv, const float* __restrict__ Wo,
  float* __restrict__ ws)
{
  const int tid = threadIdx.x;
  int blk = blockIdx.x;
  if (blk < 128){
    __shared__ unsigned short lt[64][68];
    const float* src; unsigned short* dst; int K, N, K0, N0;
    if (blk < 64){
      src = W1; dst = (unsigned short*)(ws + WS_W1T);
      K = 256; N = 1024; K0 = (blk >> 4)*64; N0 = (blk & 15)*64;
    } else {
      blk -= 64;
      src = W2; dst = (unsigned short*)(ws + WS_W2T);
      K = 1024; N = 256; K0 = (blk >> 2)*64; N0 = (blk & 3)*64;
    }
    #pragma unroll
    for (int i=0;i<4;++i){
      int r = i*16 + (tid>>4);
      int c = (tid&15)*4;
      f4 v = *(const f4*)(src + (size_t)(K0+r)*N + N0 + c);
      lt[r][c]   = f2bf(v.x); lt[r][c+1] = f2bf(v.y);
      lt[r][c+2] = f2bf(v.z); lt[r][c+3] = f2bf(v.w);
    }
    __syncthreads();
    #pragma unroll
    for (int i=0;i<4;++i){
      int n  = i*16 + (tid>>4);
      int kc = (tid&15)*4;
      ushort4 u;
      u.x = lt[kc][n]; u.y = lt[kc+1][n]; u.z = lt[kc+2][n]; u.w = lt[kc+3][n];
      *(ushort4*)(dst + (size_t)(N0+n)*K + K0 + kc) = u;
    }
  } else {
    blk -= 128;
    __shared__ float wvs[4*64];
    __shared__ float wos[64*256];
    const int h   = blk >> 6;
    const int dg4 = blk & 63;
    {
      int d = tid >> 6, e = tid & 63;
      wvs[d*64+e] = Wv[(size_t)(dg4*4 + d)*256 + h*64 + e];
    }
    {
      int e = tid >> 2, c = (tid & 3)*64;
      const float* src = Wo + (size_t)(h*64 + e)*256 + c;
      #pragma unroll
      for (int i=0;i<16;++i)
        *(f4*)&wos[e*256 + c + i*4] = *(const f4*)(src + i*4);
    }
    __syncthreads();
    float acc[4] = {};
    for (int e=0;e<64;++e){
      float wo = wos[e*256 + tid];
      acc[0] = fmaf(wvs[0*64+e], wo, acc[0]);
      acc[1] = fmaf(wvs[1*64+e], wo, acc[1]);
      acc[2] = fmaf(wvs[2*64+e], wo, acc[2]);
      acc[3] = fmaf(wvs[3*64+e], wo, acc[3]);
    }
    unsigned short* Mt = (unsigned short*)(ws + WS_MT);
    ushort4 u;
    u.x = f2bf(acc[0]); u.y = f2bf(acc[1]); u.z = f2bf(acc[2]); u.w = f2bf(acc[3]);
    *(ushort4*)(Mt + (size_t)tid*1024 + h*256 + dg4*4) = u;
  }
}

// ------------------------------------------------------------------
// K0: merged per-(b,h) setup (round-5/6/7 verified). grid=16, block=256.
// ------------------------------------------------------------------
__global__ __launch_bounds__(256) void k0_all(
    const float* __restrict__ ctx, const float* __restrict__ q_emb,
    const float* __restrict__ Wkv, const float* __restrict__ bkv,
    const float* __restrict__ Wqc, const float* __restrict__ bqc,
    const float* __restrict__ Whc, const float* __restrict__ bhc,
    const float* __restrict__ Wq,  const float* __restrict__ Wk,
    float* __restrict__ ws)
{
  const int b = blockIdx.x >> 2, h = blockIdx.x & 3;
  const int tid = threadIdx.x;
  __shared__ float c[64], qn[256], ph[256], qh64[64], red[8];
  if (tid < 64) c[tid] = ctx[b*64 + tid];
  __syncthreads();

  float skv = bkv[tid],      shkv = bkv[256+tid];
  float sq  = bqc[tid],      shq  = bqc[256+tid];
  float sh  = bhc[tid],      shh  = bhc[256+tid];
  #pragma unroll 8
  for (int j=0;j<64;++j){
    float cj = c[j];
    skv  = fmaf(cj, Wkv[j*512 + tid],       skv);
    shkv = fmaf(cj, Wkv[j*512 + 256 + tid], shkv);
    sq   = fmaf(cj, Wqc[j*512 + tid],       sq);
    shq  = fmaf(cj, Wqc[j*512 + 256 + tid], shq);
    sh   = fmaf(cj, Whc[j*512 + tid],       sh);
    shh  = fmaf(cj, Whc[j*512 + 256 + tid], shh);
  }
  if (h == 0){
    ws[WS_SKV  + b*256 + tid] = skv;
    ws[WS_SHKV + b*256 + tid] = shkv;
    ws[WS_SH   + b*256 + tid] = sh;
    ws[WS_SHH  + b*256 + tid] = shh;
  }

  float qe = q_emb[tid];
  float s1r = qe, s2r = qe*qe;
  for (int mm=1;mm<64;mm<<=1){ s1r += __shfl_xor(s1r,mm); s2r += __shfl_xor(s2r,mm); }
  int wv = tid>>6, ln = tid&63;
  if (ln==0){ red[wv*2]=s1r; red[wv*2+1]=s2r; }
  __syncthreads();
  float S1 = red[0]+red[2]+red[4]+red[6];
  float S2 = red[1]+red[3]+red[5]+red[7];
  float mean = S1*(1.0f/256.0f);
  float var  = S2*(1.0f/256.0f) - mean*mean;
  float rs   = rsqrtf(var + EPSV);
  qn[tid] = (qe-mean)*rs*(1.0f+sq) + shq;
  __syncthreads();

  {
    const int t = tid & 63, ks = tid >> 6;
    float p = 0.f;
    const float* wq = Wq + (size_t)(ks*64)*256 + h*64 + t;
    #pragma unroll 8
    for (int d=0; d<64; ++d) p = fmaf(qn[ks*64+d], wq[d*256], p);
    ph[tid] = p;
  }
  __syncthreads();
  if (tid < 64) qh64[tid] = ph[tid] + ph[64+tid] + ph[128+tid] + ph[192+tid];
  __syncthreads();

  {
    float a = 0.f;
    const float* wkr = Wk + (size_t)tid*256 + h*64;
    #pragma unroll
    for (int e4=0; e4<16; ++e4){
      f4 wv4 = *(const f4*)(wkr + e4*4);
      a = fmaf(qh64[e4*4+0], wv4.x, a);
      a = fmaf(qh64[e4*4+1], wv4.y, a);
      a = fmaf(qh64[e4*4+2], wv4.z, a);
      a = fmaf(qh64[e4*4+3], wv4.w, a);
    }
    ws[WS_A + b*1024 + h*256 + tid] = 0.125f*a;
  }
}

// ------------------------------------------------------------------
// K1F v3: round-7 structure + (a) As hoisted to registers (f-invariant),
// (b) DPP reductions (red32) instead of 5x ds_swizzle butterflies.
// grid=1024 = 512 token-tiles x 2 f-halves, block=256.
// ------------------------------------------------------------------
__global__ __launch_bounds__(256,4) void k1f_attn(
  const float* __restrict__ x, const int* __restrict__ idx,
  const float* __restrict__ Wp, const float* __restrict__ Bp,
  float* __restrict__ ws)
{
  __shared__ float xs[2048];      // [t][256]
  __shared__ float wls[4096];     // [2 f][8 i][256 d]

  const int tid = threadIdx.x;
  const int p0  = (blockIdx.x >> 1) * 8;
  const int half= blockIdx.x & 1;
  const int f0  = half * 16;
  const int b   = p0 >> 10;
  const int t   = tid >> 5;
  const int dg  = tid & 31;
  const int dA  = 4*dg, dB = 128 + 4*dg;

  {
    const float* xg = x + (size_t)p0*256 + tid*8;
    f4 a  = *(const f4*)xg;
    f4 bq = *(const f4*)(xg + 4);
    *(f4*)&xs[tid*8]     = a;
    *(f4*)&xs[tid*8 + 4] = bq;
  }
  // As hoisted into registers (f-invariant): Ar[h][0]=A[h][dA..], [1]=A[h][dB..]
  f4 Ar[4][2];
  #pragma unroll
  for (int h=0;h<4;++h){
    Ar[h][0] = *(const f4*)(ws + WS_A + b*1024 + h*256 + dA);
    Ar[h][1] = *(const f4*)(ws + WS_A + b*1024 + h*256 + dB);
  }

  f4 skA = *(const f4*)(ws + WS_SKV  + b*256 + dA);
  f4 skB = *(const f4*)(ws + WS_SKV  + b*256 + dB);
  f4 shA = *(const f4*)(ws + WS_SHKV + b*256 + dA);
  f4 shB = *(const f4*)(ws + WS_SHKV + b*256 + dB);
  float coef[8] = {1.f+skA.x,1.f+skA.y,1.f+skA.z,1.f+skA.w,
                   1.f+skB.x,1.f+skB.y,1.f+skB.z,1.f+skB.w};
  float shk[8]  = {shA.x,shA.y,shA.z,shA.w, shB.x,shB.y,shB.z,shB.w};

  int r0 = idx[f0], r1 = idx[f0+1];
  f4 u0 = *(const f4*)(Wp + (size_t)r0*2048 + tid*8);
  f4 u1 = *(const f4*)(Wp + (size_t)r0*2048 + tid*8 + 4);
  f4 u2 = *(const f4*)(Wp + (size_t)r1*2048 + tid*8);
  f4 u3 = *(const f4*)(Wp + (size_t)r1*2048 + tid*8 + 4);

  float l[4] = {0.f,0.f,0.f,0.f};
  float racc[4][8] = {};

  for (int fi = 0; fi < 8; ++fi){
    const int f = f0 + fi*2;
    __syncthreads();
    wls[0*256+tid]=u0.x; wls[1*256+tid]=u0.y; wls[2*256+tid]=u0.z; wls[3*256+tid]=u0.w;
    wls[4*256+tid]=u1.x; wls[5*256+tid]=u1.y; wls[6*256+tid]=u1.z; wls[7*256+tid]=u1.w;
    wls[2048+0*256+tid]=u2.x; wls[2048+1*256+tid]=u2.y;
    wls[2048+2*256+tid]=u2.z; wls[2048+3*256+tid]=u2.w;
    wls[2048+4*256+tid]=u3.x; wls[2048+5*256+tid]=u3.y;
    wls[2048+6*256+tid]=u3.z; wls[2048+7*256+tid]=u3.w;
    __syncthreads();

    f4 ba0 = *(const f4*)(Bp + (size_t)r0*256 + dA);
    f4 bb0 = *(const f4*)(Bp + (size_t)r0*256 + dB);
    f4 ba1 = *(const f4*)(Bp + (size_t)r1*256 + dA);
    f4 bb1 = *(const f4*)(Bp + (size_t)r1*256 + dB);

    const int fn = (fi < 7) ? f + 2 : f0;
    int rn0 = idx[fn], rn1 = idx[fn+1];
    u0 = *(const f4*)(Wp + (size_t)rn0*2048 + tid*8);
    u1 = *(const f4*)(Wp + (size_t)rn0*2048 + tid*8 + 4);
    u2 = *(const f4*)(Wp + (size_t)rn1*2048 + tid*8);
    u3 = *(const f4*)(Wp + (size_t)rn1*2048 + tid*8 + 4);

    #pragma unroll
    for (int sub=0; sub<2; ++sub){
      const float* wrow = wls + sub*2048;
      const int fc = f + sub;
      f4 ba = sub ? ba1 : ba0;
      f4 bb = sub ? bb1 : bb0;

      f4 xa = *(const f4*)&xs[t*256 + fc*8];
      f4 xb = *(const f4*)&xs[t*256 + fc*8 + 4];
      float xf[8] = {xa.x,xa.y,xa.z,xa.w, xb.x,xb.y,xb.z,xb.w};

      float val[8] = {};
      #pragma unroll
      for (int i=0;i<8;++i){
        f4 wa  = *(const f4*)&wrow[i*256 + dA];
        f4 wbv = *(const f4*)&wrow[i*256 + dB];
        FMA8(val, xf[i], wa, wbv);
      }

      float s=0.f, ss=0.f;
      #pragma unroll
      for (int jj=0;jj<8;++jj){ s += val[jj]; ss = fmaf(val[jj],val[jj],ss); }
      s = red32(s); ss = red32(ss);
      float mean = s*(1.f/256.f);
      float var  = ss*(1.f/256.f) - mean*mean;
      float rsg  = rsqrtf(var + EPSV);
      float mrs  = mean*rsg;

      float off[8] = {shk[0]+ba.x, shk[1]+ba.y, shk[2]+ba.z, shk[3]+ba.w,
                      shk[4]+bb.x, shk[5]+bb.y, shk[6]+bb.z, shk[7]+bb.w};
      float kvl[8];
      #pragma unroll
      for (int jj=0;jj<8;++jj)
        kvl[jj] = fmaf(fmaf(val[jj], rsg, -mrs), coef[jj], off[jj]);

      #pragma unroll
      for (int h=0;h<4;++h){
        float lg = 0.f;
        DOT8(lg, kvl, Ar[h][0], Ar[h][1]);
        lg = red32(lg);
        float pp = __expf(lg);
        l[h] += pp;
        #pragma unroll
        for (int jj=0;jj<8;++jj)
          racc[h][jj] = fmaf(pp, kvl[jj], racc[h][jj]);
      }
    }
    r0 = rn0; r1 = rn1;
  }

  unsigned short* Pr = (unsigned short*)(ws + WS_R);
  size_t base = (size_t)(half*4096 + p0 + t) * 1024;
  #pragma unroll
  for (int h=0;h<4;++h){
    ushort4 ua, ub;
    ua.x=f2bf(racc[h][0]); ua.y=f2bf(racc[h][1]); ua.z=f2bf(racc[h][2]); ua.w=f2bf(racc[h][3]);
    ub.x=f2bf(racc[h][4]); ub.y=f2bf(racc[h][5]); ub.z=f2bf(racc[h][6]); ub.w=f2bf(racc[h][7]);
    *(ushort4*)(Pr + base + h*256 + dA) = ua;
    *(ushort4*)(Pr + base + h*256 + dB) = ub;
  }
  if (dg == 0){
    float* Lp = ws + WS_L;
    #pragma unroll
    for (int h=0;h<4;++h) Lp[(size_t)(half*4096 + p0 + t)*4 + h] = l[h];
  }
}

// ------------------------------------------------------------------
// K2G v2: o2 = ((P0+P1)/l)_bf16 @ Mt^T -> fp32 WS_HT. The kc combine
// is folded into the A-staging path (h = ks>>3 is slice-uniform;
// inv per (t,h) precomputed in LDS). grid=512 (128 M x 4 N).
// ------------------------------------------------------------------
__global__ __launch_bounds__(256) void k2g_mfma(float* __restrict__ ws)
{
  __shared__ unsigned short aT[2][32*40];
  __shared__ unsigned short bT[2][64*40];
  __shared__ float invs[128];            // [32 t][4 h]
  const unsigned short* P0 = (const unsigned short*)(ws + WS_R);
  const unsigned short* P1 = P0 + 4194304;
  const unsigned short* mt = (const unsigned short*)(ws + WS_MT);
  const float* Lp = ws + WS_L;

  const int tid = threadIdx.x;
  const int M0 = (blockIdx.x >> 2) * 32;
  const int N0 = (blockIdx.x & 3) * 64;
  const int lane = tid & 63;
  const int wid = tid >> 6;
  const int wm = wid >> 1, wn = wid & 1;
  const int m16 = lane & 15, q = lane >> 4;

  const int sa_m = tid >> 3, sa_k = (tid & 7) * 4;
  const int sb_n = tid >> 2, sb_k = (tid & 3) * 8;

  if (tid < 128){
    int lt = tid >> 2, h = tid & 3;
    invs[tid] = 1.f / (Lp[(size_t)(M0 + lt)*4 + h] +
                       Lp[(size_t)(4096 + M0 + lt)*4 + h]);
  }

  ushort4 ua0 = *(const ushort4*)(P0 + (size_t)(M0 + sa_m)*1024 + sa_k);
  ushort4 ua1 = *(const ushort4*)(P1 + (size_t)(M0 + sa_m)*1024 + sa_k);
  f4 ub = *(const f4*)(mt + (size_t)(N0 + sb_n)*1024 + sb_k);
  __syncthreads();   // invs visible before first staging write

  ffrag acc[2];
  acc[0] = (ffrag){0.f,0.f,0.f,0.f};
  acc[1] = (ffrag){0.f,0.f,0.f,0.f};

  for (int ks=0; ks<32; ++ks){
    const int buf = ks & 1;
    float inv = invs[sa_m*4 + (ks >> 3)];
    *(ushort4*)&aT[buf][sa_m*40 + sa_k] = comb4(ua0, ua1, inv);
    *(f4*)&bT[buf][sb_n*40 + sb_k]      = ub;
    __syncthreads();
    int kn = (ks < 31) ? ks+1 : 31;
    ua0 = *(const ushort4*)(P0 + (size_t)(M0 + sa_m)*1024 + kn*32 + sa_k);
    ua1 = *(const ushort4*)(P1 + (size_t)(M0 + sa_m)*1024 + kn*32 + sa_k);
    ub  = *(const f4*)(mt + (size_t)(N0 + sb_n)*1024 + kn*32 + sb_k);

    bfrag af, bf0, bf1;
    af  = *(const bfrag*)&aT[buf][(wm*16 + m16)*40 + q*8];
    bf0 = *(const bfrag*)&bT[buf][(wn*32 + m16)*40 + q*8];
    bf1 = *(const bfrag*)&bT[buf][(wn*32 + 16 + m16)*40 + q*8];
    acc[0] = __builtin_amdgcn_mfma_f32_16x16x32_bf16(bf0, af, acc[0], 0, 0, 0);
    acc[1] = __builtin_amdgcn_mfma_f32_16x16x32_bf16(bf1, af, acc[1], 0, 0, 0);
  }

  const int m = M0 + wm*16 + m16;
  #pragma unroll
  for (int j=0;j<2;++j){
    const int n4 = N0 + wn*32 + j*16 + q*4;
    *(f4*)(ws + WS_HT + (size_t)m*256 + n4) =
      make_float4(acc[j][0], acc[j][1], acc[j][2], acc[j][3]);
  }
}

// ------------------------------------------------------------------
// KE: htok = o2 + q_emb (in-place WS_HT), hn = CLN(htok) -> bf16 HNB.
// grid=512 (8 tokens), block=256. (round-7 verified)
// ------------------------------------------------------------------
__global__ __launch_bounds__(256) void ke_ln(
  const float* __restrict__ q_emb, float* __restrict__ ws)
{
  const int tid = threadIdx.x;
  const int p0 = blockIdx.x * 8;
  const int b  = p0 >> 10;
  const int tq = tid >> 5, jq = tid & 31;
  const int cA = 4*jq, cB = 128 + 4*jq;

  float* op = ws + WS_HT + (size_t)(p0+tq)*256;
  f4 oA = *(const f4*)(op + cA);
  f4 oB = *(const f4*)(op + cB);
  f4 qA = *(const f4*)(q_emb + cA);
  f4 qB = *(const f4*)(q_emb + cB);
  float ht[8] = {oA.x+qA.x, oA.y+qA.y, oA.z+qA.z, oA.w+qA.w,
                 oB.x+qB.x, oB.y+qB.y, oB.z+qB.z, oB.w+qB.w};
  float s=0.f, ss=0.f;
  #pragma unroll
  for (int jj=0;jj<8;++jj){ s += ht[jj]; ss = fmaf(ht[jj],ht[jj],ss); }
  s = bfly32(s); ss = bfly32(ss);
  float mean = s*(1.f/256.f);
  float var  = ss*(1.f/256.f) - mean*mean;
  float rsg  = rsqrtf(var + EPSV);
  f4 sH0 = *(const f4*)(ws + WS_SH  + b*256 + cA);
  f4 sH1 = *(const f4*)(ws + WS_SH  + b*256 + cB);
  f4 hH0 = *(const f4*)(ws + WS_SHH + b*256 + cA);
  f4 hH1 = *(const f4*)(ws + WS_SHH + b*256 + cB);
  float sHv[8]  = {sH0.x,sH0.y,sH0.z,sH0.w, sH1.x,sH1.y,sH1.z,sH1.w};
  float hHv[8]  = {hH0.x,hH0.y,hH0.z,hH0.w, hH1.x,hH1.y,hH1.z,hH1.w};
  float hnv[8];
  #pragma unroll
  for (int jj=0;jj<8;++jj)
    hnv[jj] = (ht[jj]-mean)*rsg*(1.f+sHv[jj]) + hHv[jj];

  *(f4*)(op+cA) = make_float4(ht[0],ht[1],ht[2],ht[3]);
  *(f4*)(op+cB) = make_float4(ht[4],ht[5],ht[6],ht[7]);
  unsigned short* hnb = (unsigned short*)(ws + WS_HNB);
  ushort4 uA, uB;
  uA.x=f2bf(hnv[0]); uA.y=f2bf(hnv[1]); uA.z=f2bf(hnv[2]); uA.w=f2bf(hnv[3]);
  uB.x=f2bf(hnv[4]); uB.y=f2bf(hnv[5]); uB.z=f2bf(hnv[6]); uB.w=f2bf(hnv[7]);
  *(ushort4*)(hnb + (size_t)(p0+tq)*256 + cA) = uA;
  *(ushort4*)(hnb + (size_t)(p0+tq)*256 + cB) = uB;
}

// ------------------------------------------------------------------
// K3 MFMA: g_bf16 = gelu(hn_bf16 @ W1 + b1). (round-6/7 verified)
// ------------------------------------------------------------------
__global__ __launch_bounds__(256) void k3_mfma(
  const float* __restrict__ b1, float* __restrict__ ws)
{
  __shared__ unsigned short aT[2][64*40];
  __shared__ unsigned short bT[2][128*40];
  const unsigned short* hnb = (const unsigned short*)(ws + WS_HNB);
  const unsigned short* w1t = (const unsigned short*)(ws + WS_W1T);
  unsigned short* gb = (unsigned short*)(ws + WS_GB);

  const int tid = threadIdx.x;
  const int M0 = (blockIdx.x >> 3) * 64;
  const int N0 = (blockIdx.x & 7) * 128;
  const int lane = tid & 63;
  const int wid = tid >> 6;
  const int wm = wid >> 1, wn = wid & 1;
  const int m16 = lane & 15, q = lane >> 4;

  const int sa_m = tid >> 2, sa_k = (tid & 3) * 8;
  const int sb_n = tid >> 1, sb_k = (tid & 1) * 16;

  f4 ua, ub0, ub1;
  ua  = *(const f4*)(hnb + (size_t)(M0 + sa_m)*256 + sa_k);
  ub0 = *(const f4*)(w1t + (size_t)(N0 + sb_n)*256 + sb_k);
  ub1 = *(const f4*)(w1t + (size_t)(N0 + sb_n)*256 + sb_k + 8);

  ffrag acc[2][4];
  #pragma unroll
  for (int i=0;i<2;++i)
    #pragma unroll
    for (int j=0;j<4;++j) acc[i][j] = (ffrag){0.f,0.f,0.f,0.f};

  for (int ks=0; ks<8; ++ks){
    const int buf = ks & 1;
    *(f4*)&aT[buf][sa_m*40 + sa_k]     = ua;
    *(f4*)&bT[buf][sb_n*40 + sb_k]     = ub0;
    *(f4*)&bT[buf][sb_n*40 + sb_k + 8] = ub1;
    __syncthreads();
    int kn = (ks < 7) ? ks+1 : 7;
    ua  = *(const f4*)(hnb + (size_t)(M0 + sa_m)*256 + kn*32 + sa_k);
    ub0 = *(const f4*)(w1t + (size_t)(N0 + sb_n)*256 + kn*32 + sb_k);
    ub1 = *(const f4*)(w1t + (size_t)(N0 + sb_n)*256 + kn*32 + sb_k + 8);

    bfrag af[2], bf_[4];
    af[0] = *(const bfrag*)&aT[buf][(wm*32 + m16)*40 + q*8];
    af[1] = *(const bfrag*)&aT[buf][(wm*32 + 16 + m16)*40 + q*8];
    #pragma unroll
    for (int j=0;j<4;++j)
      bf_[j] = *(const bfrag*)&bT[buf][(wn*64 + j*16 + m16)*40 + q*8];
    #pragma unroll
    for (int i=0;i<2;++i)
      #pragma unroll
      for (int j=0;j<4;++j)
        acc[i][j] = __builtin_amdgcn_mfma_f32_16x16x32_bf16(bf_[j], af[i], acc[i][j], 0, 0, 0);
  }

  #pragma unroll
  for (int i=0;i<2;++i){
    const int m = M0 + wm*32 + i*16 + m16;
    #pragma unroll
    for (int j=0;j<4;++j){
      const int n4 = N0 + wn*64 + j*16 + q*4;
      f4 bv = *(const f4*)(b1 + n4);
      ushort4 u;
      u.x = f2bf(gelu_fast(acc[i][j][0] + bv.x));
      u.y = f2bf(gelu_fast(acc[i][j][1] + bv.y));
      u.z = f2bf(gelu_fast(acc[i][j][2] + bv.z));
      u.w = f2bf(gelu_fast(acc[i][j][3] + bv.w));
      *(ushort4*)(gb + (size_t)m*1024 + n4) = u;
    }
  }
}

// ------------------------------------------------------------------
// K4 MFMA: out = htok + g_bf16 @ W2 + b2. (round-6/7 verified)
// ------------------------------------------------------------------
__global__ __launch_bounds__(256) void k4_mfma(
  const float* __restrict__ b2, const float* __restrict__ ws_c,
  float* __restrict__ ws, float* __restrict__ out)
{
  __shared__ unsigned short aT[2][32*40];
  __shared__ unsigned short bT[2][64*40];
  const unsigned short* gb  = (const unsigned short*)(ws_c + WS_GB);
  const unsigned short* w2t = (const unsigned short*)(ws_c + WS_W2T);

  const int tid = threadIdx.x;
  const int M0 = (blockIdx.x >> 2) * 32;
  const int N0 = (blockIdx.x & 3) * 64;
  const int lane = tid & 63;
  const int wid = tid >> 6;
  const int wm = wid >> 1, wn = wid & 1;
  const int m16 = lane & 15, q = lane >> 4;

  const int sa_m = tid >> 3, sa_k = (tid & 7) * 4;
  const int sb_n = tid >> 2, sb_k = (tid & 3) * 8;

  ushort4 ua;
  f4 ub;
  ua = *(const ushort4*)(gb  + (size_t)(M0 + sa_m)*1024 + sa_k);
  ub = *(const f4*)(w2t + (size_t)(N0 + sb_n)*1024 + sb_k);

  ffrag acc[2];
  acc[0] = (ffrag){0.f,0.f,0.f,0.f};
  acc[1] = (ffrag){0.f,0.f,0.f,0.f};

  for (int ks=0; ks<32; ++ks){
    const int buf = ks & 1;
    *(ushort4*)&aT[buf][sa_m*40 + sa_k] = ua;
    *(f4*)&bT[buf][sb_n*40 + sb_k]      = ub;
    __syncthreads();
    int kn = (ks < 31) ? ks+1 : 31;
    ua = *(const ushort4*)(gb  + (size_t)(M0 + sa_m)*1024 + kn*32 + sa_k);
    ub = *(const f4*)(w2t + (size_t)(N0 + sb_n)*1024 + kn*32 + sb_k);

    bfrag af, bf0, bf1;
    af  = *(const bfrag*)&aT[buf][(wm*16 + m16)*40 + q*8];
    bf0 = *(const bfrag*)&bT[buf][(wn*32 + m16)*40 + q*8];
    bf1 = *(const bfrag*)&bT[buf][(wn*32 + 16 + m16)*40 + q*8];
    acc[0] = __builtin_amdgcn_mfma_f32_16x16x32_bf16(bf0, af, acc[0], 0, 0, 0);
    acc[1] = __builtin_amdgcn_mfma_f32_16x16x32_bf16(bf1, af, acc[1], 0, 0, 0);
  }

  const int m = M0 + wm*16 + m16;
  #pragma unroll
  for (int j=0;j<2;++j){
    const int n4 = N0 + wn*32 + j*16 + q*4;
    f4 bv = *(const f4*)(b2 + n4);
    f4 hv = *(const f4*)(ws + WS_HT + (size_t)m*256 + n4);
    *(f4*)(out + (size_t)m*256 + n4) =
      make_float4(acc[j][0]+bv.x+hv.x, acc[j][1]+bv.y+hv.y,
                  acc[j][2]+bv.z+hv.z, acc[j][3]+bv.w+hv.w);
  }
}

// ------------------------------------------------------------------
extern "C" void kernel_launch(void* const* d_in, const int* in_sizes, int n_in,
                              void* d_out, int out_size, void* d_ws, size_t ws_size,
                              hipStream_t stream)
{
  const float* x    = (const float*)d_in[0];
  const int*   idx  = (const int*)  d_in[1];
  const float* ctx  = (const float*)d_in[2];
  const float* Wp   = (const float*)d_in[3];
  const float* Bp   = (const float*)d_in[4];
  const float* qemb = (const float*)d_in[5];
  const float* Wkv  = (const float*)d_in[6];
  const float* bkv  = (const float*)d_in[7];
  const float* Wqc  = (const float*)d_in[8];
  const float* bqc  = (const float*)d_in[9];
  const float* Whc  = (const float*)d_in[10];
  const float* bhc  = (const float*)d_in[11];
  const float* Wq   = (const float*)d_in[12];
  const float* Wk   = (const float*)d_in[13];
  const float* Wv   = (const float*)d_in[14];
  const float* Wo   = (const float*)d_in[15];
  const float* W1   = (const float*)d_in[16];
  const float* b1   = (const float*)d_in[17];
  const float* W2   = (const float*)d_in[18];
  const float* b2   = (const float*)d_in[19];
  float* ws  = (float*)d_ws;
  float* out = (float*)d_out;

  hipLaunchKernelGGL(kwm_conv, dim3(384),  dim3(256), 0, stream, W1, W2, Wv, Wo, ws);
  hipLaunchKernelGGL(k0_all,   dim3(16),   dim3(256), 0, stream,
                     ctx, qemb, Wkv, bkv, Wqc, bqc, Whc, bhc, Wq, Wk, ws);
  hipLaunchKernelGGL(k1f_attn, dim3(1024), dim3(256), 0, stream, x, idx, Wp, Bp, ws);
  hipLaunchKernelGGL(k2g_mfma, dim3(512),  dim3(256), 0, stream, ws);
  hipLaunchKernelGGL(ke_ln,    dim3(512),  dim3(256), 0, stream, qemb, ws);
  hipLaunchKernelGGL(k3_mfma,  dim3(512),  dim3(256), 0, stream, b1, ws);
  hipLaunchKernelGGL(k4_mfma,  dim3(512),  dim3(256), 0, stream, b2, ws, ws, out);
}